// Round 1
// baseline (787.607 us; speedup 1.0000x reference)
//
#include <hip/hip_runtime.h>
#include <hip/hip_bf16.h>

#define N_NODES 50000
#define N_EDGES 800000
#define C 128
#define D_IN 32
#define T0 25000
#define OUT_DIM 16

// ---------------------------------------------------------------------------
// Encode: x[n,:] = feats_tbl(row) @ enc_w + enc_b, table chosen per node
// ---------------------------------------------------------------------------
__global__ __launch_bounds__(128) void encode_kernel(
    const float* __restrict__ feats0, const float* __restrict__ feats1,
    const float* __restrict__ w0, const float* __restrict__ b0,
    const float* __restrict__ w1, const float* __restrict__ b1,
    const int* __restrict__ row_idx, float* __restrict__ x)
{
    __shared__ float sw0[D_IN * C];
    __shared__ float sw1[D_IN * C];
    __shared__ float sb0[C];
    __shared__ float sb1[C];
    for (int i = threadIdx.x; i < D_IN * C; i += blockDim.x) {
        sw0[i] = w0[i];
        sw1[i] = w1[i];
    }
    if (threadIdx.x < C) {
        sb0[threadIdx.x] = b0[threadIdx.x];
        sb1[threadIdx.x] = b1[threadIdx.x];
    }
    __syncthreads();

    int c = threadIdx.x;  // 0..127
    for (int n = blockIdx.x; n < N_NODES; n += gridDim.x) {
        int r = row_idx[n];  // wave-uniform (same for whole block)
        const float* f = (r < T0) ? (feats0 + (size_t)r * D_IN)
                                  : (feats1 + (size_t)(r - T0) * D_IN);
        const float* W = (r < T0) ? sw0 : sw1;
        float acc = (r < T0) ? sb0[c] : sb1[c];
#pragma unroll
        for (int k = 0; k < D_IN; ++k)
            acc += f[k] * W[k * C + c];
        x[(size_t)n * C + c] = acc;
    }
}

// ---------------------------------------------------------------------------
// CSR build: histogram -> scan -> scatter
// ---------------------------------------------------------------------------
__global__ __launch_bounds__(256) void hist_kernel(const int* __restrict__ dst,
                                                   int* __restrict__ counts)
{
    int i = blockIdx.x * blockDim.x + threadIdx.x;
    if (i < N_EDGES) atomicAdd(&counts[dst[i]], 1);
}

__global__ __launch_bounds__(1024) void scan_kernel(
    const int* __restrict__ counts, int* __restrict__ offsets,
    float* __restrict__ deg)
{
    __shared__ int wave_sums[16];
    const int T = 1024;
    const int n = N_NODES;
    int tid = threadIdx.x;
    int per = (n + T - 1) / T;  // 49
    int begin = tid * per;
    int end = begin + per;
    if (end > n) end = n;

    int s = 0;
    for (int i = begin; i < end; ++i) s += counts[i];

    // inclusive scan of s across the 64-lane wave
    int lane = tid & 63, wid = tid >> 6;
    int v = s;
#pragma unroll
    for (int off = 1; off < 64; off <<= 1) {
        int t = __shfl_up(v, off, 64);
        if (lane >= off) v += t;
    }
    if (lane == 63) wave_sums[wid] = v;
    __syncthreads();
    if (tid == 0) {
        int run = 0;
        for (int i = 0; i < 16; ++i) {  // serial inclusive scan of 16 values
            int t = wave_sums[i];
            wave_sums[i] = run + t;
            run += t;
        }
    }
    __syncthreads();
    int wave_excl = (wid == 0) ? 0 : wave_sums[wid - 1];
    int run = wave_excl + (v - s);  // exclusive prefix for this thread
    for (int i = begin; i < end; ++i) {
        offsets[i] = run;
        int cnt = counts[i];
        run += cnt;
        deg[i] = (float)(cnt > 0 ? cnt : 1);
    }
    if (tid == 0) offsets[n] = wave_sums[15];
}

__global__ __launch_bounds__(256) void scatter_kernel(
    const int* __restrict__ src, const int* __restrict__ dst,
    const int* __restrict__ offsets, int* __restrict__ cursor,
    int* __restrict__ src_sorted)
{
    int i = blockIdx.x * blockDim.x + threadIdx.x;
    if (i < N_EDGES) {
        int d = dst[i];
        int pos = offsets[d] + atomicAdd(&cursor[d], 1);
        src_sorted[pos] = src[i];
    }
}

// ---------------------------------------------------------------------------
// Aggregate: one 64-lane wave per dst node; agg[n,:] = sum_e x[src_e,:] / deg
// ---------------------------------------------------------------------------
__global__ __launch_bounds__(256) void aggregate_kernel(
    const float* __restrict__ x, const int* __restrict__ offsets,
    const int* __restrict__ src_sorted, const float* __restrict__ deg,
    float* __restrict__ agg)
{
    int wave = (blockIdx.x * blockDim.x + threadIdx.x) >> 6;
    int lane = threadIdx.x & 63;
    if (wave >= N_NODES) return;
    int beg = offsets[wave];
    int end = offsets[wave + 1];
    const float2* xp = (const float2*)x;
    float2 acc = make_float2(0.f, 0.f);
    for (int e = beg; e < end; ++e) {
        int s = src_sorted[e];
        float2 v = xp[(size_t)s * 64 + lane];
        acc.x += v.x;
        acc.y += v.y;
    }
    float inv = 1.0f / deg[wave];
    ((float2*)agg)[(size_t)wave * 64 + lane] = make_float2(acc.x * inv, acc.y * inv);
}

// ---------------------------------------------------------------------------
// Layer GEMM (in-place): x = act(x @ ws + agg @ wn + b)
// block: 256 threads, 64 rows x 128 cols, K chunked by 16
// ---------------------------------------------------------------------------
#define TM 64
__global__ __launch_bounds__(256) void gemm_layer(
    float* __restrict__ x, const float* __restrict__ agg,
    const float* __restrict__ wself, const float* __restrict__ wneigh,
    const float* __restrict__ bias, int relu)
{
    __shared__ float xs[TM][16];
    __shared__ float as_[TM][16];
    __shared__ float wS[16][C];
    __shared__ float wN[16][C];
    __shared__ float bS[C];

    int row0 = blockIdx.x * TM;
    int tid = threadIdx.x;
    if (tid < C) bS[tid] = bias[tid];

    int tx = tid & 31;  // col group: cols tx*4 .. tx*4+3
    int ty = tid >> 5;  // 0..7

    float4 acc[8];
#pragma unroll
    for (int j = 0; j < 8; ++j) acc[j] = make_float4(0.f, 0.f, 0.f, 0.f);

    for (int kc = 0; kc < C; kc += 16) {
        __syncthreads();
        {
            int r = tid >> 2;  // 0..63
            int p = tid & 3;   // which float4 of the 16-float chunk
            int row = row0 + r;
            int rr = row < N_NODES ? row : N_NODES - 1;
            const float4* xp = (const float4*)(x + (size_t)rr * C + kc);
            const float4* ap = (const float4*)(agg + (size_t)rr * C + kc);
            ((float4*)&xs[r][0])[p] = xp[p];
            ((float4*)&as_[r][0])[p] = ap[p];
        }
        {
            const float4* wsp = (const float4*)(wself + (size_t)kc * C);
            const float4* wnp = (const float4*)(wneigh + (size_t)kc * C);
            float4* dS = (float4*)&wS[0][0];
            float4* dN = (float4*)&wN[0][0];
            dS[tid] = wsp[tid];
            dS[tid + 256] = wsp[tid + 256];
            dN[tid] = wnp[tid];
            dN[tid + 256] = wnp[tid + 256];
        }
        __syncthreads();
#pragma unroll
        for (int k = 0; k < 16; ++k) {
            float4 w4 = ((const float4*)&wS[k][0])[tx];
            float4 n4 = ((const float4*)&wN[k][0])[tx];
#pragma unroll
            for (int j = 0; j < 8; ++j) {
                int r = ty + 8 * j;
                float xv = xs[r][k];
                float av = as_[r][k];
                acc[j].x += xv * w4.x + av * n4.x;
                acc[j].y += xv * w4.y + av * n4.y;
                acc[j].z += xv * w4.z + av * n4.z;
                acc[j].w += xv * w4.w + av * n4.w;
            }
        }
    }

    float4 bb = ((const float4*)bS)[tx];
#pragma unroll
    for (int j = 0; j < 8; ++j) {
        int row = row0 + ty + 8 * j;
        if (row >= N_NODES) continue;
        float4 o = acc[j];
        o.x += bb.x; o.y += bb.y; o.z += bb.z; o.w += bb.w;
        if (relu) {
            o.x = fmaxf(o.x, 0.f); o.y = fmaxf(o.y, 0.f);
            o.z = fmaxf(o.z, 0.f); o.w = fmaxf(o.w, 0.f);
        }
        ((float4*)(x + (size_t)row * C))[tx] = o;
    }
}

// ---------------------------------------------------------------------------
// Head: out = x @ head_w + head_b   [N,128] @ [128,16]
// ---------------------------------------------------------------------------
__global__ __launch_bounds__(256) void head_kernel(
    const float* __restrict__ x, const float* __restrict__ hw,
    const float* __restrict__ hb, float* __restrict__ out)
{
    __shared__ float w[C * OUT_DIM];
    __shared__ float b[OUT_DIM];
    for (int i = threadIdx.x; i < C * OUT_DIM; i += blockDim.x) w[i] = hw[i];
    if (threadIdx.x < OUT_DIM) b[threadIdx.x] = hb[threadIdx.x];
    __syncthreads();

    int node = blockIdx.x * 16 + (threadIdx.x >> 4);
    int c = threadIdx.x & 15;
    if (node >= N_NODES) return;
    float acc = b[c];
    const float* xr = x + (size_t)node * C;
#pragma unroll 8
    for (int k = 0; k < C; ++k) acc += xr[k] * w[k * OUT_DIM + c];
    out[(size_t)node * OUT_DIM + c] = acc;
}

// ---------------------------------------------------------------------------
extern "C" void kernel_launch(void* const* d_in, const int* in_sizes, int n_in,
                              void* d_out, int out_size, void* d_ws, size_t ws_size,
                              hipStream_t stream)
{
    const float* feats0 = (const float*)d_in[0];
    const float* feats1 = (const float*)d_in[1];
    const float* enc_w0 = (const float*)d_in[2];
    const float* enc_b0 = (const float*)d_in[3];
    const float* enc_w1 = (const float*)d_in[4];
    const float* enc_b1 = (const float*)d_in[5];
    const float* w_self0 = (const float*)d_in[6];
    const float* w_neigh0 = (const float*)d_in[7];
    const float* b0 = (const float*)d_in[8];
    const float* w_self1 = (const float*)d_in[9];
    const float* w_neigh1 = (const float*)d_in[10];
    const float* b1 = (const float*)d_in[11];
    const float* head_w = (const float*)d_in[12];
    const float* head_b = (const float*)d_in[13];
    const int* node_row_idx = (const int*)d_in[14];
    const int* edge_index = (const int*)d_in[15];
    const int* e_src = edge_index;             // edge_index[0]
    const int* e_dst = edge_index + N_EDGES;   // edge_index[1]

    char* ws = (char*)d_ws;
    float* x = (float*)ws;        ws += (size_t)N_NODES * C * sizeof(float);
    float* agg = (float*)ws;      ws += (size_t)N_NODES * C * sizeof(float);
    float* deg = (float*)ws;      ws += (size_t)N_NODES * sizeof(float);
    int* counts = (int*)ws;       ws += (size_t)N_NODES * sizeof(int);
    int* offsets = (int*)ws;      ws += (size_t)(N_NODES + 8) * sizeof(int);
    int* cursor = (int*)ws;       ws += (size_t)N_NODES * sizeof(int);
    int* src_sorted = (int*)ws;   ws += (size_t)N_EDGES * sizeof(int);

    hipMemsetAsync(counts, 0, (size_t)N_NODES * sizeof(int), stream);
    hipMemsetAsync(cursor, 0, (size_t)N_NODES * sizeof(int), stream);

    encode_kernel<<<1024, 128, 0, stream>>>(feats0, feats1, enc_w0, enc_b0,
                                            enc_w1, enc_b1, node_row_idx, x);

    hist_kernel<<<(N_EDGES + 255) / 256, 256, 0, stream>>>(e_dst, counts);
    scan_kernel<<<1, 1024, 0, stream>>>(counts, offsets, deg);
    scatter_kernel<<<(N_EDGES + 255) / 256, 256, 0, stream>>>(
        e_src, e_dst, offsets, cursor, src_sorted);

    // Layer 0
    aggregate_kernel<<<(N_NODES * 64 + 255) / 256, 256, 0, stream>>>(
        x, offsets, src_sorted, deg, agg);
    gemm_layer<<<(N_NODES + TM - 1) / TM, 256, 0, stream>>>(
        x, agg, w_self0, w_neigh0, b0, 1);

    // Layer 1
    aggregate_kernel<<<(N_NODES * 64 + 255) / 256, 256, 0, stream>>>(
        x, offsets, src_sorted, deg, agg);
    gemm_layer<<<(N_NODES + TM - 1) / TM, 256, 0, stream>>>(
        x, agg, w_self1, w_neigh1, b1, 0);

    head_kernel<<<(N_NODES + 15) / 16, 256, 0, stream>>>(x, head_w, head_b,
                                                         (float*)d_out);
}

// Round 2
// 630.301 us; speedup vs baseline: 1.2496x; 1.2496x over previous
//
#include <hip/hip_runtime.h>
#include <hip/hip_bf16.h>

#define N_NODES 50000
#define N_EDGES 800000
#define C 128
#define D_IN 32
#define T0 25000
#define OUT_DIM 16

typedef __attribute__((ext_vector_type(8))) short short8;
typedef __attribute__((ext_vector_type(4))) float f32x4;

__device__ __forceinline__ unsigned short f2bf(float f) {
    union { float f; unsigned int i; } u; u.f = f;
    unsigned int x = u.i;
    unsigned int r = x + 0x7fffu + ((x >> 16) & 1u);
    return (unsigned short)(r >> 16);
}
__device__ __forceinline__ float bf2f(unsigned short h) {
    union { unsigned int i; float f; } u; u.i = ((unsigned int)h) << 16;
    return u.f;
}
__device__ __forceinline__ void async16(void* lds, const void* g) {
    __builtin_amdgcn_global_load_lds(
        (const __attribute__((address_space(1))) void*)g,
        (__attribute__((address_space(3))) void*)lds, 16, 0, 0);
}

// ---------------------------------------------------------------------------
// Encode: x[n,:] = feats_tbl(row) @ enc_w + enc_b -> split into bf16 hi/lo
// ---------------------------------------------------------------------------
__global__ __launch_bounds__(128) void encode_kernel(
    const float* __restrict__ feats0, const float* __restrict__ feats1,
    const float* __restrict__ w0, const float* __restrict__ b0,
    const float* __restrict__ w1, const float* __restrict__ b1,
    const int* __restrict__ row_idx,
    unsigned short* __restrict__ xh, unsigned short* __restrict__ xl)
{
    __shared__ float sw0[D_IN * C];
    __shared__ float sw1[D_IN * C];
    __shared__ float sb0[C];
    __shared__ float sb1[C];
    for (int i = threadIdx.x; i < D_IN * C; i += blockDim.x) {
        sw0[i] = w0[i];
        sw1[i] = w1[i];
    }
    if (threadIdx.x < C) {
        sb0[threadIdx.x] = b0[threadIdx.x];
        sb1[threadIdx.x] = b1[threadIdx.x];
    }
    __syncthreads();

    int c = threadIdx.x;  // 0..127
    for (int n = blockIdx.x; n < N_NODES; n += gridDim.x) {
        int r = row_idx[n];  // block-uniform
        const float* f = (r < T0) ? (feats0 + (size_t)r * D_IN)
                                  : (feats1 + (size_t)(r - T0) * D_IN);
        const float* W = (r < T0) ? sw0 : sw1;
        float acc = (r < T0) ? sb0[c] : sb1[c];
#pragma unroll
        for (int k = 0; k < D_IN; ++k)
            acc += f[k] * W[k * C + c];
        unsigned short hi = f2bf(acc);
        xh[(size_t)n * C + c] = hi;
        xl[(size_t)n * C + c] = f2bf(acc - bf2f(hi));
    }
}

// ---------------------------------------------------------------------------
// Weight prep: B_catT[layer][n][k], k in [0,768), segments:
//   0:hi(ws) 1:hi(wn) 2:hi(ws) 3:hi(wn) 4:lo(ws) 5:lo(wn)
// ---------------------------------------------------------------------------
__global__ __launch_bounds__(256) void prep_weights(
    const float* __restrict__ ws0, const float* __restrict__ wn0,
    const float* __restrict__ ws1, const float* __restrict__ wn1,
    unsigned short* __restrict__ BT0, unsigned short* __restrict__ BT1)
{
    int idx = blockIdx.x * 256 + threadIdx.x;
    const int per_layer = 128 * 768;
    if (idx >= 2 * per_layer) return;
    int lyr = idx / per_layer;
    int rem = idx - lyr * per_layer;
    int n = rem / 768;
    int k = rem - n * 768;
    int seg = k >> 7;
    int kk = k & 127;
    const float* W = (lyr == 0) ? ((seg & 1) ? wn0 : ws0)
                                : ((seg & 1) ? wn1 : ws1);
    float v = W[kk * 128 + n];
    unsigned short hi = f2bf(v);
    unsigned short out = (seg < 4) ? hi : f2bf(v - bf2f(hi));
    (lyr == 0 ? BT0 : BT1)[(size_t)n * 768 + k] = out;
}

// ---------------------------------------------------------------------------
// CSR build: histogram -> scan -> scatter
// ---------------------------------------------------------------------------
__global__ __launch_bounds__(256) void hist_kernel(const int* __restrict__ dst,
                                                   int* __restrict__ counts)
{
    int i = blockIdx.x * blockDim.x + threadIdx.x;
    if (i < N_EDGES) atomicAdd(&counts[dst[i]], 1);
}

__global__ __launch_bounds__(1024) void scan_kernel(
    const int* __restrict__ counts, int* __restrict__ offsets,
    float* __restrict__ deg)
{
    __shared__ int wave_sums[16];
    const int T = 1024;
    const int n = N_NODES;
    int tid = threadIdx.x;
    int per = (n + T - 1) / T;  // 49
    int begin = tid * per;
    int end = begin + per;
    if (end > n) end = n;

    int s = 0;
    for (int i = begin; i < end; ++i) s += counts[i];

    int lane = tid & 63, wid = tid >> 6;
    int v = s;
#pragma unroll
    for (int off = 1; off < 64; off <<= 1) {
        int t = __shfl_up(v, off, 64);
        if (lane >= off) v += t;
    }
    if (lane == 63) wave_sums[wid] = v;
    __syncthreads();
    if (tid == 0) {
        int run = 0;
        for (int i = 0; i < 16; ++i) {
            int t = wave_sums[i];
            wave_sums[i] = run + t;
            run += t;
        }
    }
    __syncthreads();
    int wave_excl = (wid == 0) ? 0 : wave_sums[wid - 1];
    int run = wave_excl + (v - s);
    for (int i = begin; i < end; ++i) {
        offsets[i] = run;
        int cnt = counts[i];
        run += cnt;
        deg[i] = (float)(cnt > 0 ? cnt : 1);
    }
    if (tid == 0) offsets[n] = wave_sums[15];
}

__global__ __launch_bounds__(256) void scatter_kernel(
    const int* __restrict__ src, const int* __restrict__ dst,
    const int* __restrict__ offsets, int* __restrict__ cursor,
    int* __restrict__ src_sorted)
{
    int i = blockIdx.x * blockDim.x + threadIdx.x;
    if (i < N_EDGES) {
        int d = dst[i];
        int pos = offsets[d] + atomicAdd(&cursor[d], 1);
        src_sorted[pos] = src[i];
    }
}

// ---------------------------------------------------------------------------
// Aggregate: one wave per dst node; mean of (hi+lo) neighbor rows,
// result split back into bf16 hi/lo.
// ---------------------------------------------------------------------------
__global__ __launch_bounds__(256) void aggregate_kernel(
    const unsigned short* __restrict__ xh, const unsigned short* __restrict__ xl,
    const int* __restrict__ offsets, const int* __restrict__ src_sorted,
    const float* __restrict__ deg,
    unsigned short* __restrict__ ah, unsigned short* __restrict__ al)
{
    int wave = (blockIdx.x * blockDim.x + threadIdx.x) >> 6;
    int lane = threadIdx.x & 63;
    if (wave >= N_NODES) return;
    int beg = offsets[wave];
    int end = offsets[wave + 1];
    const unsigned int* xh2 = (const unsigned int*)xh;
    const unsigned int* xl2 = (const unsigned int*)xl;
    float ax = 0.f, ay = 0.f;
    for (int e = beg; e < end; ++e) {
        int s = src_sorted[e];
        unsigned int h = xh2[(size_t)s * 64 + lane];
        unsigned int lo = xl2[(size_t)s * 64 + lane];
        ax += bf2f((unsigned short)(h & 0xffffu)) + bf2f((unsigned short)(lo & 0xffffu));
        ay += bf2f((unsigned short)(h >> 16)) + bf2f((unsigned short)(lo >> 16));
    }
    float inv = 1.0f / deg[wave];
    ax *= inv; ay *= inv;
    unsigned short hx = f2bf(ax), hy = f2bf(ay);
    float lx = ax - bf2f(hx), ly = ay - bf2f(hy);
    ((unsigned int*)ah)[(size_t)wave * 64 + lane] =
        (unsigned int)hx | ((unsigned int)hy << 16);
    ((unsigned int*)al)[(size_t)wave * 64 + lane] =
        (unsigned int)f2bf(lx) | ((unsigned int)f2bf(ly) << 16);
}

// ---------------------------------------------------------------------------
// Layer GEMM via split-bf16 MFMA, K = 768 over 6 segments of 128:
//   A = [x_hi | agg_hi | x_lo | agg_lo | x_hi | agg_hi]  (per-row)
//   B_catT pre-built [n=128][k=768].  In-place update of xh/xl.
// Block: 256 thr, tile 64 rows x 128 cols, BK=128, mfma 16x16x32 bf16.
// ---------------------------------------------------------------------------
#define BM 64
__global__ __launch_bounds__(256) void gemm_mfma(
    unsigned short* __restrict__ xh, unsigned short* __restrict__ xl,
    const unsigned short* __restrict__ ah, const unsigned short* __restrict__ al,
    const unsigned short* __restrict__ BT, const float* __restrict__ bias,
    int relu)
{
    __shared__ unsigned short As[64 * 128];   // [row][k]  16 KB, 256 B/row
    __shared__ unsigned short Bs[128 * 128];  // [n][k]    32 KB, 256 B/row
    __shared__ float bias_s[C];

    int tid = threadIdx.x;
    int w = tid >> 6, l = tid & 63;
    int row0 = blockIdx.x * BM;
    if (tid < C) bias_s[tid] = bias[tid];

    const unsigned short* segs[6] = {xh, ah, xl, al, xh, ah};

    f32x4 acc[2][4];
#pragma unroll
    for (int mt = 0; mt < 2; ++mt)
#pragma unroll
        for (int nt = 0; nt < 4; ++nt)
            acc[mt][nt] = (f32x4)(0.f);

    int wm = w & 1;    // row half: rows [wm*32, wm*32+32)
    int wn = w >> 1;   // col half: cols [wn*64, wn*64+64)
    int quad = l >> 4;
    int mrow = l & 15;

    for (int cidx = 0; cidx < 6; ++cidx) {
        const unsigned short* segp = segs[cidx];
        // --- stage A (16 KB): rows are contiguous 256 B in global ---
#pragma unroll
        for (int i = 0; i < 4; ++i) {
            int off = w * 4096 + i * 1024 + l * 16;
            int row = row0 + (off >> 8);
            if (row > N_NODES - 1) row = N_NODES - 1;
            const char* g = (const char*)segp + (size_t)row * 256 + (off & 255);
            async16((char*)As + w * 4096 + i * 1024, g);
        }
        // --- stage B (32 KB): BT row stride 1536 B, chunk col off cidx*256 ---
#pragma unroll
        for (int i = 0; i < 8; ++i) {
            int off = w * 8192 + i * 1024 + l * 16;
            int n = off >> 8;
            const char* g = (const char*)BT + (size_t)n * 1536 + cidx * 256 + (off & 255);
            async16((char*)Bs + w * 8192 + i * 1024, g);
        }
        __syncthreads();
#pragma unroll
        for (int ks = 0; ks < 4; ++ks) {
            int kb = ks * 64 + quad * 16;  // byte offset into 256 B row
            short8 a0 = *(const short8*)((const char*)As + (wm * 32 + mrow) * 256 + kb);
            short8 a1 = *(const short8*)((const char*)As + (wm * 32 + 16 + mrow) * 256 + kb);
            short8 b[4];
#pragma unroll
            for (int nt = 0; nt < 4; ++nt)
                b[nt] = *(const short8*)((const char*)Bs + (wn * 64 + nt * 16 + mrow) * 256 + kb);
#pragma unroll
            for (int nt = 0; nt < 4; ++nt) {
                acc[0][nt] = __builtin_amdgcn_mfma_f32_16x16x32_bf16(a0, b[nt], acc[0][nt], 0, 0, 0);
                acc[1][nt] = __builtin_amdgcn_mfma_f32_16x16x32_bf16(a1, b[nt], acc[1][nt], 0, 0, 0);
            }
        }
        __syncthreads();
    }

    // epilogue: C/D layout col=lane&15, row=quad*4+reg
#pragma unroll
    for (int mt = 0; mt < 2; ++mt)
#pragma unroll
        for (int nt = 0; nt < 4; ++nt) {
            int col = wn * 64 + nt * 16 + mrow;
            float bb = bias_s[col];
#pragma unroll
            for (int r = 0; r < 4; ++r) {
                int row = row0 + wm * 32 + mt * 16 + quad * 4 + r;
                if (row >= N_NODES) continue;
                float v = acc[mt][nt][r] + bb;
                if (relu) v = fmaxf(v, 0.f);
                unsigned short hi = f2bf(v);
                xh[(size_t)row * C + col] = hi;
                xl[(size_t)row * C + col] = f2bf(v - bf2f(hi));
            }
        }
}

// ---------------------------------------------------------------------------
// Head: out = x @ head_w + head_b   [N,128] @ [128,16]
// ---------------------------------------------------------------------------
__global__ __launch_bounds__(256) void head_kernel(
    const unsigned short* __restrict__ xh, const unsigned short* __restrict__ xl,
    const float* __restrict__ hw, const float* __restrict__ hb,
    float* __restrict__ out)
{
    __shared__ float w[C * OUT_DIM];
    __shared__ float b[OUT_DIM];
    for (int i = threadIdx.x; i < C * OUT_DIM; i += blockDim.x) w[i] = hw[i];
    if (threadIdx.x < OUT_DIM) b[threadIdx.x] = hb[threadIdx.x];
    __syncthreads();

    int node = blockIdx.x * 16 + (threadIdx.x >> 4);
    int c = threadIdx.x & 15;
    if (node >= N_NODES) return;
    float acc = b[c];
    const unsigned short* xrh = xh + (size_t)node * C;
    const unsigned short* xrl = xl + (size_t)node * C;
#pragma unroll 8
    for (int k = 0; k < C; ++k)
        acc += (bf2f(xrh[k]) + bf2f(xrl[k])) * w[k * OUT_DIM + c];
    out[(size_t)node * OUT_DIM + c] = acc;
}

// ---------------------------------------------------------------------------
extern "C" void kernel_launch(void* const* d_in, const int* in_sizes, int n_in,
                              void* d_out, int out_size, void* d_ws, size_t ws_size,
                              hipStream_t stream)
{
    const float* feats0 = (const float*)d_in[0];
    const float* feats1 = (const float*)d_in[1];
    const float* enc_w0 = (const float*)d_in[2];
    const float* enc_b0 = (const float*)d_in[3];
    const float* enc_w1 = (const float*)d_in[4];
    const float* enc_b1 = (const float*)d_in[5];
    const float* w_self0 = (const float*)d_in[6];
    const float* w_neigh0 = (const float*)d_in[7];
    const float* b0 = (const float*)d_in[8];
    const float* w_self1 = (const float*)d_in[9];
    const float* w_neigh1 = (const float*)d_in[10];
    const float* b1 = (const float*)d_in[11];
    const float* head_w = (const float*)d_in[12];
    const float* head_b = (const float*)d_in[13];
    const int* node_row_idx = (const int*)d_in[14];
    const int* edge_index = (const int*)d_in[15];
    const int* e_src = edge_index;
    const int* e_dst = edge_index + N_EDGES;

    char* p = (char*)d_ws;
    unsigned short* xh = (unsigned short*)p;  p += (size_t)N_NODES * C * 2;
    unsigned short* xl = (unsigned short*)p;  p += (size_t)N_NODES * C * 2;
    unsigned short* ah = (unsigned short*)p;  p += (size_t)N_NODES * C * 2;
    unsigned short* al = (unsigned short*)p;  p += (size_t)N_NODES * C * 2;
    unsigned short* BT0 = (unsigned short*)p; p += (size_t)128 * 768 * 2;
    unsigned short* BT1 = (unsigned short*)p; p += (size_t)128 * 768 * 2;
    float* deg = (float*)p;      p += (size_t)N_NODES * 4;
    int* counts = (int*)p;       p += (size_t)N_NODES * 4;
    int* offsets = (int*)p;      p += (size_t)(N_NODES + 8) * 4;
    int* cursor = (int*)p;       p += (size_t)N_NODES * 4;
    int* src_sorted = (int*)p;   p += (size_t)N_EDGES * 4;

    hipMemsetAsync(counts, 0, (size_t)N_NODES * sizeof(int), stream);
    hipMemsetAsync(cursor, 0, (size_t)N_NODES * sizeof(int), stream);

    encode_kernel<<<1024, 128, 0, stream>>>(feats0, feats1, enc_w0, enc_b0,
                                            enc_w1, enc_b1, node_row_idx, xh, xl);
    prep_weights<<<(2 * 128 * 768 + 255) / 256, 256, 0, stream>>>(
        w_self0, w_neigh0, w_self1, w_neigh1, BT0, BT1);

    hist_kernel<<<(N_EDGES + 255) / 256, 256, 0, stream>>>(e_dst, counts);
    scan_kernel<<<1, 1024, 0, stream>>>(counts, offsets, deg);
    scatter_kernel<<<(N_EDGES + 255) / 256, 256, 0, stream>>>(
        e_src, e_dst, offsets, cursor, src_sorted);

    // Layer 0
    aggregate_kernel<<<(N_NODES * 64 + 255) / 256, 256, 0, stream>>>(
        xh, xl, offsets, src_sorted, deg, ah, al);
    gemm_mfma<<<(N_NODES + BM - 1) / BM, 256, 0, stream>>>(
        xh, xl, ah, al, BT0, b0, 1);

    // Layer 1
    aggregate_kernel<<<(N_NODES * 64 + 255) / 256, 256, 0, stream>>>(
        xh, xl, offsets, src_sorted, deg, ah, al);
    gemm_mfma<<<(N_NODES + BM - 1) / BM, 256, 0, stream>>>(
        xh, xl, ah, al, BT1, b1, 0);

    head_kernel<<<(N_NODES + 15) / 16, 256, 0, stream>>>(xh, xl, head_w, head_b,
                                                         (float*)d_out);
}

// Round 3
// 527.706 us; speedup vs baseline: 1.4925x; 1.1944x over previous
//
#include <hip/hip_runtime.h>
#include <hip/hip_bf16.h>

#define N_NODES 50000
#define N_EDGES 800000
#define C 128
#define D_IN 32
#define T0 25000
#define OUT_DIM 16
#define SCAN_BLOCKS ((N_NODES + 255) / 256)   // 196

typedef __attribute__((ext_vector_type(8))) short short8;
typedef __attribute__((ext_vector_type(4))) float f32x4;

__device__ __forceinline__ unsigned short f2bf(float f) {
    union { float f; unsigned int i; } u; u.f = f;
    unsigned int x = u.i;
    unsigned int r = x + 0x7fffu + ((x >> 16) & 1u);
    return (unsigned short)(r >> 16);
}
__device__ __forceinline__ float bf2f(unsigned short h) {
    union { unsigned int i; float f; } u; u.i = ((unsigned int)h) << 16;
    return u.f;
}
__device__ __forceinline__ void async16(void* lds, const void* g) {
    __builtin_amdgcn_global_load_lds(
        (const __attribute__((address_space(1))) void*)g,
        (__attribute__((address_space(3))) void*)lds, 16, 0, 0);
}

// ---------------------------------------------------------------------------
// Encode: x[n,:] = feats_tbl(row) @ enc_w + enc_b -> split into bf16 hi/lo
// ---------------------------------------------------------------------------
__global__ __launch_bounds__(128) void encode_kernel(
    const float* __restrict__ feats0, const float* __restrict__ feats1,
    const float* __restrict__ w0, const float* __restrict__ b0,
    const float* __restrict__ w1, const float* __restrict__ b1,
    const int* __restrict__ row_idx,
    unsigned short* __restrict__ xh, unsigned short* __restrict__ xl)
{
    __shared__ float sw0[D_IN * C];
    __shared__ float sw1[D_IN * C];
    __shared__ float sb0[C];
    __shared__ float sb1[C];
    for (int i = threadIdx.x; i < D_IN * C; i += blockDim.x) {
        sw0[i] = w0[i];
        sw1[i] = w1[i];
    }
    if (threadIdx.x < C) {
        sb0[threadIdx.x] = b0[threadIdx.x];
        sb1[threadIdx.x] = b1[threadIdx.x];
    }
    __syncthreads();

    int c = threadIdx.x;  // 0..127
    for (int n = blockIdx.x; n < N_NODES; n += gridDim.x) {
        int r = row_idx[n];  // block-uniform
        const float* f = (r < T0) ? (feats0 + (size_t)r * D_IN)
                                  : (feats1 + (size_t)(r - T0) * D_IN);
        const float* W = (r < T0) ? sw0 : sw1;
        float acc = (r < T0) ? sb0[c] : sb1[c];
#pragma unroll
        for (int k = 0; k < D_IN; ++k)
            acc += f[k] * W[k * C + c];
        unsigned short hi = f2bf(acc);
        xh[(size_t)n * C + c] = hi;
        xl[(size_t)n * C + c] = f2bf(acc - bf2f(hi));
    }
}

// ---------------------------------------------------------------------------
// Weight prep: B_catT[layer][n][k], k in [0,768), segments:
//   0:hi(ws) 1:hi(wn) 2:hi(ws) 3:hi(wn) 4:lo(ws) 5:lo(wn)
// ---------------------------------------------------------------------------
__global__ __launch_bounds__(256) void prep_weights(
    const float* __restrict__ ws0, const float* __restrict__ wn0,
    const float* __restrict__ ws1, const float* __restrict__ wn1,
    unsigned short* __restrict__ BT0, unsigned short* __restrict__ BT1)
{
    int idx = blockIdx.x * 256 + threadIdx.x;
    const int per_layer = 128 * 768;
    if (idx >= 2 * per_layer) return;
    int lyr = idx / per_layer;
    int rem = idx - lyr * per_layer;
    int n = rem / 768;
    int k = rem - n * 768;
    int seg = k >> 7;
    int kk = k & 127;
    const float* W = (lyr == 0) ? ((seg & 1) ? wn0 : ws0)
                                : ((seg & 1) ? wn1 : ws1);
    float v = W[kk * 128 + n];
    unsigned short hi = f2bf(v);
    unsigned short out = (seg < 4) ? hi : f2bf(v - bf2f(hi));
    (lyr == 0 ? BT0 : BT1)[(size_t)n * 768 + k] = out;
}

// ---------------------------------------------------------------------------
// CSR build: histogram -> hierarchical scan (3 small kernels) -> scatter
// ---------------------------------------------------------------------------
__global__ __launch_bounds__(256) void hist_kernel(const int* __restrict__ dst,
                                                   int* __restrict__ counts)
{
    int i = blockIdx.x * blockDim.x + threadIdx.x;
    if (i < N_EDGES) atomicAdd(&counts[dst[i]], 1);
}

// phase 1: per-block exclusive scan of counts -> offsets (block-local), block sums
__global__ __launch_bounds__(256) void scan1_kernel(
    const int* __restrict__ counts, int* __restrict__ offsets,
    int* __restrict__ blk_sums)
{
    __shared__ int ws[4];
    int i = blockIdx.x * 256 + threadIdx.x;
    int c = (i < N_NODES) ? counts[i] : 0;
    int lane = threadIdx.x & 63, wid = threadIdx.x >> 6;
    int v = c;
#pragma unroll
    for (int off = 1; off < 64; off <<= 1) {
        int t = __shfl_up(v, off, 64);
        if (lane >= off) v += t;
    }
    if (lane == 63) ws[wid] = v;
    __syncthreads();
    if (threadIdx.x == 0) {
        int run = 0;
#pragma unroll
        for (int j = 0; j < 4; ++j) { int t = ws[j]; ws[j] = run; run += t; }
        blk_sums[blockIdx.x] = run;
    }
    __syncthreads();
    if (i < N_NODES) offsets[i] = ws[wid] + (v - c);
}

// phase 2: one block scans the block sums in place (each thread owns one slot)
__global__ __launch_bounds__(256) void scan2_kernel(int* __restrict__ blk_sums)
{
    __shared__ int ws[4];
    int t = threadIdx.x;
    int c = (t < SCAN_BLOCKS) ? blk_sums[t] : 0;
    int lane = t & 63, wid = t >> 6;
    int v = c;
#pragma unroll
    for (int off = 1; off < 64; off <<= 1) {
        int s = __shfl_up(v, off, 64);
        if (lane >= off) v += s;
    }
    if (lane == 63) ws[wid] = v;
    __syncthreads();
    if (t == 0) {
        int run = 0;
#pragma unroll
        for (int j = 0; j < 4; ++j) { int s = ws[j]; ws[j] = run; run += s; }
    }
    __syncthreads();
    if (t < SCAN_BLOCKS) blk_sums[t] = ws[wid] + (v - c);
}

// phase 3: add block prefix, emit final offsets, init cursor, deg
__global__ __launch_bounds__(256) void scan3_kernel(
    const int* __restrict__ counts, const int* __restrict__ blk_sums,
    int* __restrict__ offsets, int* __restrict__ cursor,
    float* __restrict__ deg)
{
    int i = blockIdx.x * 256 + threadIdx.x;
    if (i == 0) offsets[N_NODES] = N_EDGES;
    if (i >= N_NODES) return;
    int o = offsets[i] + blk_sums[blockIdx.x];
    offsets[i] = o;
    cursor[i] = o;
    int cnt = counts[i];
    deg[i] = (float)(cnt > 0 ? cnt : 1);
}

__global__ __launch_bounds__(256) void scatter_kernel(
    const int* __restrict__ src, const int* __restrict__ dst,
    int* __restrict__ cursor, int* __restrict__ src_sorted)
{
    int i = blockIdx.x * blockDim.x + threadIdx.x;
    if (i < N_EDGES) {
        int pos = atomicAdd(&cursor[dst[i]], 1);
        src_sorted[pos] = src[i];
    }
}

// ---------------------------------------------------------------------------
// Aggregate: one wave per dst node; mean of (hi+lo) neighbor rows,
// result split back into bf16 hi/lo.
// ---------------------------------------------------------------------------
__global__ __launch_bounds__(256) void aggregate_kernel(
    const unsigned short* __restrict__ xh, const unsigned short* __restrict__ xl,
    const int* __restrict__ offsets, const int* __restrict__ src_sorted,
    const float* __restrict__ deg,
    unsigned short* __restrict__ ah, unsigned short* __restrict__ al)
{
    int wave = (blockIdx.x * blockDim.x + threadIdx.x) >> 6;
    int lane = threadIdx.x & 63;
    if (wave >= N_NODES) return;
    int beg = offsets[wave];
    int end = offsets[wave + 1];
    const unsigned int* xh2 = (const unsigned int*)xh;
    const unsigned int* xl2 = (const unsigned int*)xl;
    float ax = 0.f, ay = 0.f;
    for (int e = beg; e < end; ++e) {
        int s = src_sorted[e];
        unsigned int h = xh2[(size_t)s * 64 + lane];
        unsigned int lo = xl2[(size_t)s * 64 + lane];
        ax += bf2f((unsigned short)(h & 0xffffu)) + bf2f((unsigned short)(lo & 0xffffu));
        ay += bf2f((unsigned short)(h >> 16)) + bf2f((unsigned short)(lo >> 16));
    }
    float inv = 1.0f / deg[wave];
    ax *= inv; ay *= inv;
    unsigned short hx = f2bf(ax), hy = f2bf(ay);
    float lx = ax - bf2f(hx), ly = ay - bf2f(hy);
    ((unsigned int*)ah)[(size_t)wave * 64 + lane] =
        (unsigned int)hx | ((unsigned int)hy << 16);
    ((unsigned int*)al)[(size_t)wave * 64 + lane] =
        (unsigned int)f2bf(lx) | ((unsigned int)f2bf(ly) << 16);
}

// ---------------------------------------------------------------------------
// Layer GEMM via split-bf16 MFMA, K = 768 over 6 segments of 128:
//   A = [x_hi | agg_hi | x_lo | agg_lo | x_hi | agg_hi]  (per-row)
//   B_catT pre-built [n=128][k=768].  In-place update of xh/xl.
// Block: 256 thr, tile 64 rows x 128 cols, BK=128, mfma 16x16x32 bf16.
// ---------------------------------------------------------------------------
#define BM 64
__global__ __launch_bounds__(256) void gemm_mfma(
    unsigned short* __restrict__ xh, unsigned short* __restrict__ xl,
    const unsigned short* __restrict__ ah, const unsigned short* __restrict__ al,
    const unsigned short* __restrict__ BT, const float* __restrict__ bias,
    int relu)
{
    __shared__ unsigned short As[64 * 128];   // [row][k]  16 KB, 256 B/row
    __shared__ unsigned short Bs[128 * 128];  // [n][k]    32 KB, 256 B/row
    __shared__ float bias_s[C];

    int tid = threadIdx.x;
    int w = tid >> 6, l = tid & 63;
    int row0 = blockIdx.x * BM;
    if (tid < C) bias_s[tid] = bias[tid];

    const unsigned short* segs[6] = {xh, ah, xl, al, xh, ah};

    f32x4 acc[2][4];
#pragma unroll
    for (int mt = 0; mt < 2; ++mt)
#pragma unroll
        for (int nt = 0; nt < 4; ++nt)
            acc[mt][nt] = (f32x4)(0.f);

    int wm = w & 1;    // row half: rows [wm*32, wm*32+32)
    int wn = w >> 1;   // col half: cols [wn*64, wn*64+64)
    int quad = l >> 4;
    int mrow = l & 15;

    for (int cidx = 0; cidx < 6; ++cidx) {
        const unsigned short* segp = segs[cidx];
        // --- stage A (16 KB): rows are contiguous 256 B in global ---
#pragma unroll
        for (int i = 0; i < 4; ++i) {
            int off = w * 4096 + i * 1024 + l * 16;
            int row = row0 + (off >> 8);
            if (row > N_NODES - 1) row = N_NODES - 1;
            const char* g = (const char*)segp + (size_t)row * 256 + (off & 255);
            async16((char*)As + w * 4096 + i * 1024, g);
        }
        // --- stage B (32 KB): BT row stride 1536 B, chunk col off cidx*256 ---
#pragma unroll
        for (int i = 0; i < 8; ++i) {
            int off = w * 8192 + i * 1024 + l * 16;
            int n = off >> 8;
            const char* g = (const char*)BT + (size_t)n * 1536 + cidx * 256 + (off & 255);
            async16((char*)Bs + w * 8192 + i * 1024, g);
        }
        __syncthreads();
#pragma unroll
        for (int ks = 0; ks < 4; ++ks) {
            int kb = ks * 64 + quad * 16;  // byte offset into 256 B row
            short8 a0 = *(const short8*)((const char*)As + (wm * 32 + mrow) * 256 + kb);
            short8 a1 = *(const short8*)((const char*)As + (wm * 32 + 16 + mrow) * 256 + kb);
            short8 b[4];
#pragma unroll
            for (int nt = 0; nt < 4; ++nt)
                b[nt] = *(const short8*)((const char*)Bs + (wn * 64 + nt * 16 + mrow) * 256 + kb);
#pragma unroll
            for (int nt = 0; nt < 4; ++nt) {
                acc[0][nt] = __builtin_amdgcn_mfma_f32_16x16x32_bf16(a0, b[nt], acc[0][nt], 0, 0, 0);
                acc[1][nt] = __builtin_amdgcn_mfma_f32_16x16x32_bf16(a1, b[nt], acc[1][nt], 0, 0, 0);
            }
        }
        __syncthreads();
    }

    // epilogue: C/D layout col=lane&15, row=quad*4+reg
#pragma unroll
    for (int mt = 0; mt < 2; ++mt)
#pragma unroll
        for (int nt = 0; nt < 4; ++nt) {
            int col = wn * 64 + nt * 16 + mrow;
            float bb = bias_s[col];
#pragma unroll
            for (int r = 0; r < 4; ++r) {
                int row = row0 + wm * 32 + mt * 16 + quad * 4 + r;
                if (row >= N_NODES) continue;
                float v = acc[mt][nt][r] + bb;
                if (relu) v = fmaxf(v, 0.f);
                unsigned short hi = f2bf(v);
                xh[(size_t)row * C + col] = hi;
                xl[(size_t)row * C + col] = f2bf(v - bf2f(hi));
            }
        }
}

// ---------------------------------------------------------------------------
// Head: out = x @ head_w + head_b   [N,128] @ [128,16]
// ---------------------------------------------------------------------------
__global__ __launch_bounds__(256) void head_kernel(
    const unsigned short* __restrict__ xh, const unsigned short* __restrict__ xl,
    const float* __restrict__ hw, const float* __restrict__ hb,
    float* __restrict__ out)
{
    __shared__ float w[C * OUT_DIM];
    __shared__ float b[OUT_DIM];
    for (int i = threadIdx.x; i < C * OUT_DIM; i += blockDim.x) w[i] = hw[i];
    if (threadIdx.x < OUT_DIM) b[threadIdx.x] = hb[threadIdx.x];
    __syncthreads();

    int node = blockIdx.x * 16 + (threadIdx.x >> 4);
    int c = threadIdx.x & 15;
    if (node >= N_NODES) return;
    float acc = b[c];
    const unsigned short* xrh = xh + (size_t)node * C;
    const unsigned short* xrl = xl + (size_t)node * C;
#pragma unroll 8
    for (int k = 0; k < C; ++k)
        acc += (bf2f(xrh[k]) + bf2f(xrl[k])) * w[k * OUT_DIM + c];
    out[(size_t)node * OUT_DIM + c] = acc;
}

// ---------------------------------------------------------------------------
extern "C" void kernel_launch(void* const* d_in, const int* in_sizes, int n_in,
                              void* d_out, int out_size, void* d_ws, size_t ws_size,
                              hipStream_t stream)
{
    const float* feats0 = (const float*)d_in[0];
    const float* feats1 = (const float*)d_in[1];
    const float* enc_w0 = (const float*)d_in[2];
    const float* enc_b0 = (const float*)d_in[3];
    const float* enc_w1 = (const float*)d_in[4];
    const float* enc_b1 = (const float*)d_in[5];
    const float* w_self0 = (const float*)d_in[6];
    const float* w_neigh0 = (const float*)d_in[7];
    const float* b0 = (const float*)d_in[8];
    const float* w_self1 = (const float*)d_in[9];
    const float* w_neigh1 = (const float*)d_in[10];
    const float* b1 = (const float*)d_in[11];
    const float* head_w = (const float*)d_in[12];
    const float* head_b = (const float*)d_in[13];
    const int* node_row_idx = (const int*)d_in[14];
    const int* edge_index = (const int*)d_in[15];
    const int* e_src = edge_index;
    const int* e_dst = edge_index + N_EDGES;

    char* p = (char*)d_ws;
    unsigned short* xh = (unsigned short*)p;  p += (size_t)N_NODES * C * 2;
    unsigned short* xl = (unsigned short*)p;  p += (size_t)N_NODES * C * 2;
    unsigned short* ah = (unsigned short*)p;  p += (size_t)N_NODES * C * 2;
    unsigned short* al = (unsigned short*)p;  p += (size_t)N_NODES * C * 2;
    unsigned short* BT0 = (unsigned short*)p; p += (size_t)128 * 768 * 2;
    unsigned short* BT1 = (unsigned short*)p; p += (size_t)128 * 768 * 2;
    float* deg = (float*)p;      p += (size_t)N_NODES * 4;
    int* counts = (int*)p;       p += (size_t)N_NODES * 4;
    int* offsets = (int*)p;      p += (size_t)(N_NODES + 8) * 4;
    int* cursor = (int*)p;       p += (size_t)N_NODES * 4;
    int* blk_sums = (int*)p;     p += (size_t)(SCAN_BLOCKS + 8) * 4;
    int* src_sorted = (int*)p;   p += (size_t)N_EDGES * 4;

    hipMemsetAsync(counts, 0, (size_t)N_NODES * sizeof(int), stream);

    encode_kernel<<<1024, 128, 0, stream>>>(feats0, feats1, enc_w0, enc_b0,
                                            enc_w1, enc_b1, node_row_idx, xh, xl);
    prep_weights<<<(2 * 128 * 768 + 255) / 256, 256, 0, stream>>>(
        w_self0, w_neigh0, w_self1, w_neigh1, BT0, BT1);

    hist_kernel<<<(N_EDGES + 255) / 256, 256, 0, stream>>>(e_dst, counts);
    scan1_kernel<<<SCAN_BLOCKS, 256, 0, stream>>>(counts, offsets, blk_sums);
    scan2_kernel<<<1, 256, 0, stream>>>(blk_sums);
    scan3_kernel<<<SCAN_BLOCKS, 256, 0, stream>>>(counts, blk_sums, offsets,
                                                  cursor, deg);
    scatter_kernel<<<(N_EDGES + 255) / 256, 256, 0, stream>>>(
        e_src, e_dst, cursor, src_sorted);

    // Layer 0
    aggregate_kernel<<<(N_NODES * 64 + 255) / 256, 256, 0, stream>>>(
        xh, xl, offsets, src_sorted, deg, ah, al);
    gemm_mfma<<<(N_NODES + BM - 1) / BM, 256, 0, stream>>>(
        xh, xl, ah, al, BT0, b0, 1);

    // Layer 1
    aggregate_kernel<<<(N_NODES * 64 + 255) / 256, 256, 0, stream>>>(
        xh, xl, offsets, src_sorted, deg, ah, al);
    gemm_mfma<<<(N_NODES + BM - 1) / BM, 256, 0, stream>>>(
        xh, xl, ah, al, BT1, b1, 0);

    head_kernel<<<(N_NODES + 15) / 16, 256, 0, stream>>>(xh, xl, head_w, head_b,
                                                         (float*)d_out);
}

// Round 4
// 467.882 us; speedup vs baseline: 1.6833x; 1.1279x over previous
//
#include <hip/hip_runtime.h>
#include <hip/hip_bf16.h>

#define N_NODES 50000
#define N_EDGES 800000
#define C 128
#define D_IN 32
#define T0 25000
#define OUT_DIM 16
#define SCAN_BLOCKS ((N_NODES + 255) / 256)   // 196

// Interleaved row layout for node features ("xc"/"ac"): 512 B per row,
// 32 units of 16 B: unit 2j = bf16 hi of channels 8j..8j+7,
//                   unit 2j+1 = bf16 lo of channels 8j..8j+7.
// slot s (0..255) = unit (s>>3), within (s&7); channel(s) = ((s>>4)*8)+(s&7).

typedef __attribute__((ext_vector_type(8))) short short8;
typedef __attribute__((ext_vector_type(4))) float f32x4;

__device__ __forceinline__ unsigned short f2bf(float f) {
    union { float f; unsigned int i; } u; u.f = f;
    unsigned int x = u.i;
    unsigned int r = x + 0x7fffu + ((x >> 16) & 1u);
    return (unsigned short)(r >> 16);
}
__device__ __forceinline__ float bf2f(unsigned short h) {
    union { unsigned int i; float f; } u; u.i = ((unsigned int)h) << 16;
    return u.f;
}
__device__ __forceinline__ void async16(void* lds, const void* g) {
    __builtin_amdgcn_global_load_lds(
        (const __attribute__((address_space(1))) void*)g,
        (__attribute__((address_space(3))) void*)lds, 16, 0, 0);
}
__device__ __forceinline__ size_t hi_off(int row, int c) {
    return (size_t)row * 512 + 32 * (size_t)(c >> 3) + 2 * (c & 7);
}

// ---------------------------------------------------------------------------
// Encode: x[n,:] = feats_tbl(row) @ enc_w + enc_b -> interleaved hi/lo row
// ---------------------------------------------------------------------------
__global__ __launch_bounds__(128) void encode_kernel(
    const float* __restrict__ feats0, const float* __restrict__ feats1,
    const float* __restrict__ w0, const float* __restrict__ b0,
    const float* __restrict__ w1, const float* __restrict__ b1,
    const int* __restrict__ row_idx, char* __restrict__ xc)
{
    __shared__ float sw0[D_IN * C];
    __shared__ float sw1[D_IN * C];
    __shared__ float sb0[C];
    __shared__ float sb1[C];
    for (int i = threadIdx.x; i < D_IN * C; i += blockDim.x) {
        sw0[i] = w0[i];
        sw1[i] = w1[i];
    }
    if (threadIdx.x < C) {
        sb0[threadIdx.x] = b0[threadIdx.x];
        sb1[threadIdx.x] = b1[threadIdx.x];
    }
    __syncthreads();

    int c = threadIdx.x;  // 0..127
    for (int n = blockIdx.x; n < N_NODES; n += gridDim.x) {
        int r = row_idx[n];  // block-uniform
        const float* f = (r < T0) ? (feats0 + (size_t)r * D_IN)
                                  : (feats1 + (size_t)(r - T0) * D_IN);
        const float* W = (r < T0) ? sw0 : sw1;
        float acc = (r < T0) ? sb0[c] : sb1[c];
#pragma unroll
        for (int k = 0; k < D_IN; ++k)
            acc += f[k] * W[k * C + c];
        unsigned short hi = f2bf(acc);
        size_t o = hi_off(n, c);
        *(unsigned short*)(xc + o) = hi;
        *(unsigned short*)(xc + o + 16) = f2bf(acc - bf2f(hi));
    }
}

// ---------------------------------------------------------------------------
// Weight prep: BT[layer][n][k], k in [0,1024), 4 segments of 256 slots:
//   seg0: hi(Wself)  seg1: hi(Wneigh)  seg2: lo(Wself)  seg3: lo(Wneigh)
// Slot->channel uses the interleaved A layout; B value is independent of
// the slot's hi/lo kind (hi-slot carries x_hi, lo-slot x_lo; both x W).
// ---------------------------------------------------------------------------
__global__ __launch_bounds__(256) void prep_weights(
    const float* __restrict__ ws0, const float* __restrict__ wn0,
    const float* __restrict__ ws1, const float* __restrict__ wn1,
    unsigned short* __restrict__ BT0, unsigned short* __restrict__ BT1)
{
    int idx = blockIdx.x * 256 + threadIdx.x;
    if (idx >= 2 * 128 * 1024) return;
    int lyr = idx >> 17;
    int rem = idx & 131071;
    int n = rem >> 10;        // 0..127
    int k = rem & 1023;
    int seg = k >> 8;         // 0..3
    int slot = k & 255;
    int channel = ((slot >> 4) * 8) + (slot & 7);
    const float* W = (lyr == 0) ? ((seg & 1) ? wn0 : ws0)
                                : ((seg & 1) ? wn1 : ws1);
    float v = W[channel * 128 + n];
    unsigned short hi = f2bf(v);
    unsigned short out = (seg < 2) ? hi : f2bf(v - bf2f(hi));
    (lyr == 0 ? BT0 : BT1)[(size_t)n * 1024 + k] = out;
}

// ---------------------------------------------------------------------------
// CSR build: histogram -> hierarchical scan (3 small kernels) -> scatter
// ---------------------------------------------------------------------------
__global__ __launch_bounds__(256) void hist_kernel(const int* __restrict__ dst,
                                                   int* __restrict__ counts)
{
    int i = blockIdx.x * blockDim.x + threadIdx.x;
    if (i < N_EDGES) atomicAdd(&counts[dst[i]], 1);
}

__global__ __launch_bounds__(256) void scan1_kernel(
    const int* __restrict__ counts, int* __restrict__ offsets,
    int* __restrict__ blk_sums)
{
    __shared__ int ws[4];
    int i = blockIdx.x * 256 + threadIdx.x;
    int c = (i < N_NODES) ? counts[i] : 0;
    int lane = threadIdx.x & 63, wid = threadIdx.x >> 6;
    int v = c;
#pragma unroll
    for (int off = 1; off < 64; off <<= 1) {
        int t = __shfl_up(v, off, 64);
        if (lane >= off) v += t;
    }
    if (lane == 63) ws[wid] = v;
    __syncthreads();
    if (threadIdx.x == 0) {
        int run = 0;
#pragma unroll
        for (int j = 0; j < 4; ++j) { int t = ws[j]; ws[j] = run; run += t; }
        blk_sums[blockIdx.x] = run;
    }
    __syncthreads();
    if (i < N_NODES) offsets[i] = ws[wid] + (v - c);
}

__global__ __launch_bounds__(256) void scan2_kernel(int* __restrict__ blk_sums)
{
    __shared__ int ws[4];
    int t = threadIdx.x;
    int c = (t < SCAN_BLOCKS) ? blk_sums[t] : 0;
    int lane = t & 63, wid = t >> 6;
    int v = c;
#pragma unroll
    for (int off = 1; off < 64; off <<= 1) {
        int s = __shfl_up(v, off, 64);
        if (lane >= off) v += s;
    }
    if (lane == 63) ws[wid] = v;
    __syncthreads();
    if (t == 0) {
        int run = 0;
#pragma unroll
        for (int j = 0; j < 4; ++j) { int s = ws[j]; ws[j] = run; run += s; }
    }
    __syncthreads();
    if (t < SCAN_BLOCKS) blk_sums[t] = ws[wid] + (v - c);
}

__global__ __launch_bounds__(256) void scan3_kernel(
    const int* __restrict__ counts, const int* __restrict__ blk_sums,
    int* __restrict__ offsets, int* __restrict__ cursor,
    float* __restrict__ deg)
{
    int i = blockIdx.x * 256 + threadIdx.x;
    if (i == 0) offsets[N_NODES] = N_EDGES;
    if (i >= N_NODES) return;
    int o = offsets[i] + blk_sums[blockIdx.x];
    offsets[i] = o;
    cursor[i] = o;
    int cnt = counts[i];
    deg[i] = (float)(cnt > 0 ? cnt : 1);
}

__global__ __launch_bounds__(256) void scatter_kernel(
    const int* __restrict__ src, const int* __restrict__ dst,
    int* __restrict__ cursor, int* __restrict__ src_sorted)
{
    int i = blockIdx.x * blockDim.x + threadIdx.x;
    if (i < N_EDGES) {
        int pos = atomicAdd(&cursor[dst[i]], 1);
        src_sorted[pos] = src[i];
    }
}

// ---------------------------------------------------------------------------
// Aggregate: one wave per dst node. Each lane loads ONE uint2 (8 B) per edge
// (4 bf16 of one kind); 4x unrolled for MLP. hi/lo kinds combined at the end
// with shfl_xor(2); output stored coalesced in the same interleaved layout.
// ---------------------------------------------------------------------------
__global__ __launch_bounds__(256) void aggregate_kernel(
    const char* __restrict__ xc, const int* __restrict__ offsets,
    const int* __restrict__ src_sorted, const float* __restrict__ deg,
    char* __restrict__ ac)
{
    int wave = (blockIdx.x * blockDim.x + threadIdx.x) >> 6;
    int lane = threadIdx.x & 63;
    if (wave >= N_NODES) return;
    int beg = offsets[wave];
    int end = offsets[wave + 1];
    float a0 = 0.f, a1 = 0.f, a2 = 0.f, a3 = 0.f;
    int e = beg;
    for (; e + 4 <= end; e += 4) {
        int s0 = src_sorted[e];
        int s1 = src_sorted[e + 1];
        int s2 = src_sorted[e + 2];
        int s3 = src_sorted[e + 3];
        uint2 v0 = *(const uint2*)(xc + (size_t)s0 * 512 + lane * 8);
        uint2 v1 = *(const uint2*)(xc + (size_t)s1 * 512 + lane * 8);
        uint2 v2 = *(const uint2*)(xc + (size_t)s2 * 512 + lane * 8);
        uint2 v3 = *(const uint2*)(xc + (size_t)s3 * 512 + lane * 8);
        a0 += bf2f((unsigned short)(v0.x & 0xffffu)) + bf2f((unsigned short)(v1.x & 0xffffu))
            + bf2f((unsigned short)(v2.x & 0xffffu)) + bf2f((unsigned short)(v3.x & 0xffffu));
        a1 += bf2f((unsigned short)(v0.x >> 16)) + bf2f((unsigned short)(v1.x >> 16))
            + bf2f((unsigned short)(v2.x >> 16)) + bf2f((unsigned short)(v3.x >> 16));
        a2 += bf2f((unsigned short)(v0.y & 0xffffu)) + bf2f((unsigned short)(v1.y & 0xffffu))
            + bf2f((unsigned short)(v2.y & 0xffffu)) + bf2f((unsigned short)(v3.y & 0xffffu));
        a3 += bf2f((unsigned short)(v0.y >> 16)) + bf2f((unsigned short)(v1.y >> 16))
            + bf2f((unsigned short)(v2.y >> 16)) + bf2f((unsigned short)(v3.y >> 16));
    }
    for (; e < end; ++e) {
        int s = src_sorted[e];
        uint2 v = *(const uint2*)(xc + (size_t)s * 512 + lane * 8);
        a0 += bf2f((unsigned short)(v.x & 0xffffu));
        a1 += bf2f((unsigned short)(v.x >> 16));
        a2 += bf2f((unsigned short)(v.y & 0xffffu));
        a3 += bf2f((unsigned short)(v.y >> 16));
    }
    // combine hi-kind + lo-kind partial sums (partner lane = lane^2)
    float inv = 1.0f / deg[wave];
    float t0 = (a0 + __shfl_xor(a0, 2)) * inv;
    float t1 = (a1 + __shfl_xor(a1, 2)) * inv;
    float t2 = (a2 + __shfl_xor(a2, 2)) * inv;
    float t3 = (a3 + __shfl_xor(a3, 2)) * inv;
    unsigned short h0 = f2bf(t0), h1 = f2bf(t1), h2 = f2bf(t2), h3 = f2bf(t3);
    unsigned short o0, o1, o2, o3;
    if ((lane & 2) == 0) {  // hi-kind lane
        o0 = h0; o1 = h1; o2 = h2; o3 = h3;
    } else {                // lo-kind lane
        o0 = f2bf(t0 - bf2f(h0)); o1 = f2bf(t1 - bf2f(h1));
        o2 = f2bf(t2 - bf2f(h2)); o3 = f2bf(t3 - bf2f(h3));
    }
    uint2 outp;
    outp.x = (unsigned int)o0 | ((unsigned int)o1 << 16);
    outp.y = (unsigned int)o2 | ((unsigned int)o3 << 16);
    *(uint2*)(ac + (size_t)wave * 512 + lane * 8) = outp;
}

// ---------------------------------------------------------------------------
// Layer GEMM via split-bf16 MFMA, K = 1024 in 8 chunks of 128 slots:
//   A chunks: [xc0 xc1 ac0 ac1 xc0 xc1 ac0 ac1]  (interleaved hi/lo rows)
//   B = BT [n=128][k=1024], k-order matches A slot order.
// Block: 256 thr, tile 64 rows x 128 cols, mfma 16x16x32 bf16. In-place xc.
// ---------------------------------------------------------------------------
#define BM 64
__global__ __launch_bounds__(256) void gemm_mfma(
    char* __restrict__ xc, const char* __restrict__ ac,
    const unsigned short* __restrict__ BT, const float* __restrict__ bias,
    int relu)
{
    __shared__ unsigned short As[64 * 128];   // [row][128 slots] 16 KB, 256 B/row
    __shared__ unsigned short Bs[128 * 128];  // [n][128 slots]   32 KB, 256 B/row
    __shared__ float bias_s[C];

    int tid = threadIdx.x;
    int w = tid >> 6, l = tid & 63;
    int row0 = blockIdx.x * BM;
    if (tid < C) bias_s[tid] = bias[tid];

    f32x4 acc[2][4];
#pragma unroll
    for (int mt = 0; mt < 2; ++mt)
#pragma unroll
        for (int nt = 0; nt < 4; ++nt)
            acc[mt][nt] = (f32x4)(0.f);

    int wm = w & 1;
    int wn = w >> 1;
    int quad = l >> 4;
    int mrow = l & 15;

    for (int c = 0; c < 8; ++c) {
        const char* abase = (c & 2) ? ac : xc;
        int coloff = (c & 1) * 256;
        // --- stage A (16 KB): row chunk is contiguous 256 B in global ---
#pragma unroll
        for (int i = 0; i < 4; ++i) {
            int off = w * 4096 + i * 1024 + l * 16;
            int row = row0 + (off >> 8);
            if (row > N_NODES - 1) row = N_NODES - 1;
            const char* g = abase + (size_t)row * 512 + coloff + (off & 255);
            async16((char*)As + off, g);
        }
        // --- stage B (32 KB): BT row stride 2048 B ---
#pragma unroll
        for (int i = 0; i < 8; ++i) {
            int off = w * 8192 + i * 1024 + l * 16;
            int n = off >> 8;
            const char* g = (const char*)BT + (size_t)n * 2048 + c * 256 + (off & 255);
            async16((char*)Bs + off, g);
        }
        __syncthreads();
#pragma unroll
        for (int ks = 0; ks < 4; ++ks) {
            int kb = ks * 64 + quad * 16;
            short8 a0 = *(const short8*)((const char*)As + (wm * 32 + mrow) * 256 + kb);
            short8 a1 = *(const short8*)((const char*)As + (wm * 32 + 16 + mrow) * 256 + kb);
            short8 b[4];
#pragma unroll
            for (int nt = 0; nt < 4; ++nt)
                b[nt] = *(const short8*)((const char*)Bs + (wn * 64 + nt * 16 + mrow) * 256 + kb);
#pragma unroll
            for (int nt = 0; nt < 4; ++nt) {
                acc[0][nt] = __builtin_amdgcn_mfma_f32_16x16x32_bf16(a0, b[nt], acc[0][nt], 0, 0, 0);
                acc[1][nt] = __builtin_amdgcn_mfma_f32_16x16x32_bf16(a1, b[nt], acc[1][nt], 0, 0, 0);
            }
        }
        __syncthreads();
    }

    // epilogue: C/D layout col=lane&15, row=quad*4+reg; write interleaved
#pragma unroll
    for (int mt = 0; mt < 2; ++mt)
#pragma unroll
        for (int nt = 0; nt < 4; ++nt) {
            int col = wn * 64 + nt * 16 + mrow;
            float bb = bias_s[col];
#pragma unroll
            for (int r = 0; r < 4; ++r) {
                int row = row0 + wm * 32 + mt * 16 + quad * 4 + r;
                if (row >= N_NODES) continue;
                float v = acc[mt][nt][r] + bb;
                if (relu) v = fmaxf(v, 0.f);
                unsigned short hi = f2bf(v);
                size_t o = hi_off(row, col);
                *(unsigned short*)(xc + o) = hi;
                *(unsigned short*)(xc + o + 16) = f2bf(v - bf2f(hi));
            }
        }
}

// ---------------------------------------------------------------------------
// Head: out = x @ head_w + head_b   [N,128] @ [128,16]
// ---------------------------------------------------------------------------
__global__ __launch_bounds__(256) void head_kernel(
    const char* __restrict__ xc, const float* __restrict__ hw,
    const float* __restrict__ hb, float* __restrict__ out)
{
    __shared__ float w[C * OUT_DIM];
    __shared__ float b[OUT_DIM];
    for (int i = threadIdx.x; i < C * OUT_DIM; i += blockDim.x) w[i] = hw[i];
    if (threadIdx.x < OUT_DIM) b[threadIdx.x] = hb[threadIdx.x];
    __syncthreads();

    int node = blockIdx.x * 16 + (threadIdx.x >> 4);
    int c = threadIdx.x & 15;
    if (node >= N_NODES) return;
    float acc = b[c];
    const char* xr = xc + (size_t)node * 512;
#pragma unroll 8
    for (int k = 0; k < C; ++k) {
        size_t o = 32 * (size_t)(k >> 3) + 2 * (k & 7);
        float v = bf2f(*(const unsigned short*)(xr + o))
                + bf2f(*(const unsigned short*)(xr + o + 16));
        acc += v * w[k * OUT_DIM + c];
    }
    out[(size_t)node * OUT_DIM + c] = acc;
}

// ---------------------------------------------------------------------------
extern "C" void kernel_launch(void* const* d_in, const int* in_sizes, int n_in,
                              void* d_out, int out_size, void* d_ws, size_t ws_size,
                              hipStream_t stream)
{
    const float* feats0 = (const float*)d_in[0];
    const float* feats1 = (const float*)d_in[1];
    const float* enc_w0 = (const float*)d_in[2];
    const float* enc_b0 = (const float*)d_in[3];
    const float* enc_w1 = (const float*)d_in[4];
    const float* enc_b1 = (const float*)d_in[5];
    const float* w_self0 = (const float*)d_in[6];
    const float* w_neigh0 = (const float*)d_in[7];
    const float* b0 = (const float*)d_in[8];
    const float* w_self1 = (const float*)d_in[9];
    const float* w_neigh1 = (const float*)d_in[10];
    const float* b1 = (const float*)d_in[11];
    const float* head_w = (const float*)d_in[12];
    const float* head_b = (const float*)d_in[13];
    const int* node_row_idx = (const int*)d_in[14];
    const int* edge_index = (const int*)d_in[15];
    const int* e_src = edge_index;
    const int* e_dst = edge_index + N_EDGES;

    char* p = (char*)d_ws;
    char* xc = p;                 p += (size_t)N_NODES * 512;
    char* ac = p;                 p += (size_t)N_NODES * 512;
    unsigned short* BT0 = (unsigned short*)p; p += (size_t)128 * 1024 * 2;
    unsigned short* BT1 = (unsigned short*)p; p += (size_t)128 * 1024 * 2;
    float* deg = (float*)p;      p += (size_t)N_NODES * 4;
    int* counts = (int*)p;       p += (size_t)N_NODES * 4;
    int* offsets = (int*)p;      p += (size_t)(N_NODES + 8) * 4;
    int* cursor = (int*)p;       p += (size_t)N_NODES * 4;
    int* blk_sums = (int*)p;     p += (size_t)(SCAN_BLOCKS + 8) * 4;
    int* src_sorted = (int*)p;   p += (size_t)N_EDGES * 4;

    hipMemsetAsync(counts, 0, (size_t)N_NODES * sizeof(int), stream);

    encode_kernel<<<1024, 128, 0, stream>>>(feats0, feats1, enc_w0, enc_b0,
                                            enc_w1, enc_b1, node_row_idx, xc);
    prep_weights<<<(2 * 128 * 1024 + 255) / 256, 256, 0, stream>>>(
        w_self0, w_neigh0, w_self1, w_neigh1, BT0, BT1);

    hist_kernel<<<(N_EDGES + 255) / 256, 256, 0, stream>>>(e_dst, counts);
    scan1_kernel<<<SCAN_BLOCKS, 256, 0, stream>>>(counts, offsets, blk_sums);
    scan2_kernel<<<1, 256, 0, stream>>>(blk_sums);
    scan3_kernel<<<SCAN_BLOCKS, 256, 0, stream>>>(counts, blk_sums, offsets,
                                                  cursor, deg);
    scatter_kernel<<<(N_EDGES + 255) / 256, 256, 0, stream>>>(
        e_src, e_dst, cursor, src_sorted);

    // Layer 0
    aggregate_kernel<<<(N_NODES * 64 + 255) / 256, 256, 0, stream>>>(
        xc, offsets, src_sorted, deg, ac);
    gemm_mfma<<<(N_NODES + BM - 1) / BM, 256, 0, stream>>>(xc, ac, BT0, b0, 1);

    // Layer 1
    aggregate_kernel<<<(N_NODES * 64 + 255) / 256, 256, 0, stream>>>(
        xc, offsets, src_sorted, deg, ac);
    gemm_mfma<<<(N_NODES + BM - 1) / BM, 256, 0, stream>>>(xc, ac, BT1, b1, 0);

    head_kernel<<<(N_NODES + 15) / 16, 256, 0, stream>>>(xc, head_w, head_b,
                                                         (float*)d_out);
}

// Round 5
// 386.104 us; speedup vs baseline: 2.0399x; 1.2118x over previous
//
#include <hip/hip_runtime.h>
#include <hip/hip_bf16.h>

#define N_NODES 50000
#define N_EDGES 800000
#define C 128
#define D_IN 32
#define T0 25000
#define OUT_DIM 16
#define SCAN_BLOCKS ((N_NODES + 255) / 256)   // 196

// Interleaved row layout for node features ("xc"/"ac"): 512 B per row,
// 32 units of 16 B: unit 2j = bf16 hi of channels 8j..8j+7,
//                   unit 2j+1 = bf16 lo of channels 8j..8j+7.

typedef __attribute__((ext_vector_type(8))) short short8;
typedef __attribute__((ext_vector_type(4))) float f32x4;

__device__ __forceinline__ unsigned short f2bf(float f) {
    union { float f; unsigned int i; } u; u.f = f;
    unsigned int x = u.i;
    unsigned int r = x + 0x7fffu + ((x >> 16) & 1u);
    return (unsigned short)(r >> 16);
}
__device__ __forceinline__ float bf2f(unsigned short h) {
    union { unsigned int i; float f; } u; u.i = ((unsigned int)h) << 16;
    return u.f;
}
__device__ __forceinline__ void async16(void* lds, const void* g) {
    __builtin_amdgcn_global_load_lds(
        (const __attribute__((address_space(1))) void*)g,
        (__attribute__((address_space(3))) void*)lds, 16, 0, 0);
}

// ---------------------------------------------------------------------------
// Encode: 16 threads per node, 8 consecutive channels per thread ->
// one short8 hi-unit + one short8 lo-unit store (coalesced 512 B rows).
// ---------------------------------------------------------------------------
__global__ __launch_bounds__(256) void encode_kernel(
    const float* __restrict__ feats0, const float* __restrict__ feats1,
    const float* __restrict__ w0, const float* __restrict__ b0,
    const float* __restrict__ w1, const float* __restrict__ b1,
    const int* __restrict__ row_idx, char* __restrict__ xc)
{
    __shared__ float sw0[D_IN * C];
    __shared__ float sw1[D_IN * C];
    __shared__ float sb0[C];
    __shared__ float sb1[C];
    for (int i = threadIdx.x; i < D_IN * C; i += blockDim.x) {
        sw0[i] = w0[i];
        sw1[i] = w1[i];
    }
    if (threadIdx.x < C) {
        sb0[threadIdx.x] = b0[threadIdx.x];
        sb1[threadIdx.x] = b1[threadIdx.x];
    }
    __syncthreads();

    int j = threadIdx.x & 15;        // unit pair: channels 8j..8j+7
    int ln = threadIdx.x >> 4;       // 0..15 local node
    for (int n = blockIdx.x * 16 + ln; n < N_NODES; n += gridDim.x * 16) {
        int r = row_idx[n];
        const float* f = (r < T0) ? (feats0 + (size_t)r * D_IN)
                                  : (feats1 + (size_t)(r - T0) * D_IN);
        const float* W = (r < T0) ? sw0 : sw1;
        const float* B = (r < T0) ? sb0 : sb1;
        float4 f4[8];
#pragma unroll
        for (int i = 0; i < 8; ++i) f4[i] = ((const float4*)f)[i];
        float acc[8];
#pragma unroll
        for (int cc = 0; cc < 8; ++cc) acc[cc] = B[8 * j + cc];
#pragma unroll
        for (int k = 0; k < D_IN; ++k) {
            float fk = ((const float*)f4)[k];
            float4 wa = *(const float4*)&W[k * C + 8 * j];
            float4 wb = *(const float4*)&W[k * C + 8 * j + 4];
            acc[0] += fk * wa.x; acc[1] += fk * wa.y;
            acc[2] += fk * wa.z; acc[3] += fk * wa.w;
            acc[4] += fk * wb.x; acc[5] += fk * wb.y;
            acc[6] += fk * wb.z; acc[7] += fk * wb.w;
        }
        short8 h8, l8;
#pragma unroll
        for (int cc = 0; cc < 8; ++cc) {
            unsigned short hi = f2bf(acc[cc]);
            h8[cc] = (short)hi;
            l8[cc] = (short)f2bf(acc[cc] - bf2f(hi));
        }
        char* base = xc + (size_t)n * 512 + 32 * j;
        *(short8*)base = h8;
        *(short8*)(base + 16) = l8;
    }
}

// ---------------------------------------------------------------------------
// Weight prep: BT[layer][n][k], k in [0,1024), 4 segments of 256 slots:
//   seg0: hi(Wself)  seg1: hi(Wneigh)  seg2: lo(Wself)  seg3: lo(Wneigh)
// ---------------------------------------------------------------------------
__global__ __launch_bounds__(256) void prep_weights(
    const float* __restrict__ ws0, const float* __restrict__ wn0,
    const float* __restrict__ ws1, const float* __restrict__ wn1,
    unsigned short* __restrict__ BT0, unsigned short* __restrict__ BT1)
{
    int idx = blockIdx.x * 256 + threadIdx.x;
    if (idx >= 2 * 128 * 1024) return;
    int lyr = idx >> 17;
    int rem = idx & 131071;
    int n = rem >> 10;        // 0..127
    int k = rem & 1023;
    int seg = k >> 8;         // 0..3
    int slot = k & 255;
    int channel = ((slot >> 4) * 8) + (slot & 7);
    const float* W = (lyr == 0) ? ((seg & 1) ? wn0 : ws0)
                                : ((seg & 1) ? wn1 : ws1);
    float v = W[channel * 128 + n];
    unsigned short hi = f2bf(v);
    unsigned short out = (seg < 2) ? hi : f2bf(v - bf2f(hi));
    (lyr == 0 ? BT0 : BT1)[(size_t)n * 1024 + k] = out;
}

// ---------------------------------------------------------------------------
// CSR build: histogram -> hierarchical scan -> scatter
// ---------------------------------------------------------------------------
__global__ __launch_bounds__(256) void hist_kernel(const int* __restrict__ dst,
                                                   int* __restrict__ counts)
{
    int i = blockIdx.x * blockDim.x + threadIdx.x;
    if (i < N_EDGES) atomicAdd(&counts[dst[i]], 1);
}

__global__ __launch_bounds__(256) void scan1_kernel(
    const int* __restrict__ counts, int* __restrict__ offsets,
    int* __restrict__ blk_sums)
{
    __shared__ int ws[4];
    int i = blockIdx.x * 256 + threadIdx.x;
    int c = (i < N_NODES) ? counts[i] : 0;
    int lane = threadIdx.x & 63, wid = threadIdx.x >> 6;
    int v = c;
#pragma unroll
    for (int off = 1; off < 64; off <<= 1) {
        int t = __shfl_up(v, off, 64);
        if (lane >= off) v += t;
    }
    if (lane == 63) ws[wid] = v;
    __syncthreads();
    if (threadIdx.x == 0) {
        int run = 0;
#pragma unroll
        for (int j = 0; j < 4; ++j) { int t = ws[j]; ws[j] = run; run += t; }
        blk_sums[blockIdx.x] = run;
    }
    __syncthreads();
    if (i < N_NODES) offsets[i] = ws[wid] + (v - c);
}

__global__ __launch_bounds__(256) void scan2_kernel(int* __restrict__ blk_sums)
{
    __shared__ int ws[4];
    int t = threadIdx.x;
    int c = (t < SCAN_BLOCKS) ? blk_sums[t] : 0;
    int lane = t & 63, wid = t >> 6;
    int v = c;
#pragma unroll
    for (int off = 1; off < 64; off <<= 1) {
        int s = __shfl_up(v, off, 64);
        if (lane >= off) v += s;
    }
    if (lane == 63) ws[wid] = v;
    __syncthreads();
    if (t == 0) {
        int run = 0;
#pragma unroll
        for (int j = 0; j < 4; ++j) { int s = ws[j]; ws[j] = run; run += s; }
    }
    __syncthreads();
    if (t < SCAN_BLOCKS) blk_sums[t] = ws[wid] + (v - c);
}

__global__ __launch_bounds__(256) void scan3_kernel(
    const int* __restrict__ counts, const int* __restrict__ blk_sums,
    int* __restrict__ offsets, int* __restrict__ cursor,
    float* __restrict__ deg)
{
    int i = blockIdx.x * 256 + threadIdx.x;
    if (i == 0) offsets[N_NODES] = N_EDGES;
    if (i >= N_NODES) return;
    int o = offsets[i] + blk_sums[blockIdx.x];
    offsets[i] = o;
    cursor[i] = o;
    int cnt = counts[i];
    deg[i] = (float)(cnt > 0 ? cnt : 1);
}

__global__ __launch_bounds__(256) void scatter_kernel(
    const int* __restrict__ src, const int* __restrict__ dst,
    int* __restrict__ cursor, int* __restrict__ src_sorted)
{
    int i = blockIdx.x * blockDim.x + threadIdx.x;
    if (i < N_EDGES) {
        int pos = atomicAdd(&cursor[dst[i]], 1);
        src_sorted[pos] = src[i];
    }
}

// ---------------------------------------------------------------------------
// Aggregate: one wave per dst node; 8 B per lane per edge, 4x unrolled;
// hi/lo kinds combined via shfl_xor(2); coalesced interleaved output.
// ---------------------------------------------------------------------------
__global__ __launch_bounds__(256) void aggregate_kernel(
    const char* __restrict__ xc, const int* __restrict__ offsets,
    const int* __restrict__ src_sorted, const float* __restrict__ deg,
    char* __restrict__ ac)
{
    int wave = (blockIdx.x * blockDim.x + threadIdx.x) >> 6;
    int lane = threadIdx.x & 63;
    if (wave >= N_NODES) return;
    int beg = offsets[wave];
    int end = offsets[wave + 1];
    float a0 = 0.f, a1 = 0.f, a2 = 0.f, a3 = 0.f;
    int e = beg;
    for (; e + 4 <= end; e += 4) {
        int s0 = src_sorted[e];
        int s1 = src_sorted[e + 1];
        int s2 = src_sorted[e + 2];
        int s3 = src_sorted[e + 3];
        uint2 v0 = *(const uint2*)(xc + (size_t)s0 * 512 + lane * 8);
        uint2 v1 = *(const uint2*)(xc + (size_t)s1 * 512 + lane * 8);
        uint2 v2 = *(const uint2*)(xc + (size_t)s2 * 512 + lane * 8);
        uint2 v3 = *(const uint2*)(xc + (size_t)s3 * 512 + lane * 8);
        a0 += bf2f((unsigned short)(v0.x & 0xffffu)) + bf2f((unsigned short)(v1.x & 0xffffu))
            + bf2f((unsigned short)(v2.x & 0xffffu)) + bf2f((unsigned short)(v3.x & 0xffffu));
        a1 += bf2f((unsigned short)(v0.x >> 16)) + bf2f((unsigned short)(v1.x >> 16))
            + bf2f((unsigned short)(v2.x >> 16)) + bf2f((unsigned short)(v3.x >> 16));
        a2 += bf2f((unsigned short)(v0.y & 0xffffu)) + bf2f((unsigned short)(v1.y & 0xffffu))
            + bf2f((unsigned short)(v2.y & 0xffffu)) + bf2f((unsigned short)(v3.y & 0xffffu));
        a3 += bf2f((unsigned short)(v0.y >> 16)) + bf2f((unsigned short)(v1.y >> 16))
            + bf2f((unsigned short)(v2.y >> 16)) + bf2f((unsigned short)(v3.y >> 16));
    }
    for (; e < end; ++e) {
        int s = src_sorted[e];
        uint2 v = *(const uint2*)(xc + (size_t)s * 512 + lane * 8);
        a0 += bf2f((unsigned short)(v.x & 0xffffu));
        a1 += bf2f((unsigned short)(v.x >> 16));
        a2 += bf2f((unsigned short)(v.y & 0xffffu));
        a3 += bf2f((unsigned short)(v.y >> 16));
    }
    float inv = 1.0f / deg[wave];
    float t0 = (a0 + __shfl_xor(a0, 2)) * inv;
    float t1 = (a1 + __shfl_xor(a1, 2)) * inv;
    float t2 = (a2 + __shfl_xor(a2, 2)) * inv;
    float t3 = (a3 + __shfl_xor(a3, 2)) * inv;
    unsigned short h0 = f2bf(t0), h1 = f2bf(t1), h2 = f2bf(t2), h3 = f2bf(t3);
    unsigned short o0, o1, o2, o3;
    if ((lane & 2) == 0) {
        o0 = h0; o1 = h1; o2 = h2; o3 = h3;
    } else {
        o0 = f2bf(t0 - bf2f(h0)); o1 = f2bf(t1 - bf2f(h1));
        o2 = f2bf(t2 - bf2f(h2)); o3 = f2bf(t3 - bf2f(h3));
    }
    uint2 outp;
    outp.x = (unsigned int)o0 | ((unsigned int)o1 << 16);
    outp.y = (unsigned int)o2 | ((unsigned int)o3 << 16);
    *(uint2*)(ac + (size_t)wave * 512 + lane * 8) = outp;
}

// ---------------------------------------------------------------------------
// Layer GEMM: 512 thr / 8 waves, tile 128x128, K=1024 in 8 chunks of 128.
// XOR-swizzled LDS (unit' = unit ^ (row&15)) -> conflict-free b128 reads;
// swizzle applied via per-lane global addresses in global_load_lds.
// Epilogue bounced through LDS for coalesced uint4 output. In-place xc.
// ---------------------------------------------------------------------------
#define BM 128
__global__ __launch_bounds__(512) void gemm_mfma(
    char* __restrict__ xc, const char* __restrict__ ac,
    const unsigned short* __restrict__ BT, const float* __restrict__ bias,
    int relu)
{
    __shared__ uint4 smem4[4096];           // 64 KB: As 32K | Bs 32K
    char* As = (char*)smem4;
    char* Bs = (char*)smem4 + 32768;
    __shared__ float bias_s[C];

    int tid = threadIdx.x;
    int w = tid >> 6, l = tid & 63;
    int row0 = blockIdx.x * BM;
    if (tid < C) bias_s[tid] = bias[tid];

    f32x4 acc[2][4];
#pragma unroll
    for (int mt = 0; mt < 2; ++mt)
#pragma unroll
        for (int nt = 0; nt < 4; ++nt)
            acc[mt][nt] = (f32x4)(0.f);

    int wm = w & 3;     // row quarter: rows [wm*32, wm*32+32)
    int wn = w >> 2;    // col half:    cols [wn*64, wn*64+64)
    int quad = l >> 4;
    int mrow = l & 15;

    for (int c = 0; c < 8; ++c) {
        const char* abase = (c & 2) ? ac : xc;
        int coloff = (c & 1) * 256;
        // --- stage A (32 KB), swizzled ---
#pragma unroll
        for (int i = 0; i < 4; ++i) {
            int off = i * 8192 + tid * 16;
            int rl = off >> 8;
            int row = row0 + rl;
            if (row > N_NODES - 1) row = N_NODES - 1;
            int u = ((off >> 4) & 15) ^ (rl & 15);
            const char* g = abase + (size_t)row * 512 + coloff + u * 16;
            async16(As + off, g);
        }
        // --- stage B (32 KB), swizzled; BT row stride 2048 B ---
#pragma unroll
        for (int i = 0; i < 4; ++i) {
            int off = i * 8192 + tid * 16;
            int n = off >> 8;
            int u = ((off >> 4) & 15) ^ (n & 15);
            const char* g = (const char*)BT + (size_t)n * 2048 + c * 256 + u * 16;
            async16(Bs + off, g);
        }
        __syncthreads();
#pragma unroll
        for (int ks = 0; ks < 4; ++ks) {
            int cu = ks * 4 + quad;             // unit 0..15
            int swz = (cu ^ mrow) * 16;
            short8 a0 = *(const short8*)(As + (wm * 32 + mrow) * 256 + swz);
            short8 a1 = *(const short8*)(As + (wm * 32 + 16 + mrow) * 256 + swz);
            short8 b[4];
#pragma unroll
            for (int nt = 0; nt < 4; ++nt)
                b[nt] = *(const short8*)(Bs + (wn * 64 + nt * 16 + mrow) * 256 + swz);
#pragma unroll
            for (int nt = 0; nt < 4; ++nt) {
                acc[0][nt] = __builtin_amdgcn_mfma_f32_16x16x32_bf16(a0, b[nt], acc[0][nt], 0, 0, 0);
                acc[1][nt] = __builtin_amdgcn_mfma_f32_16x16x32_bf16(a1, b[nt], acc[1][nt], 0, 0, 0);
            }
        }
        __syncthreads();
    }

    // epilogue: build interleaved tile in LDS, then coalesced uint4 copy-out
    char* tileb = (char*)smem4;
#pragma unroll
    for (int mt = 0; mt < 2; ++mt)
#pragma unroll
        for (int nt = 0; nt < 4; ++nt) {
            int col = wn * 64 + nt * 16 + mrow;
            float bb = bias_s[col];
#pragma unroll
            for (int r = 0; r < 4; ++r) {
                int rl = wm * 32 + mt * 16 + quad * 4 + r;
                float v = acc[mt][nt][r] + bb;
                if (relu) v = fmaxf(v, 0.f);
                unsigned short hi = f2bf(v);
                char* p = tileb + rl * 512 + 32 * (col >> 3) + 2 * (col & 7);
                *(unsigned short*)p = hi;
                *(unsigned short*)(p + 16) = f2bf(v - bf2f(hi));
            }
        }
    __syncthreads();
#pragma unroll
    for (int i = 0; i < 8; ++i) {
        int off = i * 8192 + tid * 16;
        int row = row0 + (off >> 9);
        if (row < N_NODES)
            *(uint4*)(xc + (size_t)row0 * 512 + off) = *(const uint4*)(tileb + off);
    }
}

// ---------------------------------------------------------------------------
// Head: out = x @ head_w + head_b   [N,128] @ [128,16]
// ---------------------------------------------------------------------------
__global__ __launch_bounds__(256) void head_kernel(
    const char* __restrict__ xc, const float* __restrict__ hw,
    const float* __restrict__ hb, float* __restrict__ out)
{
    __shared__ float w[C * OUT_DIM];
    __shared__ float b[OUT_DIM];
    for (int i = threadIdx.x; i < C * OUT_DIM; i += blockDim.x) w[i] = hw[i];
    if (threadIdx.x < OUT_DIM) b[threadIdx.x] = hb[threadIdx.x];
    __syncthreads();

    int node = blockIdx.x * 16 + (threadIdx.x >> 4);
    int c = threadIdx.x & 15;
    if (node >= N_NODES) return;
    float acc = b[c];
    const char* xr = xc + (size_t)node * 512;
#pragma unroll 8
    for (int k = 0; k < C; ++k) {
        size_t o = 32 * (size_t)(k >> 3) + 2 * (k & 7);
        float v = bf2f(*(const unsigned short*)(xr + o))
                + bf2f(*(const unsigned short*)(xr + o + 16));
        acc += v * w[k * OUT_DIM + c];
    }
    out[(size_t)node * OUT_DIM + c] = acc;
}

// ---------------------------------------------------------------------------
extern "C" void kernel_launch(void* const* d_in, const int* in_sizes, int n_in,
                              void* d_out, int out_size, void* d_ws, size_t ws_size,
                              hipStream_t stream)
{
    const float* feats0 = (const float*)d_in[0];
    const float* feats1 = (const float*)d_in[1];
    const float* enc_w0 = (const float*)d_in[2];
    const float* enc_b0 = (const float*)d_in[3];
    const float* enc_w1 = (const float*)d_in[4];
    const float* enc_b1 = (const float*)d_in[5];
    const float* w_self0 = (const float*)d_in[6];
    const float* w_neigh0 = (const float*)d_in[7];
    const float* b0 = (const float*)d_in[8];
    const float* w_self1 = (const float*)d_in[9];
    const float* w_neigh1 = (const float*)d_in[10];
    const float* b1 = (const float*)d_in[11];
    const float* head_w = (const float*)d_in[12];
    const float* head_b = (const float*)d_in[13];
    const int* node_row_idx = (const int*)d_in[14];
    const int* edge_index = (const int*)d_in[15];
    const int* e_src = edge_index;
    const int* e_dst = edge_index + N_EDGES;

    char* p = (char*)d_ws;
    char* xc = p;                 p += (size_t)N_NODES * 512;
    char* ac = p;                 p += (size_t)N_NODES * 512;
    unsigned short* BT0 = (unsigned short*)p; p += (size_t)128 * 1024 * 2;
    unsigned short* BT1 = (unsigned short*)p; p += (size_t)128 * 1024 * 2;
    float* deg = (float*)p;      p += (size_t)N_NODES * 4;
    int* counts = (int*)p;       p += (size_t)N_NODES * 4;
    int* offsets = (int*)p;      p += (size_t)(N_NODES + 8) * 4;
    int* cursor = (int*)p;       p += (size_t)N_NODES * 4;
    int* blk_sums = (int*)p;     p += (size_t)(SCAN_BLOCKS + 8) * 4;
    int* src_sorted = (int*)p;   p += (size_t)N_EDGES * 4;

    hipMemsetAsync(counts, 0, (size_t)N_NODES * sizeof(int), stream);

    encode_kernel<<<512, 256, 0, stream>>>(feats0, feats1, enc_w0, enc_b0,
                                           enc_w1, enc_b1, node_row_idx, xc);
    prep_weights<<<(2 * 128 * 1024 + 255) / 256, 256, 0, stream>>>(
        w_self0, w_neigh0, w_self1, w_neigh1, BT0, BT1);

    hist_kernel<<<(N_EDGES + 255) / 256, 256, 0, stream>>>(e_dst, counts);
    scan1_kernel<<<SCAN_BLOCKS, 256, 0, stream>>>(counts, offsets, blk_sums);
    scan2_kernel<<<1, 256, 0, stream>>>(blk_sums);
    scan3_kernel<<<SCAN_BLOCKS, 256, 0, stream>>>(counts, blk_sums, offsets,
                                                  cursor, deg);
    scatter_kernel<<<(N_EDGES + 255) / 256, 256, 0, stream>>>(
        e_src, e_dst, cursor, src_sorted);

    // Layer 0
    aggregate_kernel<<<(N_NODES * 64 + 255) / 256, 256, 0, stream>>>(
        xc, offsets, src_sorted, deg, ac);
    gemm_mfma<<<(N_NODES + BM - 1) / BM, 512, 0, stream>>>(xc, ac, BT0, b0, 1);

    // Layer 1
    aggregate_kernel<<<(N_NODES * 64 + 255) / 256, 256, 0, stream>>>(
        xc, offsets, src_sorted, deg, ac);
    gemm_mfma<<<(N_NODES + BM - 1) / BM, 512, 0, stream>>>(xc, ac, BT1, b1, 0);

    head_kernel<<<(N_NODES + 15) / 16, 256, 0, stream>>>(xc, head_w, head_b,
                                                         (float*)d_out);
}

// Round 6
// 383.847 us; speedup vs baseline: 2.0519x; 1.0059x over previous
//
#include <hip/hip_runtime.h>
#include <hip/hip_bf16.h>

#define N_NODES 50000
#define N_EDGES 800000
#define C 128
#define D_IN 32
#define T0 25000
#define OUT_DIM 16
#define SCAN_BLOCKS ((N_NODES + 255) / 256)   // 196

// Interleaved row layout for node features ("xc"/"ac"): 512 B per row,
// 32 units of 16 B: unit 2j = bf16 hi of channels 8j..8j+7,
//                   unit 2j+1 = bf16 lo of channels 8j..8j+7.

typedef __attribute__((ext_vector_type(8))) short short8;
typedef __attribute__((ext_vector_type(4))) float f32x4;

__device__ __forceinline__ unsigned short f2bf(float f) {
    union { float f; unsigned int i; } u; u.f = f;
    unsigned int x = u.i;
    unsigned int r = x + 0x7fffu + ((x >> 16) & 1u);
    return (unsigned short)(r >> 16);
}
__device__ __forceinline__ float bf2f(unsigned short h) {
    union { unsigned int i; float f; } u; u.i = ((unsigned int)h) << 16;
    return u.f;
}
__device__ __forceinline__ float lo_f(unsigned int w) {
    union { unsigned int i; float f; } u; u.i = w << 16;
    return u.f;
}
__device__ __forceinline__ float hi_f(unsigned int w) {
    union { unsigned int i; float f; } u; u.i = w & 0xffff0000u;
    return u.f;
}
__device__ __forceinline__ void async16(void* lds, const void* g) {
    __builtin_amdgcn_global_load_lds(
        (const __attribute__((address_space(1))) void*)g,
        (__attribute__((address_space(3))) void*)lds, 16, 0, 0);
}
__device__ __forceinline__ void add8(float* a, uint4 v) {
    a[0] += lo_f(v.x); a[1] += hi_f(v.x);
    a[2] += lo_f(v.y); a[3] += hi_f(v.y);
    a[4] += lo_f(v.z); a[5] += hi_f(v.z);
    a[6] += lo_f(v.w); a[7] += hi_f(v.w);
}

// ---------------------------------------------------------------------------
// Encode: 16 threads per node, 8 consecutive channels per thread ->
// one short8 hi-unit + one short8 lo-unit store (coalesced 512 B rows).
// ---------------------------------------------------------------------------
__global__ __launch_bounds__(256) void encode_kernel(
    const float* __restrict__ feats0, const float* __restrict__ feats1,
    const float* __restrict__ w0, const float* __restrict__ b0,
    const float* __restrict__ w1, const float* __restrict__ b1,
    const int* __restrict__ row_idx, char* __restrict__ xc)
{
    __shared__ float sw0[D_IN * C];
    __shared__ float sw1[D_IN * C];
    __shared__ float sb0[C];
    __shared__ float sb1[C];
    for (int i = threadIdx.x; i < D_IN * C; i += blockDim.x) {
        sw0[i] = w0[i];
        sw1[i] = w1[i];
    }
    if (threadIdx.x < C) {
        sb0[threadIdx.x] = b0[threadIdx.x];
        sb1[threadIdx.x] = b1[threadIdx.x];
    }
    __syncthreads();

    int j = threadIdx.x & 15;        // unit pair: channels 8j..8j+7
    int ln = threadIdx.x >> 4;       // 0..15 local node
    for (int n = blockIdx.x * 16 + ln; n < N_NODES; n += gridDim.x * 16) {
        int r = row_idx[n];
        const float* f = (r < T0) ? (feats0 + (size_t)r * D_IN)
                                  : (feats1 + (size_t)(r - T0) * D_IN);
        const float* W = (r < T0) ? sw0 : sw1;
        const float* B = (r < T0) ? sb0 : sb1;
        float4 f4[8];
#pragma unroll
        for (int i = 0; i < 8; ++i) f4[i] = ((const float4*)f)[i];
        float acc[8];
#pragma unroll
        for (int cc = 0; cc < 8; ++cc) acc[cc] = B[8 * j + cc];
#pragma unroll
        for (int k = 0; k < D_IN; ++k) {
            float fk = ((const float*)f4)[k];
            float4 wa = *(const float4*)&W[k * C + 8 * j];
            float4 wb = *(const float4*)&W[k * C + 8 * j + 4];
            acc[0] += fk * wa.x; acc[1] += fk * wa.y;
            acc[2] += fk * wa.z; acc[3] += fk * wa.w;
            acc[4] += fk * wb.x; acc[5] += fk * wb.y;
            acc[6] += fk * wb.z; acc[7] += fk * wb.w;
        }
        short8 h8, l8;
#pragma unroll
        for (int cc = 0; cc < 8; ++cc) {
            unsigned short hi = f2bf(acc[cc]);
            h8[cc] = (short)hi;
            l8[cc] = (short)f2bf(acc[cc] - bf2f(hi));
        }
        char* base = xc + (size_t)n * 512 + 32 * j;
        *(short8*)base = h8;
        *(short8*)(base + 16) = l8;
    }
}

// ---------------------------------------------------------------------------
// Weight prep: BT[layer][n][k], k in [0,1024), 4 segments of 256 slots:
//   seg0: hi(Wself)  seg1: hi(Wneigh)  seg2: lo(Wself)  seg3: lo(Wneigh)
// ---------------------------------------------------------------------------
__global__ __launch_bounds__(256) void prep_weights(
    const float* __restrict__ ws0, const float* __restrict__ wn0,
    const float* __restrict__ ws1, const float* __restrict__ wn1,
    unsigned short* __restrict__ BT0, unsigned short* __restrict__ BT1)
{
    int idx = blockIdx.x * 256 + threadIdx.x;
    if (idx >= 2 * 128 * 1024) return;
    int lyr = idx >> 17;
    int rem = idx & 131071;
    int n = rem >> 10;        // 0..127
    int k = rem & 1023;
    int seg = k >> 8;         // 0..3
    int slot = k & 255;
    int channel = ((slot >> 4) * 8) + (slot & 7);
    const float* W = (lyr == 0) ? ((seg & 1) ? wn0 : ws0)
                                : ((seg & 1) ? wn1 : ws1);
    float v = W[channel * 128 + n];
    unsigned short hi = f2bf(v);
    unsigned short out = (seg < 2) ? hi : f2bf(v - bf2f(hi));
    (lyr == 0 ? BT0 : BT1)[(size_t)n * 1024 + k] = out;
}

// ---------------------------------------------------------------------------
// CSR build: histogram -> hierarchical scan -> scatter
// ---------------------------------------------------------------------------
__global__ __launch_bounds__(256) void hist_kernel(const int* __restrict__ dst,
                                                   int* __restrict__ counts)
{
    int i = blockIdx.x * blockDim.x + threadIdx.x;
    if (i < N_EDGES) atomicAdd(&counts[dst[i]], 1);
}

__global__ __launch_bounds__(256) void scan1_kernel(
    const int* __restrict__ counts, int* __restrict__ offsets,
    int* __restrict__ blk_sums)
{
    __shared__ int ws[4];
    int i = blockIdx.x * 256 + threadIdx.x;
    int c = (i < N_NODES) ? counts[i] : 0;
    int lane = threadIdx.x & 63, wid = threadIdx.x >> 6;
    int v = c;
#pragma unroll
    for (int off = 1; off < 64; off <<= 1) {
        int t = __shfl_up(v, off, 64);
        if (lane >= off) v += t;
    }
    if (lane == 63) ws[wid] = v;
    __syncthreads();
    if (threadIdx.x == 0) {
        int run = 0;
#pragma unroll
        for (int j = 0; j < 4; ++j) { int t = ws[j]; ws[j] = run; run += t; }
        blk_sums[blockIdx.x] = run;
    }
    __syncthreads();
    if (i < N_NODES) offsets[i] = ws[wid] + (v - c);
}

__global__ __launch_bounds__(256) void scan2_kernel(int* __restrict__ blk_sums)
{
    __shared__ int ws[4];
    int t = threadIdx.x;
    int c = (t < SCAN_BLOCKS) ? blk_sums[t] : 0;
    int lane = t & 63, wid = t >> 6;
    int v = c;
#pragma unroll
    for (int off = 1; off < 64; off <<= 1) {
        int s = __shfl_up(v, off, 64);
        if (lane >= off) v += s;
    }
    if (lane == 63) ws[wid] = v;
    __syncthreads();
    if (t == 0) {
        int run = 0;
#pragma unroll
        for (int j = 0; j < 4; ++j) { int s = ws[j]; ws[j] = run; run += s; }
    }
    __syncthreads();
    if (t < SCAN_BLOCKS) blk_sums[t] = ws[wid] + (v - c);
}

__global__ __launch_bounds__(256) void scan3_kernel(
    const int* __restrict__ counts, const int* __restrict__ blk_sums,
    int* __restrict__ offsets, int* __restrict__ cursor,
    float* __restrict__ deg)
{
    int i = blockIdx.x * 256 + threadIdx.x;
    if (i == 0) offsets[N_NODES] = N_EDGES;
    if (i >= N_NODES) return;
    int o = offsets[i] + blk_sums[blockIdx.x];
    offsets[i] = o;
    cursor[i] = o;
    int cnt = counts[i];
    deg[i] = (float)(cnt > 0 ? cnt : 1);
}

__global__ __launch_bounds__(256) void scatter_kernel(
    const int* __restrict__ src, const int* __restrict__ dst,
    int* __restrict__ cursor, int* __restrict__ src_sorted)
{
    int i = blockIdx.x * blockDim.x + threadIdx.x;
    if (i < N_EDGES) {
        int pos = atomicAdd(&cursor[dst[i]], 1);
        src_sorted[pos] = src[i];
    }
}

// ---------------------------------------------------------------------------
// Aggregate: one wave per dst node; 16 B per lane, 32 lanes per row ->
// each wave-load covers TWO edges (half-wave h = lane>>5 takes edge e+h).
// 8 edges per unrolled iter (4 loads in flight). shfl_xor(32) combines the
// half-waves, shfl_xor(1) combines hi/lo kind partners; lanes 0..31 emit
// one short8 each -> coalesced 512 B interleaved output row.
// ---------------------------------------------------------------------------
__global__ __launch_bounds__(256) void aggregate_kernel(
    const char* __restrict__ xc, const int* __restrict__ offsets,
    const int* __restrict__ src_sorted, const float* __restrict__ deg,
    char* __restrict__ ac)
{
    int wave = (blockIdx.x * blockDim.x + threadIdx.x) >> 6;
    int lane = threadIdx.x & 63;
    if (wave >= N_NODES) return;
    int h = lane >> 5;          // which edge of a pair
    int u = lane & 31;          // 16 B unit index within row
    int beg = offsets[wave];
    int end = offsets[wave + 1];
    float acc[8];
#pragma unroll
    for (int j = 0; j < 8; ++j) acc[j] = 0.f;

    int e = beg;
    for (; e + 8 <= end; e += 8) {
        int sA = src_sorted[e + h];
        int sB = src_sorted[e + 2 + h];
        int sC = src_sorted[e + 4 + h];
        int sD = src_sorted[e + 6 + h];
        uint4 vA = *(const uint4*)(xc + (size_t)sA * 512 + u * 16);
        uint4 vB = *(const uint4*)(xc + (size_t)sB * 512 + u * 16);
        uint4 vC = *(const uint4*)(xc + (size_t)sC * 512 + u * 16);
        uint4 vD = *(const uint4*)(xc + (size_t)sD * 512 + u * 16);
        add8(acc, vA); add8(acc, vB); add8(acc, vC); add8(acc, vD);
    }
    for (; e + 2 <= end; e += 2) {
        int s = src_sorted[e + h];
        uint4 v = *(const uint4*)(xc + (size_t)s * 512 + u * 16);
        add8(acc, v);
    }
    if (e < end && h == 0) {
        int s = src_sorted[e];
        uint4 v = *(const uint4*)(xc + (size_t)s * 512 + u * 16);
        add8(acc, v);
    }

    // combine the two half-waves
#pragma unroll
    for (int j = 0; j < 8; ++j) acc[j] += __shfl_xor(acc[j], 32);
    // combine hi/lo kind partners (unit u ^ 1 == lane ^ 1)
    float inv = 1.0f / deg[wave];
    short8 outv;
    bool hiKind = (u & 1) == 0;
#pragma unroll
    for (int j = 0; j < 8; ++j) {
        float t = (acc[j] + __shfl_xor(acc[j], 1)) * inv;
        unsigned short hi = f2bf(t);
        outv[j] = hiKind ? (short)hi : (short)f2bf(t - bf2f(hi));
    }
    if (lane < 32)
        *(short8*)(ac + (size_t)wave * 512 + u * 16) = outv;
}

// ---------------------------------------------------------------------------
// Layer GEMM: 512 thr / 8 waves, tile 128x128, K=1024 in 8 chunks of 128.
// XOR-swizzled LDS (unit' = unit ^ (row&15)) -> conflict-free b128 reads;
// swizzle applied via per-lane global addresses in global_load_lds.
// Epilogue bounced through LDS for coalesced uint4 output. In-place xc.
// ---------------------------------------------------------------------------
#define BM 128
__global__ __launch_bounds__(512) void gemm_mfma(
    char* __restrict__ xc, const char* __restrict__ ac,
    const unsigned short* __restrict__ BT, const float* __restrict__ bias,
    int relu)
{
    __shared__ uint4 smem4[4096];           // 64 KB: As 32K | Bs 32K
    char* As = (char*)smem4;
    char* Bs = (char*)smem4 + 32768;
    __shared__ float bias_s[C];

    int tid = threadIdx.x;
    int w = tid >> 6, l = tid & 63;
    int row0 = blockIdx.x * BM;
    if (tid < C) bias_s[tid] = bias[tid];

    f32x4 acc[2][4];
#pragma unroll
    for (int mt = 0; mt < 2; ++mt)
#pragma unroll
        for (int nt = 0; nt < 4; ++nt)
            acc[mt][nt] = (f32x4)(0.f);

    int wm = w & 3;     // row quarter: rows [wm*32, wm*32+32)
    int wn = w >> 2;    // col half:    cols [wn*64, wn*64+64)
    int quad = l >> 4;
    int mrow = l & 15;

    for (int c = 0; c < 8; ++c) {
        const char* abase = (c & 2) ? ac : xc;
        int coloff = (c & 1) * 256;
        // --- stage A (32 KB), swizzled ---
#pragma unroll
        for (int i = 0; i < 4; ++i) {
            int off = i * 8192 + tid * 16;
            int rl = off >> 8;
            int row = row0 + rl;
            if (row > N_NODES - 1) row = N_NODES - 1;
            int u = ((off >> 4) & 15) ^ (rl & 15);
            const char* g = abase + (size_t)row * 512 + coloff + u * 16;
            async16(As + off, g);
        }
        // --- stage B (32 KB), swizzled; BT row stride 2048 B ---
#pragma unroll
        for (int i = 0; i < 4; ++i) {
            int off = i * 8192 + tid * 16;
            int n = off >> 8;
            int u = ((off >> 4) & 15) ^ (n & 15);
            const char* g = (const char*)BT + (size_t)n * 2048 + c * 256 + u * 16;
            async16(Bs + off, g);
        }
        __syncthreads();
#pragma unroll
        for (int ks = 0; ks < 4; ++ks) {
            int cu = ks * 4 + quad;             // unit 0..15
            int swz = (cu ^ mrow) * 16;
            short8 a0 = *(const short8*)(As + (wm * 32 + mrow) * 256 + swz);
            short8 a1 = *(const short8*)(As + (wm * 32 + 16 + mrow) * 256 + swz);
            short8 b[4];
#pragma unroll
            for (int nt = 0; nt < 4; ++nt)
                b[nt] = *(const short8*)(Bs + (wn * 64 + nt * 16 + mrow) * 256 + swz);
#pragma unroll
            for (int nt = 0; nt < 4; ++nt) {
                acc[0][nt] = __builtin_amdgcn_mfma_f32_16x16x32_bf16(a0, b[nt], acc[0][nt], 0, 0, 0);
                acc[1][nt] = __builtin_amdgcn_mfma_f32_16x16x32_bf16(a1, b[nt], acc[1][nt], 0, 0, 0);
            }
        }
        __syncthreads();
    }

    // epilogue: build interleaved tile in LDS, then coalesced uint4 copy-out
    char* tileb = (char*)smem4;
#pragma unroll
    for (int mt = 0; mt < 2; ++mt)
#pragma unroll
        for (int nt = 0; nt < 4; ++nt) {
            int col = wn * 64 + nt * 16 + mrow;
            float bb = bias_s[col];
#pragma unroll
            for (int r = 0; r < 4; ++r) {
                int rl = wm * 32 + mt * 16 + quad * 4 + r;
                float v = acc[mt][nt][r] + bb;
                if (relu) v = fmaxf(v, 0.f);
                unsigned short hi = f2bf(v);
                char* p = tileb + rl * 512 + 32 * (col >> 3) + 2 * (col & 7);
                *(unsigned short*)p = hi;
                *(unsigned short*)(p + 16) = f2bf(v - bf2f(hi));
            }
        }
    __syncthreads();
#pragma unroll
    for (int i = 0; i < 8; ++i) {
        int off = i * 8192 + tid * 16;
        int row = row0 + (off >> 9);
        if (row < N_NODES)
            *(uint4*)(xc + (size_t)row0 * 512 + off) = *(const uint4*)(tileb + off);
    }
}

// ---------------------------------------------------------------------------
// Head: out = x @ head_w + head_b   [N,128] @ [128,16]
// ---------------------------------------------------------------------------
__global__ __launch_bounds__(256) void head_kernel(
    const char* __restrict__ xc, const float* __restrict__ hw,
    const float* __restrict__ hb, float* __restrict__ out)
{
    __shared__ float w[C * OUT_DIM];
    __shared__ float b[OUT_DIM];
    for (int i = threadIdx.x; i < C * OUT_DIM; i += blockDim.x) w[i] = hw[i];
    if (threadIdx.x < OUT_DIM) b[threadIdx.x] = hb[threadIdx.x];
    __syncthreads();

    int node = blockIdx.x * 16 + (threadIdx.x >> 4);
    int c = threadIdx.x & 15;
    if (node >= N_NODES) return;
    float acc = b[c];
    const char* xr = xc + (size_t)node * 512;
#pragma unroll 8
    for (int k = 0; k < C; ++k) {
        size_t o = 32 * (size_t)(k >> 3) + 2 * (k & 7);
        float v = bf2f(*(const unsigned short*)(xr + o))
                + bf2f(*(const unsigned short*)(xr + o + 16));
        acc += v * w[k * OUT_DIM + c];
    }
    out[(size_t)node * OUT_DIM + c] = acc;
}

// ---------------------------------------------------------------------------
extern "C" void kernel_launch(void* const* d_in, const int* in_sizes, int n_in,
                              void* d_out, int out_size, void* d_ws, size_t ws_size,
                              hipStream_t stream)
{
    const float* feats0 = (const float*)d_in[0];
    const float* feats1 = (const float*)d_in[1];
    const float* enc_w0 = (const float*)d_in[2];
    const float* enc_b0 = (const float*)d_in[3];
    const float* enc_w1 = (const float*)d_in[4];
    const float* enc_b1 = (const float*)d_in[5];
    const float* w_self0 = (const float*)d_in[6];
    const float* w_neigh0 = (const float*)d_in[7];
    const float* b0 = (const float*)d_in[8];
    const float* w_self1 = (const float*)d_in[9];
    const float* w_neigh1 = (const float*)d_in[10];
    const float* b1 = (const float*)d_in[11];
    const float* head_w = (const float*)d_in[12];
    const float* head_b = (const float*)d_in[13];
    const int* node_row_idx = (const int*)d_in[14];
    const int* edge_index = (const int*)d_in[15];
    const int* e_src = edge_index;
    const int* e_dst = edge_index + N_EDGES;

    char* p = (char*)d_ws;
    char* xc = p;                 p += (size_t)N_NODES * 512;
    char* ac = p;                 p += (size_t)N_NODES * 512;
    unsigned short* BT0 = (unsigned short*)p; p += (size_t)128 * 1024 * 2;
    unsigned short* BT1 = (unsigned short*)p; p += (size_t)128 * 1024 * 2;
    float* deg = (float*)p;      p += (size_t)N_NODES * 4;
    int* counts = (int*)p;       p += (size_t)N_NODES * 4;
    int* offsets = (int*)p;      p += (size_t)(N_NODES + 8) * 4;
    int* cursor = (int*)p;       p += (size_t)N_NODES * 4;
    int* blk_sums = (int*)p;     p += (size_t)(SCAN_BLOCKS + 8) * 4;
    int* src_sorted = (int*)p;   p += (size_t)N_EDGES * 4;

    hipMemsetAsync(counts, 0, (size_t)N_NODES * sizeof(int), stream);

    encode_kernel<<<512, 256, 0, stream>>>(feats0, feats1, enc_w0, enc_b0,
                                           enc_w1, enc_b1, node_row_idx, xc);
    prep_weights<<<(2 * 128 * 1024 + 255) / 256, 256, 0, stream>>>(
        w_self0, w_neigh0, w_self1, w_neigh1, BT0, BT1);

    hist_kernel<<<(N_EDGES + 255) / 256, 256, 0, stream>>>(e_dst, counts);
    scan1_kernel<<<SCAN_BLOCKS, 256, 0, stream>>>(counts, offsets, blk_sums);
    scan2_kernel<<<1, 256, 0, stream>>>(blk_sums);
    scan3_kernel<<<SCAN_BLOCKS, 256, 0, stream>>>(counts, blk_sums, offsets,
                                                  cursor, deg);
    scatter_kernel<<<(N_EDGES + 255) / 256, 256, 0, stream>>>(
        e_src, e_dst, cursor, src_sorted);

    // Layer 0
    aggregate_kernel<<<(N_NODES * 64 + 255) / 256, 256, 0, stream>>>(
        xc, offsets, src_sorted, deg, ac);
    gemm_mfma<<<(N_NODES + BM - 1) / BM, 512, 0, stream>>>(xc, ac, BT0, b0, 1);

    // Layer 1
    aggregate_kernel<<<(N_NODES * 64 + 255) / 256, 256, 0, stream>>>(
        xc, offsets, src_sorted, deg, ac);
    gemm_mfma<<<(N_NODES + BM - 1) / BM, 512, 0, stream>>>(xc, ac, BT1, b1, 0);

    head_kernel<<<(N_NODES + 15) / 16, 256, 0, stream>>>(xc, head_w, head_b,
                                                         (float*)d_out);
}

// Round 7
// 328.261 us; speedup vs baseline: 2.3993x; 1.1693x over previous
//
#include <hip/hip_runtime.h>
#include <hip/hip_bf16.h>

#define N_NODES 50000
#define N_EDGES 800000
#define C 128
#define D_IN 32
#define T0 25000
#define OUT_DIM 16
#define SCAN_BLOCKS ((N_NODES + 255) / 256)   // 196

// Feature storage: two planes, plain row-major bf16:
//   xh[N][128] (hi part), xl[N][128] (lo part), row = 256 B each.
// Aggregation gathers ONLY xh (dropped lo-term error ~3e-4, margin 0.066).

typedef __attribute__((ext_vector_type(8))) short short8;
typedef __attribute__((ext_vector_type(4))) float f32x4;

__device__ __forceinline__ unsigned short f2bf(float f) {
    union { float f; unsigned int i; } u; u.f = f;
    unsigned int x = u.i;
    unsigned int r = x + 0x7fffu + ((x >> 16) & 1u);
    return (unsigned short)(r >> 16);
}
__device__ __forceinline__ float bf2f(unsigned short h) {
    union { unsigned int i; float f; } u; u.i = ((unsigned int)h) << 16;
    return u.f;
}
__device__ __forceinline__ float lo_f(unsigned int w) {
    union { unsigned int i; float f; } u; u.i = w << 16;
    return u.f;
}
__device__ __forceinline__ float hi_f(unsigned int w) {
    union { unsigned int i; float f; } u; u.i = w & 0xffff0000u;
    return u.f;
}
__device__ __forceinline__ void async16(void* lds, const void* g) {
    __builtin_amdgcn_global_load_lds(
        (const __attribute__((address_space(1))) void*)g,
        (__attribute__((address_space(3))) void*)lds, 16, 0, 0);
}
__device__ __forceinline__ void add8(float* a, uint4 v) {
    a[0] += lo_f(v.x); a[1] += hi_f(v.x);
    a[2] += lo_f(v.y); a[3] += hi_f(v.y);
    a[4] += lo_f(v.z); a[5] += hi_f(v.z);
    a[6] += lo_f(v.w); a[7] += hi_f(v.w);
}

// ---------------------------------------------------------------------------
// Encode: 16 threads per node, 8 consecutive channels per thread ->
// one short8 store per plane (coalesced 256 B rows).
// ---------------------------------------------------------------------------
__global__ __launch_bounds__(256) void encode_kernel(
    const float* __restrict__ feats0, const float* __restrict__ feats1,
    const float* __restrict__ w0, const float* __restrict__ b0,
    const float* __restrict__ w1, const float* __restrict__ b1,
    const int* __restrict__ row_idx,
    unsigned short* __restrict__ xh, unsigned short* __restrict__ xl)
{
    __shared__ float sw0[D_IN * C];
    __shared__ float sw1[D_IN * C];
    __shared__ float sb0[C];
    __shared__ float sb1[C];
    for (int i = threadIdx.x; i < D_IN * C; i += blockDim.x) {
        sw0[i] = w0[i];
        sw1[i] = w1[i];
    }
    if (threadIdx.x < C) {
        sb0[threadIdx.x] = b0[threadIdx.x];
        sb1[threadIdx.x] = b1[threadIdx.x];
    }
    __syncthreads();

    int j = threadIdx.x & 15;        // channels 8j..8j+7
    int ln = threadIdx.x >> 4;       // 0..15 local node
    for (int n = blockIdx.x * 16 + ln; n < N_NODES; n += gridDim.x * 16) {
        int r = row_idx[n];
        const float* f = (r < T0) ? (feats0 + (size_t)r * D_IN)
                                  : (feats1 + (size_t)(r - T0) * D_IN);
        const float* W = (r < T0) ? sw0 : sw1;
        const float* B = (r < T0) ? sb0 : sb1;
        float4 f4[8];
#pragma unroll
        for (int i = 0; i < 8; ++i) f4[i] = ((const float4*)f)[i];
        float acc[8];
#pragma unroll
        for (int cc = 0; cc < 8; ++cc) acc[cc] = B[8 * j + cc];
#pragma unroll
        for (int k = 0; k < D_IN; ++k) {
            float fk = ((const float*)f4)[k];
            float4 wa = *(const float4*)&W[k * C + 8 * j];
            float4 wb = *(const float4*)&W[k * C + 8 * j + 4];
            acc[0] += fk * wa.x; acc[1] += fk * wa.y;
            acc[2] += fk * wa.z; acc[3] += fk * wa.w;
            acc[4] += fk * wb.x; acc[5] += fk * wb.y;
            acc[6] += fk * wb.z; acc[7] += fk * wb.w;
        }
        short8 h8, l8;
#pragma unroll
        for (int cc = 0; cc < 8; ++cc) {
            unsigned short hi = f2bf(acc[cc]);
            h8[cc] = (short)hi;
            l8[cc] = (short)f2bf(acc[cc] - bf2f(hi));
        }
        *(short8*)(xh + (size_t)n * 128 + 8 * j) = h8;
        *(short8*)(xl + (size_t)n * 128 + 8 * j) = l8;
    }
}

// ---------------------------------------------------------------------------
// Weight prep: BT[layer][n][k], k in [0,768), 6 segments of 128 channels:
//   seg0: hi(Ws)  seg1: hi(Wn)  seg2: hi(Ws)  seg3: hi(Wn)
//   seg4: lo(Ws)  seg5: lo(Wn)
// Pairs with A-chunk order {xh, ah, xl, al, xh, ah}.
// ---------------------------------------------------------------------------
__global__ __launch_bounds__(256) void prep_weights(
    const float* __restrict__ ws0, const float* __restrict__ wn0,
    const float* __restrict__ ws1, const float* __restrict__ wn1,
    unsigned short* __restrict__ BT0, unsigned short* __restrict__ BT1)
{
    int idx = blockIdx.x * 256 + threadIdx.x;
    const int per_layer = 128 * 768;
    if (idx >= 2 * per_layer) return;
    int lyr = idx / per_layer;
    int rem = idx - lyr * per_layer;
    int n = rem / 768;
    int k = rem - n * 768;
    int seg = k >> 7;         // 0..5
    int ch = k & 127;
    const float* W = (lyr == 0) ? ((seg & 1) ? wn0 : ws0)
                                : ((seg & 1) ? wn1 : ws1);
    float v = W[ch * 128 + n];
    unsigned short hi = f2bf(v);
    unsigned short out = (seg < 4) ? hi : f2bf(v - bf2f(hi));
    (lyr == 0 ? BT0 : BT1)[(size_t)n * 768 + k] = out;
}

// ---------------------------------------------------------------------------
// CSR build: histogram -> hierarchical scan -> scatter
// ---------------------------------------------------------------------------
__global__ __launch_bounds__(256) void hist_kernel(const int* __restrict__ dst,
                                                   int* __restrict__ counts)
{
    int i = blockIdx.x * blockDim.x + threadIdx.x;
    if (i < N_EDGES) atomicAdd(&counts[dst[i]], 1);
}

__global__ __launch_bounds__(256) void scan1_kernel(
    const int* __restrict__ counts, int* __restrict__ offsets,
    int* __restrict__ blk_sums)
{
    __shared__ int ws[4];
    int i = blockIdx.x * 256 + threadIdx.x;
    int c = (i < N_NODES) ? counts[i] : 0;
    int lane = threadIdx.x & 63, wid = threadIdx.x >> 6;
    int v = c;
#pragma unroll
    for (int off = 1; off < 64; off <<= 1) {
        int t = __shfl_up(v, off, 64);
        if (lane >= off) v += t;
    }
    if (lane == 63) ws[wid] = v;
    __syncthreads();
    if (threadIdx.x == 0) {
        int run = 0;
#pragma unroll
        for (int j = 0; j < 4; ++j) { int t = ws[j]; ws[j] = run; run += t; }
        blk_sums[blockIdx.x] = run;
    }
    __syncthreads();
    if (i < N_NODES) offsets[i] = ws[wid] + (v - c);
}

__global__ __launch_bounds__(256) void scan2_kernel(int* __restrict__ blk_sums)
{
    __shared__ int ws[4];
    int t = threadIdx.x;
    int c = (t < SCAN_BLOCKS) ? blk_sums[t] : 0;
    int lane = t & 63, wid = t >> 6;
    int v = c;
#pragma unroll
    for (int off = 1; off < 64; off <<= 1) {
        int s = __shfl_up(v, off, 64);
        if (lane >= off) v += s;
    }
    if (lane == 63) ws[wid] = v;
    __syncthreads();
    if (t == 0) {
        int run = 0;
#pragma unroll
        for (int j = 0; j < 4; ++j) { int s = ws[j]; ws[j] = run; run += s; }
    }
    __syncthreads();
    if (t < SCAN_BLOCKS) blk_sums[t] = ws[wid] + (v - c);
}

__global__ __launch_bounds__(256) void scan3_kernel(
    const int* __restrict__ counts, const int* __restrict__ blk_sums,
    int* __restrict__ offsets, int* __restrict__ cursor,
    float* __restrict__ deg)
{
    int i = blockIdx.x * 256 + threadIdx.x;
    if (i == 0) offsets[N_NODES] = N_EDGES;
    if (i >= N_NODES) return;
    int o = offsets[i] + blk_sums[blockIdx.x];
    offsets[i] = o;
    cursor[i] = o;
    int cnt = counts[i];
    deg[i] = (float)(cnt > 0 ? cnt : 1);
}

__global__ __launch_bounds__(256) void scatter_kernel(
    const int* __restrict__ src, const int* __restrict__ dst,
    int* __restrict__ cursor, int* __restrict__ src_sorted)
{
    int i = blockIdx.x * blockDim.x + threadIdx.x;
    if (i < N_EDGES) {
        int pos = atomicAdd(&cursor[dst[i]], 1);
        src_sorted[pos] = src[i];
    }
}

// ---------------------------------------------------------------------------
// Aggregate: one wave per dst node, hi-plane ONLY (256 B rows).
// lane = h*16 + u: h picks edge within a group of 4, u is the 16 B unit.
// One wave-load covers FOUR edges; 16 edges per unrolled iter.
// shfl_xor(16)+shfl_xor(32) combine the 4 sub-waves; lanes 0..15 split the
// mean into hi/lo and store one short8 per plane (coalesced 256 B rows).
// ---------------------------------------------------------------------------
__global__ __launch_bounds__(256) void aggregate_kernel(
    const unsigned short* __restrict__ xh, const int* __restrict__ offsets,
    const int* __restrict__ src_sorted, const float* __restrict__ deg,
    unsigned short* __restrict__ ah, unsigned short* __restrict__ al)
{
    int wave = (blockIdx.x * blockDim.x + threadIdx.x) >> 6;
    int lane = threadIdx.x & 63;
    if (wave >= N_NODES) return;
    int h = lane >> 4;          // 0..3: which edge of a group
    int u = lane & 15;          // 16 B unit (8 channels)
    int beg = offsets[wave];
    int end = offsets[wave + 1];
    float acc[8];
#pragma unroll
    for (int j = 0; j < 8; ++j) acc[j] = 0.f;

    int e = beg;
    for (; e + 16 <= end; e += 16) {
        int sA = src_sorted[e + h];
        int sB = src_sorted[e + 4 + h];
        int sC = src_sorted[e + 8 + h];
        int sD = src_sorted[e + 12 + h];
        uint4 vA = *(const uint4*)(xh + (size_t)sA * 128 + u * 8);
        uint4 vB = *(const uint4*)(xh + (size_t)sB * 128 + u * 8);
        uint4 vC = *(const uint4*)(xh + (size_t)sC * 128 + u * 8);
        uint4 vD = *(const uint4*)(xh + (size_t)sD * 128 + u * 8);
        add8(acc, vA); add8(acc, vB); add8(acc, vC); add8(acc, vD);
    }
    for (; e + 4 <= end; e += 4) {
        int s = src_sorted[e + h];
        uint4 v = *(const uint4*)(xh + (size_t)s * 128 + u * 8);
        add8(acc, v);
    }
    int rem = end - e;
    if (h < rem) {
        int s = src_sorted[e + h];
        uint4 v = *(const uint4*)(xh + (size_t)s * 128 + u * 8);
        add8(acc, v);
    }

#pragma unroll
    for (int j = 0; j < 8; ++j) {
        acc[j] += __shfl_xor(acc[j], 16);
        acc[j] += __shfl_xor(acc[j], 32);
    }
    if (lane < 16) {
        float inv = 1.0f / deg[wave];
        short8 hv, lv;
#pragma unroll
        for (int j = 0; j < 8; ++j) {
            float t = acc[j] * inv;
            unsigned short hi = f2bf(t);
            hv[j] = (short)hi;
            lv[j] = (short)f2bf(t - bf2f(hi));
        }
        *(short8*)(ah + (size_t)wave * 128 + u * 8) = hv;
        *(short8*)(al + (size_t)wave * 128 + u * 8) = lv;
    }
}

// ---------------------------------------------------------------------------
// Layer GEMM: 512 thr / 8 waves, tile 128x128, K=768 in 6 chunks of 128.
// A-chunk bases {xh, ah, xl, al, xh, ah}; B = BT[n][768] matching segs.
// XOR-swizzled LDS; epilogue bounced through LDS -> coalesced uint4 stores
// to both planes. In-place update of xh/xl.
// ---------------------------------------------------------------------------
#define BM 128
__global__ __launch_bounds__(512) void gemm_mfma(
    unsigned short* __restrict__ xh, unsigned short* __restrict__ xl,
    const unsigned short* __restrict__ ah, const unsigned short* __restrict__ al,
    const unsigned short* __restrict__ BT, const float* __restrict__ bias,
    int relu)
{
    __shared__ uint4 smem4[4096];           // 64 KB: As 32K | Bs 32K
    char* As = (char*)smem4;
    char* Bs = (char*)smem4 + 32768;
    __shared__ float bias_s[C];

    int tid = threadIdx.x;
    int w = tid >> 6, l = tid & 63;
    int row0 = blockIdx.x * BM;
    if (tid < C) bias_s[tid] = bias[tid];

    f32x4 acc[2][4];
#pragma unroll
    for (int mt = 0; mt < 2; ++mt)
#pragma unroll
        for (int nt = 0; nt < 4; ++nt)
            acc[mt][nt] = (f32x4)(0.f);

    int wm = w & 3;     // row quarter
    int wn = w >> 2;    // col half
    int quad = l >> 4;
    int mrow = l & 15;

    const unsigned short* abases[6] = {xh, ah, xl, al, xh, ah};

    for (int c = 0; c < 6; ++c) {
        const char* abase = (const char*)abases[c];
        // --- stage A (32 KB = 128 rows x 256 B), swizzled ---
#pragma unroll
        for (int i = 0; i < 4; ++i) {
            int off = i * 8192 + tid * 16;
            int rl = off >> 8;
            int row = row0 + rl;
            if (row > N_NODES - 1) row = N_NODES - 1;
            int u = ((off >> 4) & 15) ^ (rl & 15);
            async16(As + off, abase + (size_t)row * 256 + u * 16);
        }
        // --- stage B (32 KB), swizzled; BT row stride 1536 B ---
#pragma unroll
        for (int i = 0; i < 4; ++i) {
            int off = i * 8192 + tid * 16;
            int n = off >> 8;
            int u = ((off >> 4) & 15) ^ (n & 15);
            async16(Bs + off, (const char*)BT + (size_t)n * 1536 + c * 256 + u * 16);
        }
        __syncthreads();
#pragma unroll
        for (int ks = 0; ks < 4; ++ks) {
            int cu = ks * 4 + quad;             // unit 0..15
            int swz = (cu ^ mrow) * 16;
            short8 a0 = *(const short8*)(As + (wm * 32 + mrow) * 256 + swz);
            short8 a1 = *(const short8*)(As + (wm * 32 + 16 + mrow) * 256 + swz);
            short8 b[4];
#pragma unroll
            for (int nt = 0; nt < 4; ++nt)
                b[nt] = *(const short8*)(Bs + (wn * 64 + nt * 16 + mrow) * 256 + swz);
#pragma unroll
            for (int nt = 0; nt < 4; ++nt) {
                acc[0][nt] = __builtin_amdgcn_mfma_f32_16x16x32_bf16(a0, b[nt], acc[0][nt], 0, 0, 0);
                acc[1][nt] = __builtin_amdgcn_mfma_f32_16x16x32_bf16(a1, b[nt], acc[1][nt], 0, 0, 0);
            }
        }
        __syncthreads();
    }

    // epilogue: hi tile + lo tile in LDS, then coalesced uint4 copy-out
    char* th = (char*)smem4;            // 32 KB: 128 rows x 256 B
    char* tl = (char*)smem4 + 32768;
#pragma unroll
    for (int mt = 0; mt < 2; ++mt)
#pragma unroll
        for (int nt = 0; nt < 4; ++nt) {
            int col = wn * 64 + nt * 16 + mrow;
            float bb = bias_s[col];
#pragma unroll
            for (int r = 0; r < 4; ++r) {
                int rl = wm * 32 + mt * 16 + quad * 4 + r;
                float v = acc[mt][nt][r] + bb;
                if (relu) v = fmaxf(v, 0.f);
                unsigned short hi = f2bf(v);
                *(unsigned short*)(th + rl * 256 + col * 2) = hi;
                *(unsigned short*)(tl + rl * 256 + col * 2) = f2bf(v - bf2f(hi));
            }
        }
    __syncthreads();
#pragma unroll
    for (int i = 0; i < 4; ++i) {
        int off = i * 8192 + tid * 16;
        int row = row0 + (off >> 8);
        if (row < N_NODES)
            *(uint4*)((char*)xh + (size_t)row0 * 256 + off) = *(const uint4*)(th + off);
    }
#pragma unroll
    for (int i = 0; i < 4; ++i) {
        int off = i * 8192 + tid * 16;
        int row = row0 + (off >> 8);
        if (row < N_NODES)
            *(uint4*)((char*)xl + (size_t)row0 * 256 + off) = *(const uint4*)(tl + off);
    }
}

// ---------------------------------------------------------------------------
// Head: out = x @ head_w + head_b   [N,128] @ [128,16]
// ---------------------------------------------------------------------------
__global__ __launch_bounds__(256) void head_kernel(
    const unsigned short* __restrict__ xh, const unsigned short* __restrict__ xl,
    const float* __restrict__ hw, const float* __restrict__ hb,
    float* __restrict__ out)
{
    __shared__ float w[C * OUT_DIM];
    __shared__ float b[OUT_DIM];
    for (int i = threadIdx.x; i < C * OUT_DIM; i += blockDim.x) w[i] = hw[i];
    if (threadIdx.x < OUT_DIM) b[threadIdx.x] = hb[threadIdx.x];
    __syncthreads();

    int node = blockIdx.x * 16 + (threadIdx.x >> 4);
    int c = threadIdx.x & 15;
    if (node >= N_NODES) return;
    float acc = b[c];
    const uint2* rh = (const uint2*)(xh + (size_t)node * 128);
    const uint2* rl = (const uint2*)(xl + (size_t)node * 128);
#pragma unroll 8
    for (int kk = 0; kk < 32; ++kk) {   // 4 channels per iter
        uint2 vh = rh[kk];
        uint2 vl = rl[kk];
        int k = kk * 4;
        acc += (lo_f(vh.x) + lo_f(vl.x)) * w[k * OUT_DIM + c];
        acc += (hi_f(vh.x) + hi_f(vl.x)) * w[(k + 1) * OUT_DIM + c];
        acc += (lo_f(vh.y) + lo_f(vl.y)) * w[(k + 2) * OUT_DIM + c];
        acc += (hi_f(vh.y) + hi_f(vl.y)) * w[(k + 3) * OUT_DIM + c];
    }
    out[(size_t)node * OUT_DIM + c] = acc;
}

// ---------------------------------------------------------------------------
extern "C" void kernel_launch(void* const* d_in, const int* in_sizes, int n_in,
                              void* d_out, int out_size, void* d_ws, size_t ws_size,
                              hipStream_t stream)
{
    const float* feats0 = (const float*)d_in[0];
    const float* feats1 = (const float*)d_in[1];
    const float* enc_w0 = (const float*)d_in[2];
    const float* enc_b0 = (const float*)d_in[3];
    const float* enc_w1 = (const float*)d_in[4];
    const float* enc_b1 = (const float*)d_in[5];
    const float* w_self0 = (const float*)d_in[6];
    const float* w_neigh0 = (const float*)d_in[7];
    const float* b0 = (const float*)d_in[8];
    const float* w_self1 = (const float*)d_in[9];
    const float* w_neigh1 = (const float*)d_in[10];
    const float* b1 = (const float*)d_in[11];
    const float* head_w = (const float*)d_in[12];
    const float* head_b = (const float*)d_in[13];
    const int* node_row_idx = (const int*)d_in[14];
    const int* edge_index = (const int*)d_in[15];
    const int* e_src = edge_index;
    const int* e_dst = edge_index + N_EDGES;

    char* p = (char*)d_ws;
    unsigned short* xh = (unsigned short*)p;  p += (size_t)N_NODES * C * 2;
    unsigned short* xl = (unsigned short*)p;  p += (size_t)N_NODES * C * 2;
    unsigned short* ah = (unsigned short*)p;  p += (size_t)N_NODES * C * 2;
    unsigned short* al = (unsigned short*)p;  p += (size_t)N_NODES * C * 2;
    unsigned short* BT0 = (unsigned short*)p; p += (size_t)128 * 768 * 2;
    unsigned short* BT1 = (unsigned short*)p; p += (size_t)128 * 768 * 2;
    float* deg = (float*)p;      p += (size_t)N_NODES * 4;
    int* counts = (int*)p;       p += (size_t)N_NODES * 4;
    int* offsets = (int*)p;      p += (size_t)(N_NODES + 8) * 4;
    int* cursor = (int*)p;       p += (size_t)N_NODES * 4;
    int* blk_sums = (int*)p;     p += (size_t)(SCAN_BLOCKS + 8) * 4;
    int* src_sorted = (int*)p;   p += (size_t)N_EDGES * 4;

    hipMemsetAsync(counts, 0, (size_t)N_NODES * sizeof(int), stream);

    encode_kernel<<<512, 256, 0, stream>>>(feats0, feats1, enc_w0, enc_b0,
                                           enc_w1, enc_b1, node_row_idx, xh, xl);
    prep_weights<<<(2 * 128 * 768 + 255) / 256, 256, 0, stream>>>(
        w_self0, w_neigh0, w_self1, w_neigh1, BT0, BT1);

    hist_kernel<<<(N_EDGES + 255) / 256, 256, 0, stream>>>(e_dst, counts);
    scan1_kernel<<<SCAN_BLOCKS, 256, 0, stream>>>(counts, offsets, blk_sums);
    scan2_kernel<<<1, 256, 0, stream>>>(blk_sums);
    scan3_kernel<<<SCAN_BLOCKS, 256, 0, stream>>>(counts, blk_sums, offsets,
                                                  cursor, deg);
    scatter_kernel<<<(N_EDGES + 255) / 256, 256, 0, stream>>>(
        e_src, e_dst, cursor, src_sorted);

    // Layer 0
    aggregate_kernel<<<(N_NODES * 64 + 255) / 256, 256, 0, stream>>>(
        xh, offsets, src_sorted, deg, ah, al);
    gemm_mfma<<<(N_NODES + BM - 1) / BM, 512, 0, stream>>>(
        xh, xl, ah, al, BT0, b0, 1);

    // Layer 1
    aggregate_kernel<<<(N_NODES * 64 + 255) / 256, 256, 0, stream>>>(
        xh, offsets, src_sorted, deg, ah, al);
    gemm_mfma<<<(N_NODES + BM - 1) / BM, 512, 0, stream>>>(
        xh, xl, ah, al, BT1, b1, 0);

    head_kernel<<<(N_NODES + 15) / 16, 256, 0, stream>>>(xh, xl, head_w, head_b,
                                                         (float*)d_out);
}

// Round 8
// 311.969 us; speedup vs baseline: 2.5246x; 1.0522x over previous
//
#include <hip/hip_runtime.h>
#include <hip/hip_bf16.h>

#define N_NODES 50000
#define N_EDGES 800000
#define C 128
#define D_IN 32
#define T0 25000
#define OUT_DIM 16
#define SCAN_BLOCKS ((N_NODES + 255) / 256)   // 196
#define NBUCKETS SCAN_BLOCKS                  // bucket = dst>>8
#define NB1 512
#define CHUNK1 ((N_EDGES + NB1 - 1) / NB1)    // 1563

// Feature storage: two planes, plain row-major bf16:
//   xh[N][128] (hi part), xl[N][128] (lo part), row = 256 B each.
// Aggregation gathers ONLY xh (dropped lo-term error ~3e-4, margin 0.066).

typedef __attribute__((ext_vector_type(8))) short short8;
typedef __attribute__((ext_vector_type(4))) float f32x4;

__device__ __forceinline__ unsigned short f2bf(float f) {
    union { float f; unsigned int i; } u; u.f = f;
    unsigned int x = u.i;
    unsigned int r = x + 0x7fffu + ((x >> 16) & 1u);
    return (unsigned short)(r >> 16);
}
__device__ __forceinline__ float bf2f(unsigned short h) {
    union { unsigned int i; float f; } u; u.i = ((unsigned int)h) << 16;
    return u.f;
}
__device__ __forceinline__ float lo_f(unsigned int w) {
    union { unsigned int i; float f; } u; u.i = w << 16;
    return u.f;
}
__device__ __forceinline__ float hi_f(unsigned int w) {
    union { unsigned int i; float f; } u; u.i = w & 0xffff0000u;
    return u.f;
}
__device__ __forceinline__ void async16(void* lds, const void* g) {
    __builtin_amdgcn_global_load_lds(
        (const __attribute__((address_space(1))) void*)g,
        (__attribute__((address_space(3))) void*)lds, 16, 0, 0);
}
__device__ __forceinline__ void add8(float* a, uint4 v) {
    a[0] += lo_f(v.x); a[1] += hi_f(v.x);
    a[2] += lo_f(v.y); a[3] += hi_f(v.y);
    a[4] += lo_f(v.z); a[5] += hi_f(v.z);
    a[6] += lo_f(v.w); a[7] += hi_f(v.w);
}

// ---------------------------------------------------------------------------
// Encode: 16 threads per node, 8 consecutive channels per thread ->
// one short8 store per plane (coalesced 256 B rows).
// ---------------------------------------------------------------------------
__global__ __launch_bounds__(256) void encode_kernel(
    const float* __restrict__ feats0, const float* __restrict__ feats1,
    const float* __restrict__ w0, const float* __restrict__ b0,
    const float* __restrict__ w1, const float* __restrict__ b1,
    const int* __restrict__ row_idx,
    unsigned short* __restrict__ xh, unsigned short* __restrict__ xl)
{
    __shared__ float sw0[D_IN * C];
    __shared__ float sw1[D_IN * C];
    __shared__ float sb0[C];
    __shared__ float sb1[C];
    for (int i = threadIdx.x; i < D_IN * C; i += blockDim.x) {
        sw0[i] = w0[i];
        sw1[i] = w1[i];
    }
    if (threadIdx.x < C) {
        sb0[threadIdx.x] = b0[threadIdx.x];
        sb1[threadIdx.x] = b1[threadIdx.x];
    }
    __syncthreads();

    int j = threadIdx.x & 15;        // channels 8j..8j+7
    int ln = threadIdx.x >> 4;       // 0..15 local node
    for (int n = blockIdx.x * 16 + ln; n < N_NODES; n += gridDim.x * 16) {
        int r = row_idx[n];
        const float* f = (r < T0) ? (feats0 + (size_t)r * D_IN)
                                  : (feats1 + (size_t)(r - T0) * D_IN);
        const float* W = (r < T0) ? sw0 : sw1;
        const float* B = (r < T0) ? sb0 : sb1;
        float4 f4[8];
#pragma unroll
        for (int i = 0; i < 8; ++i) f4[i] = ((const float4*)f)[i];
        float acc[8];
#pragma unroll
        for (int cc = 0; cc < 8; ++cc) acc[cc] = B[8 * j + cc];
#pragma unroll
        for (int k = 0; k < D_IN; ++k) {
            float fk = ((const float*)f4)[k];
            float4 wa = *(const float4*)&W[k * C + 8 * j];
            float4 wb = *(const float4*)&W[k * C + 8 * j + 4];
            acc[0] += fk * wa.x; acc[1] += fk * wa.y;
            acc[2] += fk * wa.z; acc[3] += fk * wa.w;
            acc[4] += fk * wb.x; acc[5] += fk * wb.y;
            acc[6] += fk * wb.z; acc[7] += fk * wb.w;
        }
        short8 h8, l8;
#pragma unroll
        for (int cc = 0; cc < 8; ++cc) {
            unsigned short hi = f2bf(acc[cc]);
            h8[cc] = (short)hi;
            l8[cc] = (short)f2bf(acc[cc] - bf2f(hi));
        }
        *(short8*)(xh + (size_t)n * 128 + 8 * j) = h8;
        *(short8*)(xl + (size_t)n * 128 + 8 * j) = l8;
    }
}

// ---------------------------------------------------------------------------
// Weight prep: BT[layer][n][k], k in [0,768), 6 segments of 128 channels:
//   seg0: hi(Ws)  seg1: hi(Wn)  seg2: hi(Ws)  seg3: hi(Wn)
//   seg4: lo(Ws)  seg5: lo(Wn)
// Pairs with A-chunk order {xh, ah, xl, al, xh, ah}.
// ---------------------------------------------------------------------------
__global__ __launch_bounds__(256) void prep_weights(
    const float* __restrict__ ws0, const float* __restrict__ wn0,
    const float* __restrict__ ws1, const float* __restrict__ wn1,
    unsigned short* __restrict__ BT0, unsigned short* __restrict__ BT1)
{
    int idx = blockIdx.x * 256 + threadIdx.x;
    const int per_layer = 128 * 768;
    if (idx >= 2 * per_layer) return;
    int lyr = idx / per_layer;
    int rem = idx - lyr * per_layer;
    int n = rem / 768;
    int k = rem - n * 768;
    int seg = k >> 7;         // 0..5
    int ch = k & 127;
    const float* W = (lyr == 0) ? ((seg & 1) ? wn0 : ws0)
                                : ((seg & 1) ? wn1 : ws1);
    float v = W[ch * 128 + n];
    unsigned short hi = f2bf(v);
    unsigned short out = (seg < 4) ? hi : f2bf(v - bf2f(hi));
    (lyr == 0 ? BT0 : BT1)[(size_t)n * 768 + k] = out;
}

// ---------------------------------------------------------------------------
// CSR build: histogram -> hierarchical scan -> two-pass bucket scatter
// ---------------------------------------------------------------------------
__global__ __launch_bounds__(256) void hist_kernel(const int* __restrict__ dst,
                                                   int* __restrict__ counts)
{
    int i = blockIdx.x * blockDim.x + threadIdx.x;
    if (i < N_EDGES) atomicAdd(&counts[dst[i]], 1);
}

__global__ __launch_bounds__(256) void scan1_kernel(
    const int* __restrict__ counts, int* __restrict__ offsets,
    int* __restrict__ blk_sums)
{
    __shared__ int ws[4];
    int i = blockIdx.x * 256 + threadIdx.x;
    int c = (i < N_NODES) ? counts[i] : 0;
    int lane = threadIdx.x & 63, wid = threadIdx.x >> 6;
    int v = c;
#pragma unroll
    for (int off = 1; off < 64; off <<= 1) {
        int t = __shfl_up(v, off, 64);
        if (lane >= off) v += t;
    }
    if (lane == 63) ws[wid] = v;
    __syncthreads();
    if (threadIdx.x == 0) {
        int run = 0;
#pragma unroll
        for (int j = 0; j < 4; ++j) { int t = ws[j]; ws[j] = run; run += t; }
        blk_sums[blockIdx.x] = run;
    }
    __syncthreads();
    if (i < N_NODES) offsets[i] = ws[wid] + (v - c);
}

__global__ __launch_bounds__(256) void scan2_kernel(int* __restrict__ blk_sums)
{
    __shared__ int ws[4];
    int t = threadIdx.x;
    int c = (t < SCAN_BLOCKS) ? blk_sums[t] : 0;
    int lane = t & 63, wid = t >> 6;
    int v = c;
#pragma unroll
    for (int off = 1; off < 64; off <<= 1) {
        int s = __shfl_up(v, off, 64);
        if (lane >= off) v += s;
    }
    if (lane == 63) ws[wid] = v;
    __syncthreads();
    if (t == 0) {
        int run = 0;
#pragma unroll
        for (int j = 0; j < 4; ++j) { int s = ws[j]; ws[j] = run; run += s; }
    }
    __syncthreads();
    if (t < SCAN_BLOCKS) blk_sums[t] = ws[wid] + (v - c);
}

// phase 3: final offsets, deg, and bucket cursors (bucket b starts at
// offsets[256*b] since buckets are contiguous node ranges)
__global__ __launch_bounds__(256) void scan3_kernel(
    const int* __restrict__ counts, const int* __restrict__ blk_sums,
    int* __restrict__ offsets, float* __restrict__ deg,
    int* __restrict__ bucket_cursor)
{
    int i = blockIdx.x * 256 + threadIdx.x;
    if (i == 0) offsets[N_NODES] = N_EDGES;
    if (i >= N_NODES) return;
    int o = offsets[i] + blk_sums[blockIdx.x];
    offsets[i] = o;
    if ((i & 255) == 0) bucket_cursor[i >> 8] = o;
    int cnt = counts[i];
    deg[i] = (float)(cnt > 0 ? cnt : 1);
}

// bucket pass 1: bin (src,dst) pairs into coarse bucket regions.
// Per-block LDS histogram -> one returning global atomic per (block,bucket)
// -> contiguous per-chunk pair writes (no write amplification).
__global__ __launch_bounds__(256) void bucket1_kernel(
    const int* __restrict__ src, const int* __restrict__ dst,
    int* __restrict__ bucket_cursor, uint2* __restrict__ pairs)
{
    __shared__ int hist[NBUCKETS];
    __shared__ int base[NBUCKETS];
    __shared__ int cur[NBUCKETS];
    int tid = threadIdx.x;
    for (int i = tid; i < NBUCKETS; i += 256) { hist[i] = 0; cur[i] = 0; }
    __syncthreads();
    int ebeg = blockIdx.x * CHUNK1;
    int eend = ebeg + CHUNK1;
    if (eend > N_EDGES) eend = N_EDGES;
    for (int e = ebeg + tid; e < eend; e += 256)
        atomicAdd(&hist[dst[e] >> 8], 1);
    __syncthreads();
    for (int i = tid; i < NBUCKETS; i += 256)
        if (hist[i] > 0) base[i] = atomicAdd(&bucket_cursor[i], hist[i]);
    __syncthreads();
    for (int e = ebeg + tid; e < eend; e += 256) {
        int d = dst[e];
        int b = d >> 8;
        int pos = base[b] + atomicAdd(&cur[b], 1);
        pairs[pos] = make_uint2((unsigned)src[e], (unsigned)d);
    }
}

// bucket pass 2: one block per bucket; local 256-node CSR via LDS atomics;
// src_sorted writes land inside the bucket's ~16 KB region (L2-dense).
__global__ __launch_bounds__(256) void bucket2_kernel(
    const uint2* __restrict__ pairs, const int* __restrict__ offsets,
    int* __restrict__ src_sorted)
{
    __shared__ int noff[256];
    __shared__ int cur[256];
    int b = blockIdx.x;
    int n0 = b << 8;
    int tid = threadIdx.x;
    int nn = N_NODES - n0; if (nn > 256) nn = 256;
    if (tid < nn) noff[tid] = offsets[n0 + tid];
    cur[tid] = 0;
    __syncthreads();
    int rbeg = noff[0];
    int rend = (n0 + 256 <= N_NODES) ? offsets[n0 + 256] : N_EDGES;
    for (int e = rbeg + tid; e < rend; e += 256) {
        uint2 p = pairs[e];
        int local = p.y & 255;
        int pos = noff[local] + atomicAdd(&cur[local], 1);
        src_sorted[pos] = (int)p.x;
    }
}

// ---------------------------------------------------------------------------
// Aggregate: one wave per dst node, hi-plane ONLY (256 B rows).
// lane = h*16 + u: h picks edge within a group of 4, u is the 16 B unit.
// One wave-load covers FOUR edges; 16 edges per unrolled iter.
// ---------------------------------------------------------------------------
__global__ __launch_bounds__(256) void aggregate_kernel(
    const unsigned short* __restrict__ xh, const int* __restrict__ offsets,
    const int* __restrict__ src_sorted, const float* __restrict__ deg,
    unsigned short* __restrict__ ah, unsigned short* __restrict__ al)
{
    int wave = (blockIdx.x * blockDim.x + threadIdx.x) >> 6;
    int lane = threadIdx.x & 63;
    if (wave >= N_NODES) return;
    int h = lane >> 4;          // 0..3: which edge of a group
    int u = lane & 15;          // 16 B unit (8 channels)
    int beg = offsets[wave];
    int end = offsets[wave + 1];
    float acc[8];
#pragma unroll
    for (int j = 0; j < 8; ++j) acc[j] = 0.f;

    int e = beg;
    for (; e + 16 <= end; e += 16) {
        int sA = src_sorted[e + h];
        int sB = src_sorted[e + 4 + h];
        int sC = src_sorted[e + 8 + h];
        int sD = src_sorted[e + 12 + h];
        uint4 vA = *(const uint4*)(xh + (size_t)sA * 128 + u * 8);
        uint4 vB = *(const uint4*)(xh + (size_t)sB * 128 + u * 8);
        uint4 vC = *(const uint4*)(xh + (size_t)sC * 128 + u * 8);
        uint4 vD = *(const uint4*)(xh + (size_t)sD * 128 + u * 8);
        add8(acc, vA); add8(acc, vB); add8(acc, vC); add8(acc, vD);
    }
    for (; e + 4 <= end; e += 4) {
        int s = src_sorted[e + h];
        uint4 v = *(const uint4*)(xh + (size_t)s * 128 + u * 8);
        add8(acc, v);
    }
    int rem = end - e;
    if (h < rem) {
        int s = src_sorted[e + h];
        uint4 v = *(const uint4*)(xh + (size_t)s * 128 + u * 8);
        add8(acc, v);
    }

#pragma unroll
    for (int j = 0; j < 8; ++j) {
        acc[j] += __shfl_xor(acc[j], 16);
        acc[j] += __shfl_xor(acc[j], 32);
    }
    if (lane < 16) {
        float inv = 1.0f / deg[wave];
        short8 hv, lv;
#pragma unroll
        for (int j = 0; j < 8; ++j) {
            float t = acc[j] * inv;
            unsigned short hi = f2bf(t);
            hv[j] = (short)hi;
            lv[j] = (short)f2bf(t - bf2f(hi));
        }
        *(short8*)(ah + (size_t)wave * 128 + u * 8) = hv;
        *(short8*)(al + (size_t)wave * 128 + u * 8) = lv;
    }
}

// ---------------------------------------------------------------------------
// Layer GEMM: 512 thr / 8 waves, tile 128x128, K=768 in 6 chunks of 128.
// A-chunk bases {xh, ah, xl, al, xh, ah}; B = BT[n][768] matching segs.
// XOR-swizzled LDS; epilogue bounced through LDS -> coalesced uint4 stores.
// ---------------------------------------------------------------------------
#define BM 128
__global__ __launch_bounds__(512) void gemm_mfma(
    unsigned short* __restrict__ xh, unsigned short* __restrict__ xl,
    const unsigned short* __restrict__ ah, const unsigned short* __restrict__ al,
    const unsigned short* __restrict__ BT, const float* __restrict__ bias,
    int relu)
{
    __shared__ uint4 smem4[4096];           // 64 KB: As 32K | Bs 32K
    char* As = (char*)smem4;
    char* Bs = (char*)smem4 + 32768;
    __shared__ float bias_s[C];

    int tid = threadIdx.x;
    int w = tid >> 6, l = tid & 63;
    int row0 = blockIdx.x * BM;
    if (tid < C) bias_s[tid] = bias[tid];

    f32x4 acc[2][4];
#pragma unroll
    for (int mt = 0; mt < 2; ++mt)
#pragma unroll
        for (int nt = 0; nt < 4; ++nt)
            acc[mt][nt] = (f32x4)(0.f);

    int wm = w & 3;     // row quarter
    int wn = w >> 2;    // col half
    int quad = l >> 4;
    int mrow = l & 15;

    const unsigned short* abases[6] = {xh, ah, xl, al, xh, ah};

    for (int c = 0; c < 6; ++c) {
        const char* abase = (const char*)abases[c];
#pragma unroll
        for (int i = 0; i < 4; ++i) {
            int off = i * 8192 + tid * 16;
            int rl = off >> 8;
            int row = row0 + rl;
            if (row > N_NODES - 1) row = N_NODES - 1;
            int u = ((off >> 4) & 15) ^ (rl & 15);
            async16(As + off, abase + (size_t)row * 256 + u * 16);
        }
#pragma unroll
        for (int i = 0; i < 4; ++i) {
            int off = i * 8192 + tid * 16;
            int n = off >> 8;
            int u = ((off >> 4) & 15) ^ (n & 15);
            async16(Bs + off, (const char*)BT + (size_t)n * 1536 + c * 256 + u * 16);
        }
        __syncthreads();
#pragma unroll
        for (int ks = 0; ks < 4; ++ks) {
            int cu = ks * 4 + quad;             // unit 0..15
            int swz = (cu ^ mrow) * 16;
            short8 a0 = *(const short8*)(As + (wm * 32 + mrow) * 256 + swz);
            short8 a1 = *(const short8*)(As + (wm * 32 + 16 + mrow) * 256 + swz);
            short8 b[4];
#pragma unroll
            for (int nt = 0; nt < 4; ++nt)
                b[nt] = *(const short8*)(Bs + (wn * 64 + nt * 16 + mrow) * 256 + swz);
#pragma unroll
            for (int nt = 0; nt < 4; ++nt) {
                acc[0][nt] = __builtin_amdgcn_mfma_f32_16x16x32_bf16(a0, b[nt], acc[0][nt], 0, 0, 0);
                acc[1][nt] = __builtin_amdgcn_mfma_f32_16x16x32_bf16(a1, b[nt], acc[1][nt], 0, 0, 0);
            }
        }
        __syncthreads();
    }

    // epilogue: hi tile + lo tile in LDS, then coalesced uint4 copy-out
    char* th = (char*)smem4;            // 32 KB: 128 rows x 256 B
    char* tl = (char*)smem4 + 32768;
#pragma unroll
    for (int mt = 0; mt < 2; ++mt)
#pragma unroll
        for (int nt = 0; nt < 4; ++nt) {
            int col = wn * 64 + nt * 16 + mrow;
            float bb = bias_s[col];
#pragma unroll
            for (int r = 0; r < 4; ++r) {
                int rl = wm * 32 + mt * 16 + quad * 4 + r;
                float v = acc[mt][nt][r] + bb;
                if (relu) v = fmaxf(v, 0.f);
                unsigned short hi = f2bf(v);
                *(unsigned short*)(th + rl * 256 + col * 2) = hi;
                *(unsigned short*)(tl + rl * 256 + col * 2) = f2bf(v - bf2f(hi));
            }
        }
    __syncthreads();
#pragma unroll
    for (int i = 0; i < 4; ++i) {
        int off = i * 8192 + tid * 16;
        int row = row0 + (off >> 8);
        if (row < N_NODES)
            *(uint4*)((char*)xh + (size_t)row0 * 256 + off) = *(const uint4*)(th + off);
    }
#pragma unroll
    for (int i = 0; i < 4; ++i) {
        int off = i * 8192 + tid * 16;
        int row = row0 + (off >> 8);
        if (row < N_NODES)
            *(uint4*)((char*)xl + (size_t)row0 * 256 + off) = *(const uint4*)(tl + off);
    }
}

// ---------------------------------------------------------------------------
// Head: out = x @ head_w + head_b   [N,128] @ [128,16]
// ---------------------------------------------------------------------------
__global__ __launch_bounds__(256) void head_kernel(
    const unsigned short* __restrict__ xh, const unsigned short* __restrict__ xl,
    const float* __restrict__ hw, const float* __restrict__ hb,
    float* __restrict__ out)
{
    __shared__ float w[C * OUT_DIM];
    __shared__ float b[OUT_DIM];
    for (int i = threadIdx.x; i < C * OUT_DIM; i += blockDim.x) w[i] = hw[i];
    if (threadIdx.x < OUT_DIM) b[threadIdx.x] = hb[threadIdx.x];
    __syncthreads();

    int node = blockIdx.x * 16 + (threadIdx.x >> 4);
    int c = threadIdx.x & 15;
    if (node >= N_NODES) return;
    float acc = b[c];
    const uint2* rh = (const uint2*)(xh + (size_t)node * 128);
    const uint2* rl = (const uint2*)(xl + (size_t)node * 128);
#pragma unroll 8
    for (int kk = 0; kk < 32; ++kk) {   // 4 channels per iter
        uint2 vh = rh[kk];
        uint2 vl = rl[kk];
        int k = kk * 4;
        acc += (lo_f(vh.x) + lo_f(vl.x)) * w[k * OUT_DIM + c];
        acc += (hi_f(vh.x) + hi_f(vl.x)) * w[(k + 1) * OUT_DIM + c];
        acc += (lo_f(vh.y) + lo_f(vl.y)) * w[(k + 2) * OUT_DIM + c];
        acc += (hi_f(vh.y) + hi_f(vl.y)) * w[(k + 3) * OUT_DIM + c];
    }
    out[(size_t)node * OUT_DIM + c] = acc;
}

// ---------------------------------------------------------------------------
extern "C" void kernel_launch(void* const* d_in, const int* in_sizes, int n_in,
                              void* d_out, int out_size, void* d_ws, size_t ws_size,
                              hipStream_t stream)
{
    const float* feats0 = (const float*)d_in[0];
    const float* feats1 = (const float*)d_in[1];
    const float* enc_w0 = (const float*)d_in[2];
    const float* enc_b0 = (const float*)d_in[3];
    const float* enc_w1 = (const float*)d_in[4];
    const float* enc_b1 = (const float*)d_in[5];
    const float* w_self0 = (const float*)d_in[6];
    const float* w_neigh0 = (const float*)d_in[7];
    const float* b0 = (const float*)d_in[8];
    const float* w_self1 = (const float*)d_in[9];
    const float* w_neigh1 = (const float*)d_in[10];
    const float* b1 = (const float*)d_in[11];
    const float* head_w = (const float*)d_in[12];
    const float* head_b = (const float*)d_in[13];
    const int* node_row_idx = (const int*)d_in[14];
    const int* edge_index = (const int*)d_in[15];
    const int* e_src = edge_index;
    const int* e_dst = edge_index + N_EDGES;

    char* p = (char*)d_ws;
    unsigned short* xh = (unsigned short*)p;  p += (size_t)N_NODES * C * 2;
    unsigned short* xl = (unsigned short*)p;  p += (size_t)N_NODES * C * 2;
    unsigned short* ah = (unsigned short*)p;  p += (size_t)N_NODES * C * 2;
    unsigned short* al = (unsigned short*)p;  p += (size_t)N_NODES * C * 2;
    unsigned short* BT0 = (unsigned short*)p; p += (size_t)128 * 768 * 2;
    unsigned short* BT1 = (unsigned short*)p; p += (size_t)128 * 768 * 2;
    float* deg = (float*)p;      p += (size_t)N_NODES * 4;
    int* counts = (int*)p;       p += (size_t)N_NODES * 4;
    int* offsets = (int*)p;      p += (size_t)(N_NODES + 8) * 4;
    int* blk_sums = (int*)p;     p += (size_t)(SCAN_BLOCKS + 8) * 4;
    int* bucket_cursor = (int*)p; p += (size_t)(NBUCKETS + 8) * 4;
    int* src_sorted = (int*)p;   p += (size_t)N_EDGES * 4;
    // pairs buffer aliases ah/al (unwritten until aggregate, which runs
    // after bucket2 on the same stream): 800K * 8 B = 6.4 MB <= 12.8 MB
    uint2* pairs = (uint2*)ah;

    hipMemsetAsync(counts, 0, (size_t)N_NODES * sizeof(int), stream);

    encode_kernel<<<512, 256, 0, stream>>>(feats0, feats1, enc_w0, enc_b0,
                                           enc_w1, enc_b1, node_row_idx, xh, xl);
    prep_weights<<<(2 * 128 * 768 + 255) / 256, 256, 0, stream>>>(
        w_self0, w_neigh0, w_self1, w_neigh1, BT0, BT1);

    hist_kernel<<<(N_EDGES + 255) / 256, 256, 0, stream>>>(e_dst, counts);
    scan1_kernel<<<SCAN_BLOCKS, 256, 0, stream>>>(counts, offsets, blk_sums);
    scan2_kernel<<<1, 256, 0, stream>>>(blk_sums);
    scan3_kernel<<<SCAN_BLOCKS, 256, 0, stream>>>(counts, blk_sums, offsets,
                                                  deg, bucket_cursor);
    bucket1_kernel<<<NB1, 256, 0, stream>>>(e_src, e_dst, bucket_cursor, pairs);
    bucket2_kernel<<<NBUCKETS, 256, 0, stream>>>(pairs, offsets, src_sorted);

    // Layer 0
    aggregate_kernel<<<(N_NODES * 64 + 255) / 256, 256, 0, stream>>>(
        xh, offsets, src_sorted, deg, ah, al);
    gemm_mfma<<<(N_NODES + BM - 1) / BM, 512, 0, stream>>>(
        xh, xl, ah, al, BT0, b0, 1);

    // Layer 1
    aggregate_kernel<<<(N_NODES * 64 + 255) / 256, 256, 0, stream>>>(
        xh, offsets, src_sorted, deg, ah, al);
    gemm_mfma<<<(N_NODES + BM - 1) / BM, 512, 0, stream>>>(
        xh, xl, ah, al, BT1, b1, 0);

    head_kernel<<<(N_NODES + 15) / 16, 256, 0, stream>>>(xh, xl, head_w, head_b,
                                                         (float*)d_out);
}

// Round 9
// 273.817 us; speedup vs baseline: 2.8764x; 1.1393x over previous
//
#include <hip/hip_runtime.h>
#include <hip/hip_bf16.h>

#define N_NODES 50000
#define N_EDGES 800000
#define C 128
#define D_IN 32
#define T0 25000
#define OUT_DIM 16
#define NBUCKETS ((N_NODES + 255) / 256)      // 196, bucket = dst>>8
#define NB1 512
#define CHUNK1 ((N_EDGES + NB1 - 1) / NB1)    // 1563

// Feature storage: planes xh[N][128] (bf16 hi), xl[N][128] (bf16 lo);
// agg: ah only (lo-correction of the neighbor path is ~6e-4 -> dropped).
// GEMM K=512: segs {xh*Ws_hi, ah*Wn_hi, xl*Ws_hi, xh*Ws_lo}.

typedef __attribute__((ext_vector_type(8))) short short8;
typedef __attribute__((ext_vector_type(4))) float f32x4;

__device__ __forceinline__ unsigned short f2bf(float f) {
    union { float f; unsigned int i; } u; u.f = f;
    unsigned int x = u.i;
    unsigned int r = x + 0x7fffu + ((x >> 16) & 1u);
    return (unsigned short)(r >> 16);
}
__device__ __forceinline__ float bf2f(unsigned short h) {
    union { unsigned int i; float f; } u; u.i = ((unsigned int)h) << 16;
    return u.f;
}
__device__ __forceinline__ float lo_f(unsigned int w) {
    union { unsigned int i; float f; } u; u.i = w << 16;
    return u.f;
}
__device__ __forceinline__ float hi_f(unsigned int w) {
    union { unsigned int i; float f; } u; u.i = w & 0xffff0000u;
    return u.f;
}
__device__ __forceinline__ void async16(void* lds, const void* g) {
    __builtin_amdgcn_global_load_lds(
        (const __attribute__((address_space(1))) void*)g,
        (__attribute__((address_space(3))) void*)lds, 16, 0, 0);
}
__device__ __forceinline__ void add8(float* a, uint4 v) {
    a[0] += lo_f(v.x); a[1] += hi_f(v.x);
    a[2] += lo_f(v.y); a[3] += hi_f(v.y);
    a[4] += lo_f(v.z); a[5] += hi_f(v.z);
    a[6] += lo_f(v.w); a[7] += hi_f(v.w);
}

// ---------------------------------------------------------------------------
// Encode: 16 threads per node, 8 channels per thread -> short8 per plane.
// ---------------------------------------------------------------------------
__global__ __launch_bounds__(256) void encode_kernel(
    const float* __restrict__ feats0, const float* __restrict__ feats1,
    const float* __restrict__ w0, const float* __restrict__ b0,
    const float* __restrict__ w1, const float* __restrict__ b1,
    const int* __restrict__ row_idx,
    unsigned short* __restrict__ xh, unsigned short* __restrict__ xl)
{
    __shared__ float sw0[D_IN * C];
    __shared__ float sw1[D_IN * C];
    __shared__ float sb0[C];
    __shared__ float sb1[C];
    for (int i = threadIdx.x; i < D_IN * C; i += blockDim.x) {
        sw0[i] = w0[i];
        sw1[i] = w1[i];
    }
    if (threadIdx.x < C) {
        sb0[threadIdx.x] = b0[threadIdx.x];
        sb1[threadIdx.x] = b1[threadIdx.x];
    }
    __syncthreads();

    int j = threadIdx.x & 15;
    int ln = threadIdx.x >> 4;
    for (int n = blockIdx.x * 16 + ln; n < N_NODES; n += gridDim.x * 16) {
        int r = row_idx[n];
        const float* f = (r < T0) ? (feats0 + (size_t)r * D_IN)
                                  : (feats1 + (size_t)(r - T0) * D_IN);
        const float* W = (r < T0) ? sw0 : sw1;
        const float* B = (r < T0) ? sb0 : sb1;
        float4 f4[8];
#pragma unroll
        for (int i = 0; i < 8; ++i) f4[i] = ((const float4*)f)[i];
        float acc[8];
#pragma unroll
        for (int cc = 0; cc < 8; ++cc) acc[cc] = B[8 * j + cc];
#pragma unroll
        for (int k = 0; k < D_IN; ++k) {
            float fk = ((const float*)f4)[k];
            float4 wa = *(const float4*)&W[k * C + 8 * j];
            float4 wb = *(const float4*)&W[k * C + 8 * j + 4];
            acc[0] += fk * wa.x; acc[1] += fk * wa.y;
            acc[2] += fk * wa.z; acc[3] += fk * wa.w;
            acc[4] += fk * wb.x; acc[5] += fk * wb.y;
            acc[6] += fk * wb.z; acc[7] += fk * wb.w;
        }
        short8 h8, l8;
#pragma unroll
        for (int cc = 0; cc < 8; ++cc) {
            unsigned short hi = f2bf(acc[cc]);
            h8[cc] = (short)hi;
            l8[cc] = (short)f2bf(acc[cc] - bf2f(hi));
        }
        *(short8*)(xh + (size_t)n * 128 + 8 * j) = h8;
        *(short8*)(xl + (size_t)n * 128 + 8 * j) = l8;
    }
}

// ---------------------------------------------------------------------------
// Weight prep: BT[layer][n][k], k in [0,512), 4 segments of 128 channels:
//   seg0: hi(Ws)  seg1: hi(Wn)  seg2: hi(Ws)  seg3: lo(Ws)
// Pairs with A-chunk order {xh, ah, xl, xh}.
// ---------------------------------------------------------------------------
__global__ __launch_bounds__(256) void prep_weights(
    const float* __restrict__ ws0, const float* __restrict__ wn0,
    const float* __restrict__ ws1, const float* __restrict__ wn1,
    unsigned short* __restrict__ BT0, unsigned short* __restrict__ BT1)
{
    int idx = blockIdx.x * 256 + threadIdx.x;
    const int per_layer = 128 * 512;
    if (idx >= 2 * per_layer) return;
    int lyr = idx / per_layer;
    int rem = idx - lyr * per_layer;
    int n = rem >> 9;
    int k = rem & 511;
    int seg = k >> 7;         // 0..3
    int ch = k & 127;
    const float* W = (lyr == 0) ? ((seg == 1) ? wn0 : ws0)
                                : ((seg == 1) ? wn1 : ws1);
    float v = W[ch * 128 + n];
    unsigned short hi = f2bf(v);
    unsigned short out = (seg == 3) ? f2bf(v - bf2f(hi)) : hi;
    (lyr == 0 ? BT0 : BT1)[(size_t)n * 512 + k] = out;
}

// ---------------------------------------------------------------------------
// CSR build: bucket hist (196) -> tiny scan -> bucket scatter -> local CSR
// ---------------------------------------------------------------------------
__global__ __launch_bounds__(256) void histb_kernel(
    const int* __restrict__ dst, int* __restrict__ bucket_counts)
{
    __shared__ int h[NBUCKETS];
    for (int i = threadIdx.x; i < NBUCKETS; i += 256) h[i] = 0;
    __syncthreads();
    for (int e = blockIdx.x * 256 + threadIdx.x; e < N_EDGES; e += gridDim.x * 256)
        atomicAdd(&h[dst[e] >> 8], 1);
    __syncthreads();
    for (int i = threadIdx.x; i < NBUCKETS; i += 256)
        if (h[i]) atomicAdd(&bucket_counts[i], h[i]);
}

__global__ __launch_bounds__(256) void scanb_kernel(
    const int* __restrict__ bucket_counts, int* __restrict__ bucket_base,
    int* __restrict__ bucket_cursor, int* __restrict__ offsets)
{
    __shared__ int ws[4];
    int t = threadIdx.x;
    int c = (t < NBUCKETS) ? bucket_counts[t] : 0;
    int lane = t & 63, wid = t >> 6;
    int v = c;
#pragma unroll
    for (int off = 1; off < 64; off <<= 1) {
        int s = __shfl_up(v, off, 64);
        if (lane >= off) v += s;
    }
    if (lane == 63) ws[wid] = v;
    __syncthreads();
    if (t == 0) {
        int run = 0;
#pragma unroll
        for (int j = 0; j < 4; ++j) { int s = ws[j]; ws[j] = run; run += s; }
    }
    __syncthreads();
    int excl = ws[wid] + (v - c);
    if (t < NBUCKETS) {
        bucket_base[t] = excl;
        bucket_cursor[t] = excl;
    }
    if (t == 0) {
        bucket_base[NBUCKETS] = N_EDGES;
        offsets[N_NODES] = N_EDGES;
    }
}

// bucket pass 1: bin (src,dst) pairs into coarse bucket regions.
__global__ __launch_bounds__(256) void bucket1_kernel(
    const int* __restrict__ src, const int* __restrict__ dst,
    int* __restrict__ bucket_cursor, uint2* __restrict__ pairs)
{
    __shared__ int hist[NBUCKETS];
    __shared__ int base[NBUCKETS];
    __shared__ int cur[NBUCKETS];
    int tid = threadIdx.x;
    for (int i = tid; i < NBUCKETS; i += 256) { hist[i] = 0; cur[i] = 0; }
    __syncthreads();
    int ebeg = blockIdx.x * CHUNK1;
    int eend = ebeg + CHUNK1;
    if (eend > N_EDGES) eend = N_EDGES;
    for (int e = ebeg + tid; e < eend; e += 256)
        atomicAdd(&hist[dst[e] >> 8], 1);
    __syncthreads();
    for (int i = tid; i < NBUCKETS; i += 256)
        if (hist[i] > 0) base[i] = atomicAdd(&bucket_cursor[i], hist[i]);
    __syncthreads();
    for (int e = ebeg + tid; e < eend; e += 256) {
        int d = dst[e];
        int b = d >> 8;
        int pos = base[b] + atomicAdd(&cur[b], 1);
        pairs[pos] = make_uint2((unsigned)src[e], (unsigned)d);
    }
}

// bucket pass 2: one block per bucket; derive local per-node CSR (offsets,
// deg) from the region, then place src into src_sorted (L2-dense writes).
__global__ __launch_bounds__(256) void bucket2_kernel(
    const uint2* __restrict__ pairs, const int* __restrict__ bucket_base,
    int* __restrict__ offsets, float* __restrict__ deg,
    int* __restrict__ src_sorted)
{
    __shared__ int cnt[256];
    __shared__ int noff[256];
    __shared__ int cur[256];
    __shared__ int ws[4];
    int b = blockIdx.x;
    int n0 = b << 8;
    int tid = threadIdx.x;
    int bb = bucket_base[b];
    int be = bucket_base[b + 1];
    cnt[tid] = 0;
    cur[tid] = 0;
    __syncthreads();
    for (int e = bb + tid; e < be; e += 256)
        atomicAdd(&cnt[pairs[e].y & 255], 1);
    __syncthreads();
    int c = cnt[tid];
    int lane = tid & 63, wid = tid >> 6;
    int v = c;
#pragma unroll
    for (int off = 1; off < 64; off <<= 1) {
        int s = __shfl_up(v, off, 64);
        if (lane >= off) v += s;
    }
    if (lane == 63) ws[wid] = v;
    __syncthreads();
    if (tid == 0) {
        int run = 0;
#pragma unroll
        for (int j = 0; j < 4; ++j) { int s = ws[j]; ws[j] = run; run += s; }
    }
    __syncthreads();
    int o = bb + ws[wid] + (v - c);
    noff[tid] = o;
    int n = n0 + tid;
    if (n < N_NODES) {
        offsets[n] = o;
        deg[n] = (float)(c > 0 ? c : 1);
    }
    __syncthreads();
    for (int e = bb + tid; e < be; e += 256) {
        uint2 p = pairs[e];
        int local = p.y & 255;
        int pos = noff[local] + atomicAdd(&cur[local], 1);
        src_sorted[pos] = (int)p.x;
    }
}

// ---------------------------------------------------------------------------
// Aggregate: one wave per dst node, hi-plane ONLY (256 B rows).
// lane = h*16 + u: one wave-load covers FOUR edges; 16 edges per iter.
// Output: ah only (bf16 of the mean).
// ---------------------------------------------------------------------------
__global__ __launch_bounds__(256) void aggregate_kernel(
    const unsigned short* __restrict__ xh, const int* __restrict__ offsets,
    const int* __restrict__ src_sorted, const float* __restrict__ deg,
    unsigned short* __restrict__ ah)
{
    int wave = (blockIdx.x * blockDim.x + threadIdx.x) >> 6;
    int lane = threadIdx.x & 63;
    if (wave >= N_NODES) return;
    int h = lane >> 4;
    int u = lane & 15;
    int beg = offsets[wave];
    int end = offsets[wave + 1];
    float acc[8];
#pragma unroll
    for (int j = 0; j < 8; ++j) acc[j] = 0.f;

    int e = beg;
    for (; e + 16 <= end; e += 16) {
        int sA = src_sorted[e + h];
        int sB = src_sorted[e + 4 + h];
        int sC = src_sorted[e + 8 + h];
        int sD = src_sorted[e + 12 + h];
        uint4 vA = *(const uint4*)(xh + (size_t)sA * 128 + u * 8);
        uint4 vB = *(const uint4*)(xh + (size_t)sB * 128 + u * 8);
        uint4 vC = *(const uint4*)(xh + (size_t)sC * 128 + u * 8);
        uint4 vD = *(const uint4*)(xh + (size_t)sD * 128 + u * 8);
        add8(acc, vA); add8(acc, vB); add8(acc, vC); add8(acc, vD);
    }
    for (; e + 4 <= end; e += 4) {
        int s = src_sorted[e + h];
        uint4 v = *(const uint4*)(xh + (size_t)s * 128 + u * 8);
        add8(acc, v);
    }
    int rem = end - e;
    if (h < rem) {
        int s = src_sorted[e + h];
        uint4 v = *(const uint4*)(xh + (size_t)s * 128 + u * 8);
        add8(acc, v);
    }

#pragma unroll
    for (int j = 0; j < 8; ++j) {
        acc[j] += __shfl_xor(acc[j], 16);
        acc[j] += __shfl_xor(acc[j], 32);
    }
    if (lane < 16) {
        float inv = 1.0f / deg[wave];
        short8 hv;
#pragma unroll
        for (int j = 0; j < 8; ++j)
            hv[j] = (short)f2bf(acc[j] * inv);
        *(short8*)(ah + (size_t)wave * 128 + u * 8) = hv;
    }
}

// ---------------------------------------------------------------------------
// Layer GEMM: 512 thr / 8 waves, tile 128x128, K=512 in 4 chunks of 128.
// A-chunk bases {xh, ah, xl, xh}; B = BT[n][512] segs {Wsh, Wnh, Wsh, Wsl}.
// XOR-swizzled LDS; epilogue bounced through LDS -> coalesced uint4 stores.
// ---------------------------------------------------------------------------
#define BM 128
__global__ __launch_bounds__(512) void gemm_mfma(
    unsigned short* __restrict__ xh, unsigned short* __restrict__ xl,
    const unsigned short* __restrict__ ah,
    const unsigned short* __restrict__ BT, const float* __restrict__ bias,
    int relu)
{
    __shared__ uint4 smem4[4096];           // 64 KB: As 32K | Bs 32K
    char* As = (char*)smem4;
    char* Bs = (char*)smem4 + 32768;
    __shared__ float bias_s[C];

    int tid = threadIdx.x;
    int w = tid >> 6, l = tid & 63;
    int row0 = blockIdx.x * BM;
    if (tid < C) bias_s[tid] = bias[tid];

    f32x4 acc[2][4];
#pragma unroll
    for (int mt = 0; mt < 2; ++mt)
#pragma unroll
        for (int nt = 0; nt < 4; ++nt)
            acc[mt][nt] = (f32x4)(0.f);

    int wm = w & 3;
    int wn = w >> 2;
    int quad = l >> 4;
    int mrow = l & 15;

    const unsigned short* abases[4] = {xh, ah, xl, xh};

    for (int c = 0; c < 4; ++c) {
        const char* abase = (const char*)abases[c];
#pragma unroll
        for (int i = 0; i < 4; ++i) {
            int off = i * 8192 + tid * 16;
            int rl = off >> 8;
            int row = row0 + rl;
            if (row > N_NODES - 1) row = N_NODES - 1;
            int u = ((off >> 4) & 15) ^ (rl & 15);
            async16(As + off, abase + (size_t)row * 256 + u * 16);
        }
#pragma unroll
        for (int i = 0; i < 4; ++i) {
            int off = i * 8192 + tid * 16;
            int n = off >> 8;
            int u = ((off >> 4) & 15) ^ (n & 15);
            async16(Bs + off, (const char*)BT + (size_t)n * 1024 + c * 256 + u * 16);
        }
        __syncthreads();
#pragma unroll
        for (int ks = 0; ks < 4; ++ks) {
            int cu = ks * 4 + quad;
            int swz = (cu ^ mrow) * 16;
            short8 a0 = *(const short8*)(As + (wm * 32 + mrow) * 256 + swz);
            short8 a1 = *(const short8*)(As + (wm * 32 + 16 + mrow) * 256 + swz);
            short8 b[4];
#pragma unroll
            for (int nt = 0; nt < 4; ++nt)
                b[nt] = *(const short8*)(Bs + (wn * 64 + nt * 16 + mrow) * 256 + swz);
#pragma unroll
            for (int nt = 0; nt < 4; ++nt) {
                acc[0][nt] = __builtin_amdgcn_mfma_f32_16x16x32_bf16(a0, b[nt], acc[0][nt], 0, 0, 0);
                acc[1][nt] = __builtin_amdgcn_mfma_f32_16x16x32_bf16(a1, b[nt], acc[1][nt], 0, 0, 0);
            }
        }
        __syncthreads();
    }

    // epilogue: hi tile + lo tile in LDS, then coalesced uint4 copy-out
    char* th = (char*)smem4;            // 32 KB: 128 rows x 256 B
    char* tl = (char*)smem4 + 32768;
#pragma unroll
    for (int mt = 0; mt < 2; ++mt)
#pragma unroll
        for (int nt = 0; nt < 4; ++nt) {
            int col = wn * 64 + nt * 16 + mrow;
            float bb = bias_s[col];
#pragma unroll
            for (int r = 0; r < 4; ++r) {
                int rl = wm * 32 + mt * 16 + quad * 4 + r;
                float v = acc[mt][nt][r] + bb;
                if (relu) v = fmaxf(v, 0.f);
                unsigned short hi = f2bf(v);
                *(unsigned short*)(th + rl * 256 + col * 2) = hi;
                *(unsigned short*)(tl + rl * 256 + col * 2) = f2bf(v - bf2f(hi));
            }
        }
    __syncthreads();
#pragma unroll
    for (int i = 0; i < 4; ++i) {
        int off = i * 8192 + tid * 16;
        int row = row0 + (off >> 8);
        if (row < N_NODES)
            *(uint4*)((char*)xh + (size_t)row0 * 256 + off) = *(const uint4*)(th + off);
    }
#pragma unroll
    for (int i = 0; i < 4; ++i) {
        int off = i * 8192 + tid * 16;
        int row = row0 + (off >> 8);
        if (row < N_NODES)
            *(uint4*)((char*)xl + (size_t)row0 * 256 + off) = *(const uint4*)(tl + off);
    }
}

// ---------------------------------------------------------------------------
// Head: out = x @ head_w + head_b   [N,128] @ [128,16]
// ---------------------------------------------------------------------------
__global__ __launch_bounds__(256) void head_kernel(
    const unsigned short* __restrict__ xh, const unsigned short* __restrict__ xl,
    const float* __restrict__ hw, const float* __restrict__ hb,
    float* __restrict__ out)
{
    __shared__ float w[C * OUT_DIM];
    __shared__ float b[OUT_DIM];
    for (int i = threadIdx.x; i < C * OUT_DIM; i += blockDim.x) w[i] = hw[i];
    if (threadIdx.x < OUT_DIM) b[threadIdx.x] = hb[threadIdx.x];
    __syncthreads();

    int node = blockIdx.x * 16 + (threadIdx.x >> 4);
    int c = threadIdx.x & 15;
    if (node >= N_NODES) return;
    float acc = b[c];
    const uint2* rh = (const uint2*)(xh + (size_t)node * 128);
    const uint2* rl = (const uint2*)(xl + (size_t)node * 128);
#pragma unroll 8
    for (int kk = 0; kk < 32; ++kk) {
        uint2 vh = rh[kk];
        uint2 vl = rl[kk];
        int k = kk * 4;
        acc += (lo_f(vh.x) + lo_f(vl.x)) * w[k * OUT_DIM + c];
        acc += (hi_f(vh.x) + hi_f(vl.x)) * w[(k + 1) * OUT_DIM + c];
        acc += (lo_f(vh.y) + lo_f(vl.y)) * w[(k + 2) * OUT_DIM + c];
        acc += (hi_f(vh.y) + hi_f(vl.y)) * w[(k + 3) * OUT_DIM + c];
    }
    out[(size_t)node * OUT_DIM + c] = acc;
}

// ---------------------------------------------------------------------------
extern "C" void kernel_launch(void* const* d_in, const int* in_sizes, int n_in,
                              void* d_out, int out_size, void* d_ws, size_t ws_size,
                              hipStream_t stream)
{
    const float* feats0 = (const float*)d_in[0];
    const float* feats1 = (const float*)d_in[1];
    const float* enc_w0 = (const float*)d_in[2];
    const float* enc_b0 = (const float*)d_in[3];
    const float* enc_w1 = (const float*)d_in[4];
    const float* enc_b1 = (const float*)d_in[5];
    const float* w_self0 = (const float*)d_in[6];
    const float* w_neigh0 = (const float*)d_in[7];
    const float* b0 = (const float*)d_in[8];
    const float* w_self1 = (const float*)d_in[9];
    const float* w_neigh1 = (const float*)d_in[10];
    const float* b1 = (const float*)d_in[11];
    const float* head_w = (const float*)d_in[12];
    const float* head_b = (const float*)d_in[13];
    const int* node_row_idx = (const int*)d_in[14];
    const int* edge_index = (const int*)d_in[15];
    const int* e_src = edge_index;
    const int* e_dst = edge_index + N_EDGES;

    char* p = (char*)d_ws;
    unsigned short* xh = (unsigned short*)p;  p += (size_t)N_NODES * C * 2;
    unsigned short* xl = (unsigned short*)p;  p += (size_t)N_NODES * C * 2;
    unsigned short* ah = (unsigned short*)p;  p += (size_t)N_NODES * C * 2;
    unsigned short* BT0 = (unsigned short*)p; p += (size_t)128 * 512 * 2;
    unsigned short* BT1 = (unsigned short*)p; p += (size_t)128 * 512 * 2;
    float* deg = (float*)p;        p += (size_t)N_NODES * 4;
    int* offsets = (int*)p;        p += (size_t)(N_NODES + 8) * 4;
    int* bucket_counts = (int*)p;  p += (size_t)(NBUCKETS + 8) * 4;
    int* bucket_base = (int*)p;    p += (size_t)(NBUCKETS + 8) * 4;
    int* bucket_cursor = (int*)p;  p += (size_t)(NBUCKETS + 8) * 4;
    int* src_sorted = (int*)p;     p += (size_t)N_EDGES * 4;
    // pairs aliases ah (ah unwritten until aggregate, which runs after
    // bucket2 on the same stream): 800K * 8 B = 6.4 MB <= 12.8 MB
    uint2* pairs = (uint2*)ah;

    hipMemsetAsync(bucket_counts, 0, (size_t)(NBUCKETS + 8) * 4, stream);

    encode_kernel<<<512, 256, 0, stream>>>(feats0, feats1, enc_w0, enc_b0,
                                           enc_w1, enc_b1, node_row_idx, xh, xl);
    prep_weights<<<(2 * 128 * 512 + 255) / 256, 256, 0, stream>>>(
        w_self0, w_neigh0, w_self1, w_neigh1, BT0, BT1);

    histb_kernel<<<512, 256, 0, stream>>>(e_dst, bucket_counts);
    scanb_kernel<<<1, 256, 0, stream>>>(bucket_counts, bucket_base,
                                        bucket_cursor, offsets);
    bucket1_kernel<<<NB1, 256, 0, stream>>>(e_src, e_dst, bucket_cursor, pairs);
    bucket2_kernel<<<NBUCKETS, 256, 0, stream>>>(pairs, bucket_base, offsets,
                                                 deg, src_sorted);

    // Layer 0
    aggregate_kernel<<<(N_NODES * 64 + 255) / 256, 256, 0, stream>>>(
        xh, offsets, src_sorted, deg, ah);
    gemm_mfma<<<(N_NODES + BM - 1) / BM, 512, 0, stream>>>(
        xh, xl, ah, BT0, b0, 1);

    // Layer 1
    aggregate_kernel<<<(N_NODES * 64 + 255) / 256, 256, 0, stream>>>(
        xh, offsets, src_sorted, deg, ah);
    gemm_mfma<<<(N_NODES + BM - 1) / BM, 512, 0, stream>>>(
        xh, xl, ah, BT1, b1, 0);

    head_kernel<<<(N_NODES + 15) / 16, 256, 0, stream>>>(xh, xl, head_w, head_b,
                                                         (float*)d_out);
}

// Round 10
// 246.505 us; speedup vs baseline: 3.1951x; 1.1108x over previous
//
#include <hip/hip_runtime.h>
#include <hip/hip_bf16.h>

#define N_NODES 50000
#define N_EDGES 800000
#define C 128
#define D_IN 32
#define T0 25000
#define OUT_DIM 16
#define NBUCKETS ((N_NODES + 255) / 256)      // 196, bucket = dst>>8
#define NB1 512
#define CHUNK1 ((N_EDGES + NB1 - 1) / NB1)    // 1563
#define ENC_BLOCKS 512
#define HIST_BLOCKS 256

// Feature storage: planes xh[N][128] (bf16 hi), xl[N][128] (bf16 lo);
// agg: ah only. GEMM K=512: segs {xh*Ws_hi, ah*Wn_hi, xl*Ws_hi, xh*Ws_lo}.
// Layer-1 GEMM fuses the head: out = (x2_hi+x2_lo) @ (hw_hi [+ hw_lo]) + hb.

typedef __attribute__((ext_vector_type(8))) short short8;
typedef __attribute__((ext_vector_type(4))) float f32x4;

__device__ __forceinline__ unsigned short f2bf(float f) {
    union { float f; unsigned int i; } u; u.f = f;
    unsigned int x = u.i;
    unsigned int r = x + 0x7fffu + ((x >> 16) & 1u);
    return (unsigned short)(r >> 16);
}
__device__ __forceinline__ float bf2f(unsigned short h) {
    union { unsigned int i; float f; } u; u.i = ((unsigned int)h) << 16;
    return u.f;
}
__device__ __forceinline__ float lo_f(unsigned int w) {
    union { unsigned int i; float f; } u; u.i = w << 16;
    return u.f;
}
__device__ __forceinline__ float hi_f(unsigned int w) {
    union { unsigned int i; float f; } u; u.i = w & 0xffff0000u;
    return u.f;
}
__device__ __forceinline__ void async16(void* lds, const void* g) {
    __builtin_amdgcn_global_load_lds(
        (const __attribute__((address_space(1))) void*)g,
        (__attribute__((address_space(3))) void*)lds, 16, 0, 0);
}
__device__ __forceinline__ void add8(float* a, uint4 v) {
    a[0] += lo_f(v.x); a[1] += hi_f(v.x);
    a[2] += lo_f(v.y); a[3] += hi_f(v.y);
    a[4] += lo_f(v.z); a[5] += hi_f(v.z);
    a[6] += lo_f(v.w); a[7] += hi_f(v.w);
}

// ---------------------------------------------------------------------------
// Fused encode (blocks 0..511) + bucket histogram (blocks 512..767).
// ---------------------------------------------------------------------------
__global__ __launch_bounds__(256) void encode_hist_kernel(
    const float* __restrict__ feats0, const float* __restrict__ feats1,
    const float* __restrict__ w0, const float* __restrict__ b0,
    const float* __restrict__ w1, const float* __restrict__ b1,
    const int* __restrict__ row_idx,
    unsigned short* __restrict__ xh, unsigned short* __restrict__ xl,
    const int* __restrict__ dst, int* __restrict__ bucket_counts)
{
    if (blockIdx.x >= ENC_BLOCKS) {
        __shared__ int h[NBUCKETS];
        for (int i = threadIdx.x; i < NBUCKETS; i += 256) h[i] = 0;
        __syncthreads();
        int bid = blockIdx.x - ENC_BLOCKS;
        for (int e = bid * 256 + threadIdx.x; e < N_EDGES;
             e += HIST_BLOCKS * 256)
            atomicAdd(&h[dst[e] >> 8], 1);
        __syncthreads();
        for (int i = threadIdx.x; i < NBUCKETS; i += 256)
            if (h[i]) atomicAdd(&bucket_counts[i], h[i]);
        return;
    }

    __shared__ float sw0[D_IN * C];
    __shared__ float sw1[D_IN * C];
    __shared__ float sb0[C];
    __shared__ float sb1[C];
    for (int i = threadIdx.x; i < D_IN * C; i += blockDim.x) {
        sw0[i] = w0[i];
        sw1[i] = w1[i];
    }
    if (threadIdx.x < C) {
        sb0[threadIdx.x] = b0[threadIdx.x];
        sb1[threadIdx.x] = b1[threadIdx.x];
    }
    __syncthreads();

    int j = threadIdx.x & 15;
    int ln = threadIdx.x >> 4;
    for (int n = blockIdx.x * 16 + ln; n < N_NODES; n += ENC_BLOCKS * 16) {
        int r = row_idx[n];
        const float* f = (r < T0) ? (feats0 + (size_t)r * D_IN)
                                  : (feats1 + (size_t)(r - T0) * D_IN);
        const float* W = (r < T0) ? sw0 : sw1;
        const float* B = (r < T0) ? sb0 : sb1;
        float4 f4[8];
#pragma unroll
        for (int i = 0; i < 8; ++i) f4[i] = ((const float4*)f)[i];
        float acc[8];
#pragma unroll
        for (int cc = 0; cc < 8; ++cc) acc[cc] = B[8 * j + cc];
#pragma unroll
        for (int k = 0; k < D_IN; ++k) {
            float fk = ((const float*)f4)[k];
            float4 wa = *(const float4*)&W[k * C + 8 * j];
            float4 wb = *(const float4*)&W[k * C + 8 * j + 4];
            acc[0] += fk * wa.x; acc[1] += fk * wa.y;
            acc[2] += fk * wa.z; acc[3] += fk * wa.w;
            acc[4] += fk * wb.x; acc[5] += fk * wb.y;
            acc[6] += fk * wb.z; acc[7] += fk * wb.w;
        }
        short8 h8, l8;
#pragma unroll
        for (int cc = 0; cc < 8; ++cc) {
            unsigned short hi = f2bf(acc[cc]);
            h8[cc] = (short)hi;
            l8[cc] = (short)f2bf(acc[cc] - bf2f(hi));
        }
        *(short8*)(xh + (size_t)n * 128 + 8 * j) = h8;
        *(short8*)(xl + (size_t)n * 128 + 8 * j) = l8;
    }
}

// ---------------------------------------------------------------------------
// Weight prep: BT[layer][n][k] (K=512 segs {Wsh,Wnh,Wsh,Wsl}) + head tables
// hwbh/hwbl[n][k] (n<16, k<128, padded element-stride 136).
// ---------------------------------------------------------------------------
__global__ __launch_bounds__(256) void prep_weights(
    const float* __restrict__ ws0, const float* __restrict__ wn0,
    const float* __restrict__ ws1, const float* __restrict__ wn1,
    const float* __restrict__ hw,
    unsigned short* __restrict__ BT0, unsigned short* __restrict__ BT1,
    unsigned short* __restrict__ hwbh, unsigned short* __restrict__ hwbl)
{
    int idx = blockIdx.x * 256 + threadIdx.x;
    const int per_layer = 128 * 512;
    if (idx < 2 * per_layer) {
        int lyr = idx / per_layer;
        int rem = idx - lyr * per_layer;
        int n = rem >> 9;
        int k = rem & 511;
        int seg = k >> 7;         // 0..3
        int ch = k & 127;
        const float* W = (lyr == 0) ? ((seg == 1) ? wn0 : ws0)
                                    : ((seg == 1) ? wn1 : ws1);
        float v = W[ch * 128 + n];
        unsigned short hi = f2bf(v);
        unsigned short out = (seg == 3) ? f2bf(v - bf2f(hi)) : hi;
        (lyr == 0 ? BT0 : BT1)[(size_t)n * 512 + k] = out;
        return;
    }
    int jdx = idx - 2 * per_layer;
    if (jdx >= 2 * 16 * 128) return;
    int plane = jdx >> 11;
    int rem = jdx & 2047;
    int n = rem >> 7;         // 0..15 output channel
    int k = rem & 127;        // 0..127
    float v = hw[k * OUT_DIM + n];
    unsigned short hi = f2bf(v);
    (plane ? hwbl : hwbh)[n * 136 + k] =
        plane ? f2bf(v - bf2f(hi)) : hi;
}

// ---------------------------------------------------------------------------
// CSR build: tiny scan -> bucket scatter -> local CSR
// ---------------------------------------------------------------------------
__global__ __launch_bounds__(256) void scanb_kernel(
    const int* __restrict__ bucket_counts, int* __restrict__ bucket_base,
    int* __restrict__ bucket_cursor, int* __restrict__ offsets)
{
    __shared__ int ws[4];
    int t = threadIdx.x;
    int c = (t < NBUCKETS) ? bucket_counts[t] : 0;
    int lane = t & 63, wid = t >> 6;
    int v = c;
#pragma unroll
    for (int off = 1; off < 64; off <<= 1) {
        int s = __shfl_up(v, off, 64);
        if (lane >= off) v += s;
    }
    if (lane == 63) ws[wid] = v;
    __syncthreads();
    if (t == 0) {
        int run = 0;
#pragma unroll
        for (int j = 0; j < 4; ++j) { int s = ws[j]; ws[j] = run; run += s; }
    }
    __syncthreads();
    int excl = ws[wid] + (v - c);
    if (t < NBUCKETS) {
        bucket_base[t] = excl;
        bucket_cursor[t] = excl;
    }
    if (t == 0) {
        bucket_base[NBUCKETS] = N_EDGES;
        offsets[N_NODES] = N_EDGES;
    }
}

__global__ __launch_bounds__(256) void bucket1_kernel(
    const int* __restrict__ src, const int* __restrict__ dst,
    int* __restrict__ bucket_cursor, uint2* __restrict__ pairs)
{
    __shared__ int hist[NBUCKETS];
    __shared__ int base[NBUCKETS];
    __shared__ int cur[NBUCKETS];
    int tid = threadIdx.x;
    for (int i = tid; i < NBUCKETS; i += 256) { hist[i] = 0; cur[i] = 0; }
    __syncthreads();
    int ebeg = blockIdx.x * CHUNK1;
    int eend = ebeg + CHUNK1;
    if (eend > N_EDGES) eend = N_EDGES;
    for (int e = ebeg + tid; e < eend; e += 256)
        atomicAdd(&hist[dst[e] >> 8], 1);
    __syncthreads();
    for (int i = tid; i < NBUCKETS; i += 256)
        if (hist[i] > 0) base[i] = atomicAdd(&bucket_cursor[i], hist[i]);
    __syncthreads();
    for (int e = ebeg + tid; e < eend; e += 256) {
        int d = dst[e];
        int b = d >> 8;
        int pos = base[b] + atomicAdd(&cur[b], 1);
        pairs[pos] = make_uint2((unsigned)src[e], (unsigned)d);
    }
}

__global__ __launch_bounds__(256) void bucket2_kernel(
    const uint2* __restrict__ pairs, const int* __restrict__ bucket_base,
    int* __restrict__ offsets, float* __restrict__ deg,
    int* __restrict__ src_sorted)
{
    __shared__ int cnt[256];
    __shared__ int noff[256];
    __shared__ int cur[256];
    __shared__ int ws[4];
    int b = blockIdx.x;
    int n0 = b << 8;
    int tid = threadIdx.x;
    int bb = bucket_base[b];
    int be = bucket_base[b + 1];
    cnt[tid] = 0;
    cur[tid] = 0;
    __syncthreads();
    for (int e = bb + tid; e < be; e += 256)
        atomicAdd(&cnt[pairs[e].y & 255], 1);
    __syncthreads();
    int c = cnt[tid];
    int lane = tid & 63, wid = tid >> 6;
    int v = c;
#pragma unroll
    for (int off = 1; off < 64; off <<= 1) {
        int s = __shfl_up(v, off, 64);
        if (lane >= off) v += s;
    }
    if (lane == 63) ws[wid] = v;
    __syncthreads();
    if (tid == 0) {
        int run = 0;
#pragma unroll
        for (int j = 0; j < 4; ++j) { int s = ws[j]; ws[j] = run; run += s; }
    }
    __syncthreads();
    int o = bb + ws[wid] + (v - c);
    noff[tid] = o;
    int n = n0 + tid;
    if (n < N_NODES) {
        offsets[n] = o;
        deg[n] = (float)(c > 0 ? c : 1);
    }
    __syncthreads();
    for (int e = bb + tid; e < be; e += 256) {
        uint2 p = pairs[e];
        int local = p.y & 255;
        int pos = noff[local] + atomicAdd(&cur[local], 1);
        src_sorted[pos] = (int)p.x;
    }
}

// ---------------------------------------------------------------------------
// Aggregate: one wave per dst node, hi-plane only (256 B rows).
// ---------------------------------------------------------------------------
__global__ __launch_bounds__(256) void aggregate_kernel(
    const unsigned short* __restrict__ xh, const int* __restrict__ offsets,
    const int* __restrict__ src_sorted, const float* __restrict__ deg,
    unsigned short* __restrict__ ah)
{
    int wave = (blockIdx.x * blockDim.x + threadIdx.x) >> 6;
    int lane = threadIdx.x & 63;
    if (wave >= N_NODES) return;
    int h = lane >> 4;
    int u = lane & 15;
    int beg = offsets[wave];
    int end = offsets[wave + 1];
    float acc[8];
#pragma unroll
    for (int j = 0; j < 8; ++j) acc[j] = 0.f;

    int e = beg;
    for (; e + 16 <= end; e += 16) {
        int sA = src_sorted[e + h];
        int sB = src_sorted[e + 4 + h];
        int sC = src_sorted[e + 8 + h];
        int sD = src_sorted[e + 12 + h];
        uint4 vA = *(const uint4*)(xh + (size_t)sA * 128 + u * 8);
        uint4 vB = *(const uint4*)(xh + (size_t)sB * 128 + u * 8);
        uint4 vC = *(const uint4*)(xh + (size_t)sC * 128 + u * 8);
        uint4 vD = *(const uint4*)(xh + (size_t)sD * 128 + u * 8);
        add8(acc, vA); add8(acc, vB); add8(acc, vC); add8(acc, vD);
    }
    for (; e + 4 <= end; e += 4) {
        int s = src_sorted[e + h];
        uint4 v = *(const uint4*)(xh + (size_t)s * 128 + u * 8);
        add8(acc, v);
    }
    int rem = end - e;
    if (h < rem) {
        int s = src_sorted[e + h];
        uint4 v = *(const uint4*)(xh + (size_t)s * 128 + u * 8);
        add8(acc, v);
    }

#pragma unroll
    for (int j = 0; j < 8; ++j) {
        acc[j] += __shfl_xor(acc[j], 16);
        acc[j] += __shfl_xor(acc[j], 32);
    }
    if (lane < 16) {
        float inv = 1.0f / deg[wave];
        short8 hv;
#pragma unroll
        for (int j = 0; j < 8; ++j)
            hv[j] = (short)f2bf(acc[j] * inv);
        *(short8*)(ah + (size_t)wave * 128 + u * 8) = hv;
    }
}

// ---------------------------------------------------------------------------
// Layer GEMM: 512 thr / 8 waves, tile 128x128, K=512 in 4 chunks of 128.
// mode=1: relu, write xh/xl planes (layer 0).
// mode=2: no relu, fused head -> out[N][16] (layer 1, no plane writes).
// ---------------------------------------------------------------------------
#define BM 128
__global__ __launch_bounds__(512) void gemm_mfma(
    unsigned short* __restrict__ xh, unsigned short* __restrict__ xl,
    const unsigned short* __restrict__ ah,
    const unsigned short* __restrict__ BT, const float* __restrict__ bias,
    int mode,
    const unsigned short* __restrict__ hwbh,
    const unsigned short* __restrict__ hwbl,
    const float* __restrict__ hb, float* __restrict__ out)
{
    __shared__ uint4 smem4[4096];           // 64 KB: As 32K | Bs 32K / th | tl
    char* As = (char*)smem4;
    char* Bs = (char*)smem4 + 32768;
    __shared__ float bias_s[C];
    __shared__ unsigned short hwh_s[16 * 136];
    __shared__ unsigned short hwl_s[16 * 136];
    __shared__ float hb_s[OUT_DIM];

    int tid = threadIdx.x;
    int w = tid >> 6, l = tid & 63;
    int row0 = blockIdx.x * BM;
    if (tid < C) bias_s[tid] = bias[tid];
    if (mode == 2) {
        for (int i = tid; i < 16 * 136; i += 512) {
            hwh_s[i] = hwbh[i];
            hwl_s[i] = hwbl[i];
        }
        if (tid < OUT_DIM) hb_s[tid] = hb[tid];
    }

    f32x4 acc[2][4];
#pragma unroll
    for (int mt = 0; mt < 2; ++mt)
#pragma unroll
        for (int nt = 0; nt < 4; ++nt)
            acc[mt][nt] = (f32x4)(0.f);

    int wm = w & 3;
    int wn = w >> 2;
    int quad = l >> 4;
    int mrow = l & 15;

    const unsigned short* abases[4] = {xh, ah, xl, xh};

    for (int c = 0; c < 4; ++c) {
        const char* abase = (const char*)abases[c];
#pragma unroll
        for (int i = 0; i < 4; ++i) {
            int off = i * 8192 + tid * 16;
            int rl = off >> 8;
            int row = row0 + rl;
            if (row > N_NODES - 1) row = N_NODES - 1;
            int u = ((off >> 4) & 15) ^ (rl & 15);
            async16(As + off, abase + (size_t)row * 256 + u * 16);
        }
#pragma unroll
        for (int i = 0; i < 4; ++i) {
            int off = i * 8192 + tid * 16;
            int n = off >> 8;
            int u = ((off >> 4) & 15) ^ (n & 15);
            async16(Bs + off, (const char*)BT + (size_t)n * 1024 + c * 256 + u * 16);
        }
        __syncthreads();
#pragma unroll
        for (int ks = 0; ks < 4; ++ks) {
            int cu = ks * 4 + quad;
            int swz = (cu ^ mrow) * 16;
            short8 a0 = *(const short8*)(As + (wm * 32 + mrow) * 256 + swz);
            short8 a1 = *(const short8*)(As + (wm * 32 + 16 + mrow) * 256 + swz);
            short8 b[4];
#pragma unroll
            for (int nt = 0; nt < 4; ++nt)
                b[nt] = *(const short8*)(Bs + (wn * 64 + nt * 16 + mrow) * 256 + swz);
#pragma unroll
            for (int nt = 0; nt < 4; ++nt) {
                acc[0][nt] = __builtin_amdgcn_mfma_f32_16x16x32_bf16(a0, b[nt], acc[0][nt], 0, 0, 0);
                acc[1][nt] = __builtin_amdgcn_mfma_f32_16x16x32_bf16(a1, b[nt], acc[1][nt], 0, 0, 0);
            }
        }
        __syncthreads();
    }

    // epilogue: build hi/lo tiles in LDS, XOR-swizzled (unit' = unit^(rl&15))
    char* th = (char*)smem4;            // 32 KB: 128 rows x 256 B
    char* tl = (char*)smem4 + 32768;
    int relu = (mode == 1);
#pragma unroll
    for (int mt = 0; mt < 2; ++mt)
#pragma unroll
        for (int nt = 0; nt < 4; ++nt) {
            int col = wn * 64 + nt * 16 + mrow;
#pragma unroll
            for (int r = 0; r < 4; ++r) {
                int rl = wm * 32 + mt * 16 + quad * 4 + r;
                float v = acc[mt][nt][r] + bias_s[col];
                if (relu) v = fmaxf(v, 0.f);
                unsigned short hi = f2bf(v);
                int su = (col >> 3) ^ (rl & 15);
                char* p = th + rl * 256 + su * 16 + (col & 7) * 2;
                *(unsigned short*)p = hi;
                *(unsigned short*)(p + 32768) = f2bf(v - bf2f(hi));
            }
        }
    __syncthreads();

    if (mode == 1) {
        // unswizzling copy-out to xh/xl
#pragma unroll
        for (int i = 0; i < 4; ++i) {
            int off = i * 8192 + tid * 16;
            int rl = off >> 8;
            int su = (((off >> 4) & 15) ^ (rl & 15)) * 16;
            int row = row0 + rl;
            if (row < N_NODES) {
                *(uint4*)((char*)xh + (size_t)row * 256 + (off & 255)) =
                    *(const uint4*)(th + rl * 256 + su);
                *(uint4*)((char*)xl + (size_t)row * 256 + (off & 255)) =
                    *(const uint4*)(tl + rl * 256 + su);
            }
        }
    } else {
        // fused head: out_tile = (th + tl) @ (hwh [+ hwl]) + hb
        // wave w -> rows w*16..w*16+15; MFMA 16x16x32 over K=128, N=16.
        f32x4 hacc = (f32x4)(0.f);
        const char* Ap[3] = {th, tl, th};
        const unsigned short* Bp[3] = {hwh_s, hwh_s, hwl_s};
#pragma unroll
        for (int ps = 0; ps < 3; ++ps) {
#pragma unroll
            for (int ks = 0; ks < 4; ++ks) {
                int su = ((ks * 4 + quad) ^ mrow) * 16;
                short8 a = *(const short8*)(Ap[ps] + (w * 16 + mrow) * 256 + su);
                short8 b = *(const short8*)((const char*)Bp[ps] +
                                            mrow * 272 + ks * 64 + quad * 16);
                hacc = __builtin_amdgcn_mfma_f32_16x16x32_bf16(a, b, hacc, 0, 0, 0);
            }
        }
        float bb = hb_s[mrow];
#pragma unroll
        for (int r = 0; r < 4; ++r) {
            int grow = row0 + w * 16 + quad * 4 + r;
            if (grow < N_NODES)
                out[(size_t)grow * OUT_DIM + mrow] = hacc[r] + bb;
        }
    }
}

// ---------------------------------------------------------------------------
extern "C" void kernel_launch(void* const* d_in, const int* in_sizes, int n_in,
                              void* d_out, int out_size, void* d_ws, size_t ws_size,
                              hipStream_t stream)
{
    const float* feats0 = (const float*)d_in[0];
    const float* feats1 = (const float*)d_in[1];
    const float* enc_w0 = (const float*)d_in[2];
    const float* enc_b0 = (const float*)d_in[3];
    const float* enc_w1 = (const float*)d_in[4];
    const float* enc_b1 = (const float*)d_in[5];
    const float* w_self0 = (const float*)d_in[6];
    const float* w_neigh0 = (const float*)d_in[7];
    const float* b0 = (const float*)d_in[8];
    const float* w_self1 = (const float*)d_in[9];
    const float* w_neigh1 = (const float*)d_in[10];
    const float* b1 = (const float*)d_in[11];
    const float* head_w = (const float*)d_in[12];
    const float* head_b = (const float*)d_in[13];
    const int* node_row_idx = (const int*)d_in[14];
    const int* edge_index = (const int*)d_in[15];
    const int* e_src = edge_index;
    const int* e_dst = edge_index + N_EDGES;

    char* p = (char*)d_ws;
    unsigned short* xh = (unsigned short*)p;  p += (size_t)N_NODES * C * 2;
    unsigned short* xl = (unsigned short*)p;  p += (size_t)N_NODES * C * 2;
    unsigned short* ah = (unsigned short*)p;  p += (size_t)N_NODES * C * 2;
    unsigned short* BT0 = (unsigned short*)p; p += (size_t)128 * 512 * 2;
    unsigned short* BT1 = (unsigned short*)p; p += (size_t)128 * 512 * 2;
    unsigned short* hwbh = (unsigned short*)p; p += (size_t)16 * 136 * 2;
    unsigned short* hwbl = (unsigned short*)p; p += (size_t)16 * 136 * 2;
    float* deg = (float*)p;        p += (size_t)N_NODES * 4;
    int* offsets = (int*)p;        p += (size_t)(N_NODES + 8) * 4;
    int* bucket_counts = (int*)p;  p += (size_t)(NBUCKETS + 8) * 4;
    int* bucket_base = (int*)p;    p += (size_t)(NBUCKETS + 8) * 4;
    int* bucket_cursor = (int*)p;  p += (size_t)(NBUCKETS + 8) * 4;
    int* src_sorted = (int*)p;     p += (size_t)N_EDGES * 4;
    // pairs aliases ah (ah unwritten until aggregate, which runs after
    // bucket2 on the same stream): 800K * 8 B = 6.4 MB <= 12.8 MB
    uint2* pairs = (uint2*)ah;

    hipMemsetAsync(bucket_counts, 0, (size_t)(NBUCKETS + 8) * 4, stream);

    encode_hist_kernel<<<ENC_BLOCKS + HIST_BLOCKS, 256, 0, stream>>>(
        feats0, feats1, enc_w0, enc_b0, enc_w1, enc_b1, node_row_idx,
        xh, xl, e_dst, bucket_counts);
    prep_weights<<<(2 * 128 * 512 + 2 * 16 * 128 + 255) / 256, 256, 0, stream>>>(
        w_self0, w_neigh0, w_self1, w_neigh1, head_w, BT0, BT1, hwbh, hwbl);

    scanb_kernel<<<1, 256, 0, stream>>>(bucket_counts, bucket_base,
                                        bucket_cursor, offsets);
    bucket1_kernel<<<NB1, 256, 0, stream>>>(e_src, e_dst, bucket_cursor, pairs);
    bucket2_kernel<<<NBUCKETS, 256, 0, stream>>>(pairs, bucket_base, offsets,
                                                 deg, src_sorted);

    // Layer 0
    aggregate_kernel<<<(N_NODES * 64 + 255) / 256, 256, 0, stream>>>(
        xh, offsets, src_sorted, deg, ah);
    gemm_mfma<<<(N_NODES + BM - 1) / BM, 512, 0, stream>>>(
        xh, xl, ah, BT0, b0, 1, hwbh, hwbl, head_b, (float*)d_out);

    // Layer 1 (fused head)
    aggregate_kernel<<<(N_NODES * 64 + 255) / 256, 256, 0, stream>>>(
        xh, offsets, src_sorted, deg, ah);
    gemm_mfma<<<(N_NODES + BM - 1) / BM, 512, 0, stream>>>(
        xh, xl, ah, BT1, b1, 2, hwbh, hwbl, head_b, (float*)d_out);
}

// Round 11
// 232.610 us; speedup vs baseline: 3.3860x; 1.0597x over previous
//
#include <hip/hip_runtime.h>
#include <hip/hip_bf16.h>

#define N_NODES 50000
#define N_EDGES 800000
#define C 128
#define D_IN 32
#define T0 25000
#define OUT_DIM 16
#define NBUCKETS ((N_NODES + 255) / 256)      // 196, bucket = dst>>8
#define NB1 512
#define CHUNK1 ((N_EDGES + NB1 - 1) / NB1)    // 1563
#define ENC_BLOCKS 512
#define HIST_BLOCKS 256
#define PREP_ITEMS (2 * 128 * 384 + 2 * 16 * 128)
#define PREP_BLOCKS ((PREP_ITEMS + 255) / 256)

// Feature storage: single bf16 plane xh[N][128]; agg plane ah[N][128].
// GEMM K=384: segs {xh*Ws_hi, ah*Wn_hi, xh*Ws_lo} (W fp32-compensated,
// x bf16-rounded). Layer-1 GEMM fuses the head (hw split hi/lo).

typedef __attribute__((ext_vector_type(8))) short short8;
typedef __attribute__((ext_vector_type(4))) float f32x4;

__device__ __forceinline__ unsigned short f2bf(float f) {
    union { float f; unsigned int i; } u; u.f = f;
    unsigned int x = u.i;
    unsigned int r = x + 0x7fffu + ((x >> 16) & 1u);
    return (unsigned short)(r >> 16);
}
__device__ __forceinline__ float bf2f(unsigned short h) {
    union { unsigned int i; float f; } u; u.i = ((unsigned int)h) << 16;
    return u.f;
}
__device__ __forceinline__ float lo_f(unsigned int w) {
    union { unsigned int i; float f; } u; u.i = w << 16;
    return u.f;
}
__device__ __forceinline__ float hi_f(unsigned int w) {
    union { unsigned int i; float f; } u; u.i = w & 0xffff0000u;
    return u.f;
}
__device__ __forceinline__ void async16(void* lds, const void* g) {
    __builtin_amdgcn_global_load_lds(
        (const __attribute__((address_space(1))) void*)g,
        (__attribute__((address_space(3))) void*)lds, 16, 0, 0);
}
__device__ __forceinline__ void add8(float* a, uint4 v) {
    a[0] += lo_f(v.x); a[1] += hi_f(v.x);
    a[2] += lo_f(v.y); a[3] += hi_f(v.y);
    a[4] += lo_f(v.z); a[5] += hi_f(v.z);
    a[6] += lo_f(v.w); a[7] += hi_f(v.w);
}

// ---------------------------------------------------------------------------
// Mega-kernel: encode (blocks 0..511) + bucket hist (512..767) +
// weight prep (768..). One launch, three independent phases.
// ---------------------------------------------------------------------------
__global__ __launch_bounds__(256) void encode_hist_prep_kernel(
    const float* __restrict__ feats0, const float* __restrict__ feats1,
    const float* __restrict__ w0, const float* __restrict__ b0,
    const float* __restrict__ w1, const float* __restrict__ b1,
    const int* __restrict__ row_idx, unsigned short* __restrict__ xh,
    const int* __restrict__ dst, int* __restrict__ bucket_counts,
    const float* __restrict__ ws0, const float* __restrict__ wn0,
    const float* __restrict__ ws1, const float* __restrict__ wn1,
    const float* __restrict__ hw,
    unsigned short* __restrict__ BT0, unsigned short* __restrict__ BT1,
    unsigned short* __restrict__ hwbh, unsigned short* __restrict__ hwbl)
{
    if (blockIdx.x >= ENC_BLOCKS + HIST_BLOCKS) {
        // ---- weight prep ----
        int idx = (blockIdx.x - ENC_BLOCKS - HIST_BLOCKS) * 256 + threadIdx.x;
        const int per_layer = 128 * 384;
        if (idx < 2 * per_layer) {
            int lyr = idx / per_layer;
            int rem = idx - lyr * per_layer;
            int n = rem / 384;
            int k = rem - n * 384;
            int seg = k >> 7;     // 0:Ws_hi 1:Wn_hi 2:Ws_lo
            int ch = k & 127;
            const float* W = (lyr == 0) ? ((seg == 1) ? wn0 : ws0)
                                        : ((seg == 1) ? wn1 : ws1);
            float v = W[ch * 128 + n];
            unsigned short hi = f2bf(v);
            unsigned short out = (seg == 2) ? f2bf(v - bf2f(hi)) : hi;
            (lyr == 0 ? BT0 : BT1)[(size_t)n * 384 + k] = out;
            return;
        }
        int jdx = idx - 2 * per_layer;
        if (jdx >= 2 * 16 * 128) return;
        int plane = jdx >> 11;
        int rem = jdx & 2047;
        int n = rem >> 7;
        int k = rem & 127;
        float v = hw[k * OUT_DIM + n];
        unsigned short hi = f2bf(v);
        (plane ? hwbl : hwbh)[n * 136 + k] = plane ? f2bf(v - bf2f(hi)) : hi;
        return;
    }
    if (blockIdx.x >= ENC_BLOCKS) {
        // ---- bucket histogram ----
        __shared__ int h[NBUCKETS];
        for (int i = threadIdx.x; i < NBUCKETS; i += 256) h[i] = 0;
        __syncthreads();
        int bid = blockIdx.x - ENC_BLOCKS;
        for (int e = bid * 256 + threadIdx.x; e < N_EDGES;
             e += HIST_BLOCKS * 256)
            atomicAdd(&h[dst[e] >> 8], 1);
        __syncthreads();
        for (int i = threadIdx.x; i < NBUCKETS; i += 256)
            if (h[i]) atomicAdd(&bucket_counts[i], h[i]);
        return;
    }

    // ---- encode ----
    __shared__ float sw0[D_IN * C];
    __shared__ float sw1[D_IN * C];
    __shared__ float sb0[C];
    __shared__ float sb1[C];
    for (int i = threadIdx.x; i < D_IN * C; i += blockDim.x) {
        sw0[i] = w0[i];
        sw1[i] = w1[i];
    }
    if (threadIdx.x < C) {
        sb0[threadIdx.x] = b0[threadIdx.x];
        sb1[threadIdx.x] = b1[threadIdx.x];
    }
    __syncthreads();

    int j = threadIdx.x & 15;
    int ln = threadIdx.x >> 4;
    for (int n = blockIdx.x * 16 + ln; n < N_NODES; n += ENC_BLOCKS * 16) {
        int r = row_idx[n];
        const float* f = (r < T0) ? (feats0 + (size_t)r * D_IN)
                                  : (feats1 + (size_t)(r - T0) * D_IN);
        const float* W = (r < T0) ? sw0 : sw1;
        const float* B = (r < T0) ? sb0 : sb1;
        float4 f4[8];
#pragma unroll
        for (int i = 0; i < 8; ++i) f4[i] = ((const float4*)f)[i];
        float acc[8];
#pragma unroll
        for (int cc = 0; cc < 8; ++cc) acc[cc] = B[8 * j + cc];
#pragma unroll
        for (int k = 0; k < D_IN; ++k) {
            float fk = ((const float*)f4)[k];
            float4 wa = *(const float4*)&W[k * C + 8 * j];
            float4 wb = *(const float4*)&W[k * C + 8 * j + 4];
            acc[0] += fk * wa.x; acc[1] += fk * wa.y;
            acc[2] += fk * wa.z; acc[3] += fk * wa.w;
            acc[4] += fk * wb.x; acc[5] += fk * wb.y;
            acc[6] += fk * wb.z; acc[7] += fk * wb.w;
        }
        short8 h8;
#pragma unroll
        for (int cc = 0; cc < 8; ++cc) h8[cc] = (short)f2bf(acc[cc]);
        *(short8*)(xh + (size_t)n * 128 + 8 * j) = h8;
    }
}

// ---------------------------------------------------------------------------
// CSR build: tiny scan -> bucket scatter -> local CSR
// ---------------------------------------------------------------------------
__global__ __launch_bounds__(256) void scanb_kernel(
    const int* __restrict__ bucket_counts, int* __restrict__ bucket_base,
    int* __restrict__ bucket_cursor, int* __restrict__ offsets)
{
    __shared__ int ws[4];
    int t = threadIdx.x;
    int c = (t < NBUCKETS) ? bucket_counts[t] : 0;
    int lane = t & 63, wid = t >> 6;
    int v = c;
#pragma unroll
    for (int off = 1; off < 64; off <<= 1) {
        int s = __shfl_up(v, off, 64);
        if (lane >= off) v += s;
    }
    if (lane == 63) ws[wid] = v;
    __syncthreads();
    if (t == 0) {
        int run = 0;
#pragma unroll
        for (int j = 0; j < 4; ++j) { int s = ws[j]; ws[j] = run; run += s; }
    }
    __syncthreads();
    int excl = ws[wid] + (v - c);
    if (t < NBUCKETS) {
        bucket_base[t] = excl;
        bucket_cursor[t] = excl;
    }
    if (t == 0) {
        bucket_base[NBUCKETS] = N_EDGES;
        offsets[N_NODES] = N_EDGES;
    }
}

__global__ __launch_bounds__(256) void bucket1_kernel(
    const int* __restrict__ src, const int* __restrict__ dst,
    int* __restrict__ bucket_cursor, uint2* __restrict__ pairs)
{
    __shared__ int hist[NBUCKETS];
    __shared__ int base[NBUCKETS];
    __shared__ int cur[NBUCKETS];
    int tid = threadIdx.x;
    for (int i = tid; i < NBUCKETS; i += 256) { hist[i] = 0; cur[i] = 0; }
    __syncthreads();
    int ebeg = blockIdx.x * CHUNK1;
    int eend = ebeg + CHUNK1;
    if (eend > N_EDGES) eend = N_EDGES;
    for (int e = ebeg + tid; e < eend; e += 256)
        atomicAdd(&hist[dst[e] >> 8], 1);
    __syncthreads();
    for (int i = tid; i < NBUCKETS; i += 256)
        if (hist[i] > 0) base[i] = atomicAdd(&bucket_cursor[i], hist[i]);
    __syncthreads();
    for (int e = ebeg + tid; e < eend; e += 256) {
        int d = dst[e];
        int b = d >> 8;
        int pos = base[b] + atomicAdd(&cur[b], 1);
        pairs[pos] = make_uint2((unsigned)src[e], (unsigned)d);
    }
}

__global__ __launch_bounds__(256) void bucket2_kernel(
    const uint2* __restrict__ pairs, const int* __restrict__ bucket_base,
    int* __restrict__ offsets, float* __restrict__ deg,
    int* __restrict__ src_sorted)
{
    __shared__ int cnt[256];
    __shared__ int noff[256];
    __shared__ int cur[256];
    __shared__ int ws[4];
    int b = blockIdx.x;
    int n0 = b << 8;
    int tid = threadIdx.x;
    int bb = bucket_base[b];
    int be = bucket_base[b + 1];
    cnt[tid] = 0;
    cur[tid] = 0;
    __syncthreads();
    for (int e = bb + tid; e < be; e += 256)
        atomicAdd(&cnt[pairs[e].y & 255], 1);
    __syncthreads();
    int c = cnt[tid];
    int lane = tid & 63, wid = tid >> 6;
    int v = c;
#pragma unroll
    for (int off = 1; off < 64; off <<= 1) {
        int s = __shfl_up(v, off, 64);
        if (lane >= off) v += s;
    }
    if (lane == 63) ws[wid] = v;
    __syncthreads();
    if (tid == 0) {
        int run = 0;
#pragma unroll
        for (int j = 0; j < 4; ++j) { int s = ws[j]; ws[j] = run; run += s; }
    }
    __syncthreads();
    int o = bb + ws[wid] + (v - c);
    noff[tid] = o;
    int n = n0 + tid;
    if (n < N_NODES) {
        offsets[n] = o;
        deg[n] = (float)(c > 0 ? c : 1);
    }
    __syncthreads();
    for (int e = bb + tid; e < be; e += 256) {
        uint2 p = pairs[e];
        int local = p.y & 255;
        int pos = noff[local] + atomicAdd(&cur[local], 1);
        src_sorted[pos] = (int)p.x;
    }
}

// ---------------------------------------------------------------------------
// Aggregate: one wave per dst node. lane = h*16 + u; one wave-load covers
// FOUR edges. Fully predicated groups: 4 independent loads always in
// flight (index clamped, add masked) -> no serial tail.
// ---------------------------------------------------------------------------
__global__ __launch_bounds__(256) void aggregate_kernel(
    const unsigned short* __restrict__ xh, const int* __restrict__ offsets,
    const int* __restrict__ src_sorted, const float* __restrict__ deg,
    unsigned short* __restrict__ ah)
{
    int wave = (blockIdx.x * blockDim.x + threadIdx.x) >> 6;
    int lane = threadIdx.x & 63;
    if (wave >= N_NODES) return;
    int h = lane >> 4;
    int u = lane & 15;
    int beg = offsets[wave];
    int end = offsets[wave + 1];
    float acc[8];
#pragma unroll
    for (int j = 0; j < 8; ++j) acc[j] = 0.f;

    for (int e = beg; e < end; e += 16) {
        int i0 = e + h;
        int i1 = e + 4 + h;
        int i2 = e + 8 + h;
        int i3 = e + 12 + h;
        int c0 = i0 < end ? i0 : beg;
        int c1 = i1 < end ? i1 : beg;
        int c2 = i2 < end ? i2 : beg;
        int c3 = i3 < end ? i3 : beg;
        int s0 = src_sorted[c0];
        int s1 = src_sorted[c1];
        int s2 = src_sorted[c2];
        int s3 = src_sorted[c3];
        uint4 v0 = *(const uint4*)(xh + (size_t)s0 * 128 + u * 8);
        uint4 v1 = *(const uint4*)(xh + (size_t)s1 * 128 + u * 8);
        uint4 v2 = *(const uint4*)(xh + (size_t)s2 * 128 + u * 8);
        uint4 v3 = *(const uint4*)(xh + (size_t)s3 * 128 + u * 8);
        if (i0 < end) add8(acc, v0);
        if (i1 < end) add8(acc, v1);
        if (i2 < end) add8(acc, v2);
        if (i3 < end) add8(acc, v3);
    }

#pragma unroll
    for (int j = 0; j < 8; ++j) {
        acc[j] += __shfl_xor(acc[j], 16);
        acc[j] += __shfl_xor(acc[j], 32);
    }
    if (lane < 16) {
        float inv = 1.0f / deg[wave];
        short8 hv;
#pragma unroll
        for (int j = 0; j < 8; ++j)
            hv[j] = (short)f2bf(acc[j] * inv);
        *(short8*)(ah + (size_t)wave * 128 + u * 8) = hv;
    }
}

// ---------------------------------------------------------------------------
// Layer GEMM: 512 thr / 8 waves, tile 128x128, K=384 in 3 chunks of 128.
// A bases {xh, ah, xh}; B = BT[n][384] segs {Ws_hi, Wn_hi, Ws_lo}.
// mode=1: relu, write xh plane. mode=2: fused head -> out[N][16].
// ---------------------------------------------------------------------------
#define BM 128
__global__ __launch_bounds__(512) void gemm_mfma(
    unsigned short* __restrict__ xh, const unsigned short* __restrict__ ah,
    const unsigned short* __restrict__ BT, const float* __restrict__ bias,
    int mode,
    const unsigned short* __restrict__ hwbh,
    const unsigned short* __restrict__ hwbl,
    const float* __restrict__ hb, float* __restrict__ out)
{
    __shared__ uint4 smem4[4096];           // 64 KB: As 32K | Bs 32K / th
    char* As = (char*)smem4;
    char* Bs = (char*)smem4 + 32768;
    __shared__ float bias_s[C];
    __shared__ unsigned short hwh_s[16 * 136];
    __shared__ unsigned short hwl_s[16 * 136];
    __shared__ float hb_s[OUT_DIM];

    int tid = threadIdx.x;
    int w = tid >> 6, l = tid & 63;
    int row0 = blockIdx.x * BM;
    if (tid < C) bias_s[tid] = bias[tid];
    if (mode == 2) {
        for (int i = tid; i < 16 * 136; i += 512) {
            hwh_s[i] = hwbh[i];
            hwl_s[i] = hwbl[i];
        }
        if (tid < OUT_DIM) hb_s[tid] = hb[tid];
    }

    f32x4 acc[2][4];
#pragma unroll
    for (int mt = 0; mt < 2; ++mt)
#pragma unroll
        for (int nt = 0; nt < 4; ++nt)
            acc[mt][nt] = (f32x4)(0.f);

    int wm = w & 3;
    int wn = w >> 2;
    int quad = l >> 4;
    int mrow = l & 15;

    const unsigned short* abases[3] = {xh, ah, xh};

    for (int c = 0; c < 3; ++c) {
        const char* abase = (const char*)abases[c];
#pragma unroll
        for (int i = 0; i < 4; ++i) {
            int off = i * 8192 + tid * 16;
            int rl = off >> 8;
            int row = row0 + rl;
            if (row > N_NODES - 1) row = N_NODES - 1;
            int u = ((off >> 4) & 15) ^ (rl & 15);
            async16(As + off, abase + (size_t)row * 256 + u * 16);
        }
#pragma unroll
        for (int i = 0; i < 4; ++i) {
            int off = i * 8192 + tid * 16;
            int n = off >> 8;
            int u = ((off >> 4) & 15) ^ (n & 15);
            async16(Bs + off, (const char*)BT + (size_t)n * 768 + c * 256 + u * 16);
        }
        __syncthreads();
#pragma unroll
        for (int ks = 0; ks < 4; ++ks) {
            int cu = ks * 4 + quad;
            int swz = (cu ^ mrow) * 16;
            short8 a0 = *(const short8*)(As + (wm * 32 + mrow) * 256 + swz);
            short8 a1 = *(const short8*)(As + (wm * 32 + 16 + mrow) * 256 + swz);
            short8 b[4];
#pragma unroll
            for (int nt = 0; nt < 4; ++nt)
                b[nt] = *(const short8*)(Bs + (wn * 64 + nt * 16 + mrow) * 256 + swz);
#pragma unroll
            for (int nt = 0; nt < 4; ++nt) {
                acc[0][nt] = __builtin_amdgcn_mfma_f32_16x16x32_bf16(a0, b[nt], acc[0][nt], 0, 0, 0);
                acc[1][nt] = __builtin_amdgcn_mfma_f32_16x16x32_bf16(a1, b[nt], acc[1][nt], 0, 0, 0);
            }
        }
        __syncthreads();
    }

    // epilogue: bf16 tile in LDS, XOR-swizzled (unit' = unit ^ (rl&15))
    char* th = (char*)smem4;            // 32 KB: 128 rows x 256 B
    int relu = (mode == 1);
#pragma unroll
    for (int mt = 0; mt < 2; ++mt)
#pragma unroll
        for (int nt = 0; nt < 4; ++nt) {
            int col = wn * 64 + nt * 16 + mrow;
#pragma unroll
            for (int r = 0; r < 4; ++r) {
                int rl = wm * 32 + mt * 16 + quad * 4 + r;
                float v = acc[mt][nt][r] + bias_s[col];
                if (relu) v = fmaxf(v, 0.f);
                int su = (col >> 3) ^ (rl & 15);
                *(unsigned short*)(th + rl * 256 + su * 16 + (col & 7) * 2) =
                    f2bf(v);
            }
        }
    __syncthreads();

    if (mode == 1) {
        // unswizzling copy-out to xh
#pragma unroll
        for (int i = 0; i < 4; ++i) {
            int off = i * 8192 + tid * 16;
            int rl = off >> 8;
            int su = (((off >> 4) & 15) ^ (rl & 15)) * 16;
            int row = row0 + rl;
            if (row < N_NODES)
                *(uint4*)((char*)xh + (size_t)row * 256 + (off & 255)) =
                    *(const uint4*)(th + rl * 256 + su);
        }
    } else {
        // fused head: out_tile = th @ (hwh + hwl) + hb
        f32x4 hacc = (f32x4)(0.f);
        const unsigned short* Bp[2] = {hwh_s, hwl_s};
#pragma unroll
        for (int ps = 0; ps < 2; ++ps) {
#pragma unroll
            for (int ks = 0; ks < 4; ++ks) {
                int su = ((ks * 4 + quad) ^ mrow) * 16;
                short8 a = *(const short8*)(th + (w * 16 + mrow) * 256 + su);
                short8 b = *(const short8*)((const char*)Bp[ps] +
                                            mrow * 272 + ks * 64 + quad * 16);
                hacc = __builtin_amdgcn_mfma_f32_16x16x32_bf16(a, b, hacc, 0, 0, 0);
            }
        }
        float bb = hb_s[mrow];
#pragma unroll
        for (int r = 0; r < 4; ++r) {
            int grow = row0 + w * 16 + quad * 4 + r;
            if (grow < N_NODES)
                out[(size_t)grow * OUT_DIM + mrow] = hacc[r] + bb;
        }
    }
}

// ---------------------------------------------------------------------------
extern "C" void kernel_launch(void* const* d_in, const int* in_sizes, int n_in,
                              void* d_out, int out_size, void* d_ws, size_t ws_size,
                              hipStream_t stream)
{
    const float* feats0 = (const float*)d_in[0];
    const float* feats1 = (const float*)d_in[1];
    const float* enc_w0 = (const float*)d_in[2];
    const float* enc_b0 = (const float*)d_in[3];
    const float* enc_w1 = (const float*)d_in[4];
    const float* enc_b1 = (const float*)d_in[5];
    const float* w_self0 = (const float*)d_in[6];
    const float* w_neigh0 = (const float*)d_in[7];
    const float* b0 = (const float*)d_in[8];
    const float* w_self1 = (const float*)d_in[9];
    const float* w_neigh1 = (const float*)d_in[10];
    const float* b1 = (const float*)d_in[11];
    const float* head_w = (const float*)d_in[12];
    const float* head_b = (const float*)d_in[13];
    const int* node_row_idx = (const int*)d_in[14];
    const int* edge_index = (const int*)d_in[15];
    const int* e_src = edge_index;
    const int* e_dst = edge_index + N_EDGES;

    char* p = (char*)d_ws;
    unsigned short* xh = (unsigned short*)p;  p += (size_t)N_NODES * C * 2;
    unsigned short* ah = (unsigned short*)p;  p += (size_t)N_NODES * C * 2;
    unsigned short* BT0 = (unsigned short*)p; p += (size_t)128 * 384 * 2;
    unsigned short* BT1 = (unsigned short*)p; p += (size_t)128 * 384 * 2;
    unsigned short* hwbh = (unsigned short*)p; p += (size_t)16 * 136 * 2;
    unsigned short* hwbl = (unsigned short*)p; p += (size_t)16 * 136 * 2;
    float* deg = (float*)p;        p += (size_t)N_NODES * 4;
    int* offsets = (int*)p;        p += (size_t)(N_NODES + 8) * 4;
    int* bucket_counts = (int*)p;  p += (size_t)(NBUCKETS + 8) * 4;
    int* bucket_base = (int*)p;    p += (size_t)(NBUCKETS + 8) * 4;
    int* bucket_cursor = (int*)p;  p += (size_t)(NBUCKETS + 8) * 4;
    int* src_sorted = (int*)p;     p += (size_t)N_EDGES * 4;
    // pairs aliases ah (ah unwritten until aggregate, which runs after
    // bucket2 on the same stream): 800K * 8 B = 6.4 MB <= 12.8 MB
    uint2* pairs = (uint2*)ah;

    hipMemsetAsync(bucket_counts, 0, (size_t)(NBUCKETS + 8) * 4, stream);

    encode_hist_prep_kernel<<<ENC_BLOCKS + HIST_BLOCKS + PREP_BLOCKS, 256, 0,
                              stream>>>(
        feats0, feats1, enc_w0, enc_b0, enc_w1, enc_b1, node_row_idx, xh,
        e_dst, bucket_counts,
        w_self0, w_neigh0, w_self1, w_neigh1, head_w, BT0, BT1, hwbh, hwbl);

    scanb_kernel<<<1, 256, 0, stream>>>(bucket_counts, bucket_base,
                                        bucket_cursor, offsets);
    bucket1_kernel<<<NB1, 256, 0, stream>>>(e_src, e_dst, bucket_cursor, pairs);
    bucket2_kernel<<<NBUCKETS, 256, 0, stream>>>(pairs, bucket_base, offsets,
                                                 deg, src_sorted);

    // Layer 0
    aggregate_kernel<<<(N_NODES * 64 + 255) / 256, 256, 0, stream>>>(
        xh, offsets, src_sorted, deg, ah);
    gemm_mfma<<<(N_NODES + BM - 1) / BM, 512, 0, stream>>>(
        xh, ah, BT0, b0, 1, hwbh, hwbl, head_b, (float*)d_out);

    // Layer 1 (fused head)
    aggregate_kernel<<<(N_NODES * 64 + 255) / 256, 256, 0, stream>>>(
        xh, offsets, src_sorted, deg, ah);
    gemm_mfma<<<(N_NODES + BM - 1) / BM, 512, 0, stream>>>(
        xh, ah, BT1, b1, 2, hwbh, hwbl, head_b, (float*)d_out);
}

// Round 12
// 228.743 us; speedup vs baseline: 3.4432x; 1.0169x over previous
//
#include <hip/hip_runtime.h>
#include <hip/hip_bf16.h>

#define N_NODES 50000
#define N_EDGES 800000
#define C 128
#define D_IN 32
#define T0 25000
#define OUT_DIM 16
#define NBUCKETS ((N_NODES + 255) / 256)      // 196, bucket = dst>>8
#define NB1 512
#define CHUNK1 ((N_EDGES + NB1 - 1) / NB1)    // 1563
#define ENC_BLOCKS 512
#define HIST_BLOCKS 256
#define PREP_ITEMS (2 * 128 * 384 + 2 * 16 * 128)
#define PREP_BLOCKS ((PREP_ITEMS + 255) / 256)

// Feature storage: single bf16 plane xh[N][128]; agg plane ah[N][128].
// GEMM K=384: segs {xh*Ws_hi, ah*Wn_hi, xh*Ws_lo} (W fp32-compensated,
// x bf16-rounded). Layer-1 GEMM fuses the head (hw split hi/lo).

typedef __attribute__((ext_vector_type(8))) short short8;
typedef __attribute__((ext_vector_type(4))) float f32x4;

__device__ __forceinline__ unsigned short f2bf(float f) {
    union { float f; unsigned int i; } u; u.f = f;
    unsigned int x = u.i;
    unsigned int r = x + 0x7fffu + ((x >> 16) & 1u);
    return (unsigned short)(r >> 16);
}
__device__ __forceinline__ float bf2f(unsigned short h) {
    union { unsigned int i; float f; } u; u.i = ((unsigned int)h) << 16;
    return u.f;
}
__device__ __forceinline__ float lo_f(unsigned int w) {
    union { unsigned int i; float f; } u; u.i = w << 16;
    return u.f;
}
__device__ __forceinline__ float hi_f(unsigned int w) {
    union { unsigned int i; float f; } u; u.i = w & 0xffff0000u;
    return u.f;
}
__device__ __forceinline__ void async16(void* lds, const void* g) {
    __builtin_amdgcn_global_load_lds(
        (const __attribute__((address_space(1))) void*)g,
        (__attribute__((address_space(3))) void*)lds, 16, 0, 0);
}
__device__ __forceinline__ void add8(float* a, uint4 v) {
    a[0] += lo_f(v.x); a[1] += hi_f(v.x);
    a[2] += lo_f(v.y); a[3] += hi_f(v.y);
    a[4] += lo_f(v.z); a[5] += hi_f(v.z);
    a[6] += lo_f(v.w); a[7] += hi_f(v.w);
}

// ---------------------------------------------------------------------------
// Mega-kernel: encode (blocks 0..511) + bucket hist (512..767) +
// weight prep (768..). One launch, three independent phases.
// ---------------------------------------------------------------------------
__global__ __launch_bounds__(256) void encode_hist_prep_kernel(
    const float* __restrict__ feats0, const float* __restrict__ feats1,
    const float* __restrict__ w0, const float* __restrict__ b0,
    const float* __restrict__ w1, const float* __restrict__ b1,
    const int* __restrict__ row_idx, unsigned short* __restrict__ xh,
    const int* __restrict__ dst, int* __restrict__ bucket_counts,
    const float* __restrict__ ws0, const float* __restrict__ wn0,
    const float* __restrict__ ws1, const float* __restrict__ wn1,
    const float* __restrict__ hw,
    unsigned short* __restrict__ BT0, unsigned short* __restrict__ BT1,
    unsigned short* __restrict__ hwbh, unsigned short* __restrict__ hwbl)
{
    if (blockIdx.x >= ENC_BLOCKS + HIST_BLOCKS) {
        // ---- weight prep ----
        int idx = (blockIdx.x - ENC_BLOCKS - HIST_BLOCKS) * 256 + threadIdx.x;
        const int per_layer = 128 * 384;
        if (idx < 2 * per_layer) {
            int lyr = idx / per_layer;
            int rem = idx - lyr * per_layer;
            int n = rem / 384;
            int k = rem - n * 384;
            int seg = k >> 7;     // 0:Ws_hi 1:Wn_hi 2:Ws_lo
            int ch = k & 127;
            const float* W = (lyr == 0) ? ((seg == 1) ? wn0 : ws0)
                                        : ((seg == 1) ? wn1 : ws1);
            float v = W[ch * 128 + n];
            unsigned short hi = f2bf(v);
            unsigned short out = (seg == 2) ? f2bf(v - bf2f(hi)) : hi;
            (lyr == 0 ? BT0 : BT1)[(size_t)n * 384 + k] = out;
            return;
        }
        int jdx = idx - 2 * per_layer;
        if (jdx >= 2 * 16 * 128) return;
        int plane = jdx >> 11;
        int rem = jdx & 2047;
        int n = rem >> 7;
        int k = rem & 127;
        float v = hw[k * OUT_DIM + n];
        unsigned short hi = f2bf(v);
        (plane ? hwbl : hwbh)[n * 136 + k] = plane ? f2bf(v - bf2f(hi)) : hi;
        return;
    }
    if (blockIdx.x >= ENC_BLOCKS) {
        // ---- bucket histogram ----
        __shared__ int h[NBUCKETS];
        for (int i = threadIdx.x; i < NBUCKETS; i += 256) h[i] = 0;
        __syncthreads();
        int bid = blockIdx.x - ENC_BLOCKS;
        for (int e = bid * 256 + threadIdx.x; e < N_EDGES;
             e += HIST_BLOCKS * 256)
            atomicAdd(&h[dst[e] >> 8], 1);
        __syncthreads();
        for (int i = threadIdx.x; i < NBUCKETS; i += 256)
            if (h[i]) atomicAdd(&bucket_counts[i], h[i]);
        return;
    }

    // ---- encode ----
    __shared__ float sw0[D_IN * C];
    __shared__ float sw1[D_IN * C];
    __shared__ float sb0[C];
    __shared__ float sb1[C];
    for (int i = threadIdx.x; i < D_IN * C; i += blockDim.x) {
        sw0[i] = w0[i];
        sw1[i] = w1[i];
    }
    if (threadIdx.x < C) {
        sb0[threadIdx.x] = b0[threadIdx.x];
        sb1[threadIdx.x] = b1[threadIdx.x];
    }
    __syncthreads();

    int j = threadIdx.x & 15;
    int ln = threadIdx.x >> 4;
    for (int n = blockIdx.x * 16 + ln; n < N_NODES; n += ENC_BLOCKS * 16) {
        int r = row_idx[n];
        const float* f = (r < T0) ? (feats0 + (size_t)r * D_IN)
                                  : (feats1 + (size_t)(r - T0) * D_IN);
        const float* W = (r < T0) ? sw0 : sw1;
        const float* B = (r < T0) ? sb0 : sb1;
        float4 f4[8];
#pragma unroll
        for (int i = 0; i < 8; ++i) f4[i] = ((const float4*)f)[i];
        float acc[8];
#pragma unroll
        for (int cc = 0; cc < 8; ++cc) acc[cc] = B[8 * j + cc];
#pragma unroll
        for (int k = 0; k < D_IN; ++k) {
            float fk = ((const float*)f4)[k];
            float4 wa = *(const float4*)&W[k * C + 8 * j];
            float4 wb = *(const float4*)&W[k * C + 8 * j + 4];
            acc[0] += fk * wa.x; acc[1] += fk * wa.y;
            acc[2] += fk * wa.z; acc[3] += fk * wa.w;
            acc[4] += fk * wb.x; acc[5] += fk * wb.y;
            acc[6] += fk * wb.z; acc[7] += fk * wb.w;
        }
        short8 h8;
#pragma unroll
        for (int cc = 0; cc < 8; ++cc) h8[cc] = (short)f2bf(acc[cc]);
        *(short8*)(xh + (size_t)n * 128 + 8 * j) = h8;
    }
}

// ---------------------------------------------------------------------------
// CSR build: tiny scan -> bucket scatter -> local CSR
// ---------------------------------------------------------------------------
__global__ __launch_bounds__(256) void scanb_kernel(
    const int* __restrict__ bucket_counts, int* __restrict__ bucket_base,
    int* __restrict__ bucket_cursor, int* __restrict__ offsets)
{
    __shared__ int ws[4];
    int t = threadIdx.x;
    int c = (t < NBUCKETS) ? bucket_counts[t] : 0;
    int lane = t & 63, wid = t >> 6;
    int v = c;
#pragma unroll
    for (int off = 1; off < 64; off <<= 1) {
        int s = __shfl_up(v, off, 64);
        if (lane >= off) v += s;
    }
    if (lane == 63) ws[wid] = v;
    __syncthreads();
    if (t == 0) {
        int run = 0;
#pragma unroll
        for (int j = 0; j < 4; ++j) { int s = ws[j]; ws[j] = run; run += s; }
    }
    __syncthreads();
    int excl = ws[wid] + (v - c);
    if (t < NBUCKETS) {
        bucket_base[t] = excl;
        bucket_cursor[t] = excl;
    }
    if (t == 0) {
        bucket_base[NBUCKETS] = N_EDGES;
        offsets[N_NODES] = N_EDGES;
    }
}

__global__ __launch_bounds__(256) void bucket1_kernel(
    const int* __restrict__ src, const int* __restrict__ dst,
    int* __restrict__ bucket_cursor, uint2* __restrict__ pairs)
{
    __shared__ int hist[NBUCKETS];
    __shared__ int base[NBUCKETS];
    __shared__ int cur[NBUCKETS];
    int tid = threadIdx.x;
    for (int i = tid; i < NBUCKETS; i += 256) { hist[i] = 0; cur[i] = 0; }
    __syncthreads();
    int ebeg = blockIdx.x * CHUNK1;
    int eend = ebeg + CHUNK1;
    if (eend > N_EDGES) eend = N_EDGES;
    for (int e = ebeg + tid; e < eend; e += 256)
        atomicAdd(&hist[dst[e] >> 8], 1);
    __syncthreads();
    for (int i = tid; i < NBUCKETS; i += 256)
        if (hist[i] > 0) base[i] = atomicAdd(&bucket_cursor[i], hist[i]);
    __syncthreads();
    for (int e = ebeg + tid; e < eend; e += 256) {
        int d = dst[e];
        int b = d >> 8;
        int pos = base[b] + atomicAdd(&cur[b], 1);
        pairs[pos] = make_uint2((unsigned)src[e], (unsigned)d);
    }
}

__global__ __launch_bounds__(256) void bucket2_kernel(
    const uint2* __restrict__ pairs, const int* __restrict__ bucket_base,
    int* __restrict__ offsets, float* __restrict__ deg,
    int* __restrict__ src_sorted)
{
    __shared__ int cnt[256];
    __shared__ int noff[256];
    __shared__ int cur[256];
    __shared__ int ws[4];
    int b = blockIdx.x;
    int n0 = b << 8;
    int tid = threadIdx.x;
    int bb = bucket_base[b];
    int be = bucket_base[b + 1];
    cnt[tid] = 0;
    cur[tid] = 0;
    __syncthreads();
    for (int e = bb + tid; e < be; e += 256)
        atomicAdd(&cnt[pairs[e].y & 255], 1);
    __syncthreads();
    int c = cnt[tid];
    int lane = tid & 63, wid = tid >> 6;
    int v = c;
#pragma unroll
    for (int off = 1; off < 64; off <<= 1) {
        int s = __shfl_up(v, off, 64);
        if (lane >= off) v += s;
    }
    if (lane == 63) ws[wid] = v;
    __syncthreads();
    if (tid == 0) {
        int run = 0;
#pragma unroll
        for (int j = 0; j < 4; ++j) { int s = ws[j]; ws[j] = run; run += s; }
    }
    __syncthreads();
    int o = bb + ws[wid] + (v - c);
    noff[tid] = o;
    int n = n0 + tid;
    if (n < N_NODES) {
        offsets[n] = o;
        deg[n] = (float)(c > 0 ? c : 1);
    }
    __syncthreads();
    for (int e = bb + tid; e < be; e += 256) {
        uint2 p = pairs[e];
        int local = p.y & 255;
        int pos = noff[local] + atomicAdd(&cur[local], 1);
        src_sorted[pos] = (int)p.x;
    }
}

// ---------------------------------------------------------------------------
// Aggregate: one wave per dst node. lane = h*16 + u; one wave-load covers
// FOUR edges; 32 edges / 8 independent gathers per iteration (MLP=8).
// Out-of-range slots clamp to beg (L1-hot duplicate row), adds predicated.
// ---------------------------------------------------------------------------
__global__ __launch_bounds__(256) void aggregate_kernel(
    const unsigned short* __restrict__ xh, const int* __restrict__ offsets,
    const int* __restrict__ src_sorted, const float* __restrict__ deg,
    unsigned short* __restrict__ ah)
{
    int wave = (blockIdx.x * blockDim.x + threadIdx.x) >> 6;
    int lane = threadIdx.x & 63;
    if (wave >= N_NODES) return;
    int h = lane >> 4;
    int u = lane & 15;
    int beg = offsets[wave];
    int end = offsets[wave + 1];
    float acc[8];
#pragma unroll
    for (int j = 0; j < 8; ++j) acc[j] = 0.f;

    for (int e = beg; e < end; e += 32) {
        int idx[8], s[8];
#pragma unroll
        for (int t = 0; t < 8; ++t) {
            idx[t] = e + 4 * t + h;
            int cc = idx[t] < end ? idx[t] : beg;
            s[t] = src_sorted[cc];
        }
        uint4 v[8];
#pragma unroll
        for (int t = 0; t < 8; ++t)
            v[t] = *(const uint4*)(xh + (size_t)s[t] * 128 + u * 8);
#pragma unroll
        for (int t = 0; t < 8; ++t)
            if (idx[t] < end) add8(acc, v[t]);
    }

#pragma unroll
    for (int j = 0; j < 8; ++j) {
        acc[j] += __shfl_xor(acc[j], 16);
        acc[j] += __shfl_xor(acc[j], 32);
    }
    if (lane < 16) {
        float inv = 1.0f / deg[wave];
        short8 hv;
#pragma unroll
        for (int j = 0; j < 8; ++j)
            hv[j] = (short)f2bf(acc[j] * inv);
        *(short8*)(ah + (size_t)wave * 128 + u * 8) = hv;
    }
}

// ---------------------------------------------------------------------------
// Layer GEMM: 512 thr / 8 waves, tile 128x128, K=384 in 3 chunks of 128.
// Chunk order {xh*Ws_hi, (A kept)*Ws_lo, ah*Wn_hi} -> xh staged ONCE.
// mode=1: relu, write xh plane. mode=2: fused head -> out[N][16].
// ---------------------------------------------------------------------------
#define BM 128
__global__ __launch_bounds__(512) void gemm_mfma(
    unsigned short* __restrict__ xh, const unsigned short* __restrict__ ah,
    const unsigned short* __restrict__ BT, const float* __restrict__ bias,
    int mode,
    const unsigned short* __restrict__ hwbh,
    const unsigned short* __restrict__ hwbl,
    const float* __restrict__ hb, float* __restrict__ out)
{
    __shared__ uint4 smem4[4096];           // 64 KB: As 32K | Bs 32K / th
    char* As = (char*)smem4;
    char* Bs = (char*)smem4 + 32768;
    __shared__ float bias_s[C];
    __shared__ unsigned short hwh_s[16 * 136];
    __shared__ unsigned short hwl_s[16 * 136];
    __shared__ float hb_s[OUT_DIM];

    int tid = threadIdx.x;
    int w = tid >> 6, l = tid & 63;
    int row0 = blockIdx.x * BM;
    if (tid < C) bias_s[tid] = bias[tid];
    if (mode == 2) {
        for (int i = tid; i < 16 * 136; i += 512) {
            hwh_s[i] = hwbh[i];
            hwl_s[i] = hwbl[i];
        }
        if (tid < OUT_DIM) hb_s[tid] = hb[tid];
    }

    f32x4 acc[2][4];
#pragma unroll
    for (int mt = 0; mt < 2; ++mt)
#pragma unroll
        for (int nt = 0; nt < 4; ++nt)
            acc[mt][nt] = (f32x4)(0.f);

    int wm = w & 3;
    int wn = w >> 2;
    int quad = l >> 4;
    int mrow = l & 15;

    // iteration ci: 0 -> A=xh, B seg0 (Ws_hi); 1 -> A kept, B seg2 (Ws_lo);
    //               2 -> A=ah, B seg1 (Wn_hi)
    const int bseg[3] = {0, 2, 1};

    for (int ci = 0; ci < 3; ++ci) {
        if (ci != 1) {
            const char* abase = (const char*)(ci == 0 ? xh : ah);
#pragma unroll
            for (int i = 0; i < 4; ++i) {
                int off = i * 8192 + tid * 16;
                int rl = off >> 8;
                int row = row0 + rl;
                if (row > N_NODES - 1) row = N_NODES - 1;
                int u = ((off >> 4) & 15) ^ (rl & 15);
                async16(As + off, abase + (size_t)row * 256 + u * 16);
            }
        }
        int coff = bseg[ci] * 256;
#pragma unroll
        for (int i = 0; i < 4; ++i) {
            int off = i * 8192 + tid * 16;
            int n = off >> 8;
            int u = ((off >> 4) & 15) ^ (n & 15);
            async16(Bs + off, (const char*)BT + (size_t)n * 768 + coff + u * 16);
        }
        __syncthreads();
#pragma unroll
        for (int ks = 0; ks < 4; ++ks) {
            int cu = ks * 4 + quad;
            int swz = (cu ^ mrow) * 16;
            short8 a0 = *(const short8*)(As + (wm * 32 + mrow) * 256 + swz);
            short8 a1 = *(const short8*)(As + (wm * 32 + 16 + mrow) * 256 + swz);
            short8 b[4];
#pragma unroll
            for (int nt = 0; nt < 4; ++nt)
                b[nt] = *(const short8*)(Bs + (wn * 64 + nt * 16 + mrow) * 256 + swz);
#pragma unroll
            for (int nt = 0; nt < 4; ++nt) {
                acc[0][nt] = __builtin_amdgcn_mfma_f32_16x16x32_bf16(a0, b[nt], acc[0][nt], 0, 0, 0);
                acc[1][nt] = __builtin_amdgcn_mfma_f32_16x16x32_bf16(a1, b[nt], acc[1][nt], 0, 0, 0);
            }
        }
        __syncthreads();
    }

    // epilogue: bf16 tile in LDS, XOR-swizzled (unit' = unit ^ (rl&15))
    char* th = (char*)smem4;            // 32 KB: 128 rows x 256 B
    int relu = (mode == 1);
#pragma unroll
    for (int mt = 0; mt < 2; ++mt)
#pragma unroll
        for (int nt = 0; nt < 4; ++nt) {
            int col = wn * 64 + nt * 16 + mrow;
#pragma unroll
            for (int r = 0; r < 4; ++r) {
                int rl = wm * 32 + mt * 16 + quad * 4 + r;
                float v = acc[mt][nt][r] + bias_s[col];
                if (relu) v = fmaxf(v, 0.f);
                int su = (col >> 3) ^ (rl & 15);
                *(unsigned short*)(th + rl * 256 + su * 16 + (col & 7) * 2) =
                    f2bf(v);
            }
        }
    __syncthreads();

    if (mode == 1) {
        // unswizzling copy-out to xh
#pragma unroll
        for (int i = 0; i < 4; ++i) {
            int off = i * 8192 + tid * 16;
            int rl = off >> 8;
            int su = (((off >> 4) & 15) ^ (rl & 15)) * 16;
            int row = row0 + rl;
            if (row < N_NODES)
                *(uint4*)((char*)xh + (size_t)row * 256 + (off & 255)) =
                    *(const uint4*)(th + rl * 256 + su);
        }
    } else {
        // fused head: out_tile = th @ (hwh + hwl) + hb
        f32x4 hacc = (f32x4)(0.f);
        const unsigned short* Bp[2] = {hwh_s, hwl_s};
#pragma unroll
        for (int ps = 0; ps < 2; ++ps) {
#pragma unroll
            for (int ks = 0; ks < 4; ++ks) {
                int su = ((ks * 4 + quad) ^ mrow) * 16;
                short8 a = *(const short8*)(th + (w * 16 + mrow) * 256 + su);
                short8 b = *(const short8*)((const char*)Bp[ps] +
                                            mrow * 272 + ks * 64 + quad * 16);
                hacc = __builtin_amdgcn_mfma_f32_16x16x32_bf16(a, b, hacc, 0, 0, 0);
            }
        }
        float bb = hb_s[mrow];
#pragma unroll
        for (int r = 0; r < 4; ++r) {
            int grow = row0 + w * 16 + quad * 4 + r;
            if (grow < N_NODES)
                out[(size_t)grow * OUT_DIM + mrow] = hacc[r] + bb;
        }
    }
}

// ---------------------------------------------------------------------------
extern "C" void kernel_launch(void* const* d_in, const int* in_sizes, int n_in,
                              void* d_out, int out_size, void* d_ws, size_t ws_size,
                              hipStream_t stream)
{
    const float* feats0 = (const float*)d_in[0];
    const float* feats1 = (const float*)d_in[1];
    const float* enc_w0 = (const float*)d_in[2];
    const float* enc_b0 = (const float*)d_in[3];
    const float* enc_w1 = (const float*)d_in[4];
    const float* enc_b1 = (const float*)d_in[5];
    const float* w_self0 = (const float*)d_in[6];
    const float* w_neigh0 = (const float*)d_in[7];
    const float* b0 = (const float*)d_in[8];
    const float* w_self1 = (const float*)d_in[9];
    const float* w_neigh1 = (const float*)d_in[10];
    const float* b1 = (const float*)d_in[11];
    const float* head_w = (const float*)d_in[12];
    const float* head_b = (const float*)d_in[13];
    const int* node_row_idx = (const int*)d_in[14];
    const int* edge_index = (const int*)d_in[15];
    const int* e_src = edge_index;
    const int* e_dst = edge_index + N_EDGES;

    char* p = (char*)d_ws;
    unsigned short* xh = (unsigned short*)p;  p += (size_t)N_NODES * C * 2;
    unsigned short* ah = (unsigned short*)p;  p += (size_t)N_NODES * C * 2;
    unsigned short* BT0 = (unsigned short*)p; p += (size_t)128 * 384 * 2;
    unsigned short* BT1 = (unsigned short*)p; p += (size_t)128 * 384 * 2;
    unsigned short* hwbh = (unsigned short*)p; p += (size_t)16 * 136 * 2;
    unsigned short* hwbl = (unsigned short*)p; p += (size_t)16 * 136 * 2;
    float* deg = (float*)p;        p += (size_t)N_NODES * 4;
    int* offsets = (int*)p;        p += (size_t)(N_NODES + 8) * 4;
    int* bucket_counts = (int*)p;  p += (size_t)(NBUCKETS + 8) * 4;
    int* bucket_base = (int*)p;    p += (size_t)(NBUCKETS + 8) * 4;
    int* bucket_cursor = (int*)p;  p += (size_t)(NBUCKETS + 8) * 4;
    int* src_sorted = (int*)p;     p += (size_t)N_EDGES * 4;
    // pairs aliases ah (ah unwritten until aggregate, which runs after
    // bucket2 on the same stream): 800K * 8 B = 6.4 MB <= 12.8 MB
    uint2* pairs = (uint2*)ah;

    hipMemsetAsync(bucket_counts, 0, (size_t)(NBUCKETS + 8) * 4, stream);

    encode_hist_prep_kernel<<<ENC_BLOCKS + HIST_BLOCKS + PREP_BLOCKS, 256, 0,
                              stream>>>(
        feats0, feats1, enc_w0, enc_b0, enc_w1, enc_b1, node_row_idx, xh,
        e_dst, bucket_counts,
        w_self0, w_neigh0, w_self1, w_neigh1, head_w, BT0, BT1, hwbh, hwbl);

    scanb_kernel<<<1, 256, 0, stream>>>(bucket_counts, bucket_base,
                                        bucket_cursor, offsets);
    bucket1_kernel<<<NB1, 256, 0, stream>>>(e_src, e_dst, bucket_cursor, pairs);
    bucket2_kernel<<<NBUCKETS, 256, 0, stream>>>(pairs, bucket_base, offsets,
                                                 deg, src_sorted);

    // Layer 0
    aggregate_kernel<<<(N_NODES * 64 + 255) / 256, 256, 0, stream>>>(
        xh, offsets, src_sorted, deg, ah);
    gemm_mfma<<<(N_NODES + BM - 1) / BM, 512, 0, stream>>>(
        xh, ah, BT0, b0, 1, hwbh, hwbl, head_b, (float*)d_out);

    // Layer 1 (fused head)
    aggregate_kernel<<<(N_NODES * 64 + 255) / 256, 256, 0, stream>>>(
        xh, offsets, src_sorted, deg, ah);
    gemm_mfma<<<(N_NODES + BM - 1) / BM, 512, 0, stream>>>(
        xh, ah, BT1, b1, 2, hwbh, hwbl, head_b, (float*)d_out);
}

// Round 13
// 226.020 us; speedup vs baseline: 3.4847x; 1.0120x over previous
//
#include <hip/hip_runtime.h>
#include <hip/hip_bf16.h>

#define N_NODES 50000
#define N_EDGES 800000
#define C 128
#define D_IN 32
#define T0 25000
#define OUT_DIM 16
#define NBUCKETS ((N_NODES + 255) / 256)      // 196, bucket = dst>>8
#define NB1 512
#define CHUNK1 ((N_EDGES + NB1 - 1) / NB1)    // 1563
#define ENC_BLOCKS 512
#define HIST_BLOCKS 256
#define PREP_ITEMS (2 * 128 * 256 + 2 * 16 * 128)
#define PREP_BLOCKS ((PREP_ITEMS + 255) / 256)

// Feature storage: single bf16 plane xh[N][128]; agg plane ah[N][128].
// GEMM K=256: segs {xh*Ws_hi, ah*Wn_hi} (W-rounding error ~7e-4/layer,
// measured absmax dominated by x-bf16 rounding). Layer-1 fuses the head
// (hw split hi/lo, fp32-compensated).

typedef __attribute__((ext_vector_type(8))) short short8;
typedef __attribute__((ext_vector_type(4))) float f32x4;

__device__ __forceinline__ unsigned short f2bf(float f) {
    union { float f; unsigned int i; } u; u.f = f;
    unsigned int x = u.i;
    unsigned int r = x + 0x7fffu + ((x >> 16) & 1u);
    return (unsigned short)(r >> 16);
}
__device__ __forceinline__ float bf2f(unsigned short h) {
    union { unsigned int i; float f; } u; u.i = ((unsigned int)h) << 16;
    return u.f;
}
__device__ __forceinline__ float lo_f(unsigned int w) {
    union { unsigned int i; float f; } u; u.i = w << 16;
    return u.f;
}
__device__ __forceinline__ float hi_f(unsigned int w) {
    union { unsigned int i; float f; } u; u.i = w & 0xffff0000u;
    return u.f;
}
__device__ __forceinline__ void async16(void* lds, const void* g) {
    __builtin_amdgcn_global_load_lds(
        (const __attribute__((address_space(1))) void*)g,
        (__attribute__((address_space(3))) void*)lds, 16, 0, 0);
}
__device__ __forceinline__ void add8(float* a, uint4 v) {
    a[0] += lo_f(v.x); a[1] += hi_f(v.x);
    a[2] += lo_f(v.y); a[3] += hi_f(v.y);
    a[4] += lo_f(v.z); a[5] += hi_f(v.z);
    a[6] += lo_f(v.w); a[7] += hi_f(v.w);
}

// ---------------------------------------------------------------------------
// Mega-kernel: encode (blocks 0..511, row_idx software-pipelined) +
// bucket hist (512..767) + weight prep (768..).
// ---------------------------------------------------------------------------
__global__ __launch_bounds__(256) void encode_hist_prep_kernel(
    const float* __restrict__ feats0, const float* __restrict__ feats1,
    const float* __restrict__ w0, const float* __restrict__ b0,
    const float* __restrict__ w1, const float* __restrict__ b1,
    const int* __restrict__ row_idx, unsigned short* __restrict__ xh,
    const int* __restrict__ dst, int* __restrict__ bucket_counts,
    const float* __restrict__ ws0, const float* __restrict__ wn0,
    const float* __restrict__ ws1, const float* __restrict__ wn1,
    const float* __restrict__ hw,
    unsigned short* __restrict__ BT0, unsigned short* __restrict__ BT1,
    unsigned short* __restrict__ hwbh, unsigned short* __restrict__ hwbl)
{
    if (blockIdx.x >= ENC_BLOCKS + HIST_BLOCKS) {
        // ---- weight prep ----
        int idx = (blockIdx.x - ENC_BLOCKS - HIST_BLOCKS) * 256 + threadIdx.x;
        const int per_layer = 128 * 256;
        if (idx < 2 * per_layer) {
            int lyr = idx / per_layer;
            int rem = idx - lyr * per_layer;
            int n = rem >> 8;
            int k = rem & 255;
            int seg = k >> 7;     // 0:Ws_hi 1:Wn_hi
            int ch = k & 127;
            const float* W = (lyr == 0) ? (seg ? wn0 : ws0)
                                        : (seg ? wn1 : ws1);
            (lyr == 0 ? BT0 : BT1)[(size_t)n * 256 + k] =
                f2bf(W[ch * 128 + n]);
            return;
        }
        int jdx = idx - 2 * per_layer;
        if (jdx >= 2 * 16 * 128) return;
        int plane = jdx >> 11;
        int rem = jdx & 2047;
        int n = rem >> 7;
        int k = rem & 127;
        float v = hw[k * OUT_DIM + n];
        unsigned short hi = f2bf(v);
        (plane ? hwbl : hwbh)[n * 136 + k] = plane ? f2bf(v - bf2f(hi)) : hi;
        return;
    }
    if (blockIdx.x >= ENC_BLOCKS) {
        // ---- bucket histogram ----
        __shared__ int h[NBUCKETS];
        for (int i = threadIdx.x; i < NBUCKETS; i += 256) h[i] = 0;
        __syncthreads();
        int bid = blockIdx.x - ENC_BLOCKS;
        for (int e = bid * 256 + threadIdx.x; e < N_EDGES;
             e += HIST_BLOCKS * 256)
            atomicAdd(&h[dst[e] >> 8], 1);
        __syncthreads();
        for (int i = threadIdx.x; i < NBUCKETS; i += 256)
            if (h[i]) atomicAdd(&bucket_counts[i], h[i]);
        return;
    }

    // ---- encode (pipelined row_idx prefetch) ----
    __shared__ float sw0[D_IN * C];
    __shared__ float sw1[D_IN * C];
    __shared__ float sb0[C];
    __shared__ float sb1[C];
    for (int i = threadIdx.x; i < D_IN * C; i += blockDim.x) {
        sw0[i] = w0[i];
        sw1[i] = w1[i];
    }
    if (threadIdx.x < C) {
        sb0[threadIdx.x] = b0[threadIdx.x];
        sb1[threadIdx.x] = b1[threadIdx.x];
    }
    __syncthreads();

    const int STEP = ENC_BLOCKS * 16;
    int j = threadIdx.x & 15;
    int ln = threadIdx.x >> 4;
    int n = blockIdx.x * 16 + ln;
    int r = (n < N_NODES) ? row_idx[n] : 0;
    for (; n < N_NODES; n += STEP) {
        int nn = n + STEP;
        int rn = (nn < N_NODES) ? row_idx[nn] : 0;
        const float* f = (r < T0) ? (feats0 + (size_t)r * D_IN)
                                  : (feats1 + (size_t)(r - T0) * D_IN);
        const float* W = (r < T0) ? sw0 : sw1;
        const float* B = (r < T0) ? sb0 : sb1;
        float4 f4[8];
#pragma unroll
        for (int i = 0; i < 8; ++i) f4[i] = ((const float4*)f)[i];
        float acc[8];
#pragma unroll
        for (int cc = 0; cc < 8; ++cc) acc[cc] = B[8 * j + cc];
#pragma unroll
        for (int k = 0; k < D_IN; ++k) {
            float fk = ((const float*)f4)[k];
            float4 wa = *(const float4*)&W[k * C + 8 * j];
            float4 wb = *(const float4*)&W[k * C + 8 * j + 4];
            acc[0] += fk * wa.x; acc[1] += fk * wa.y;
            acc[2] += fk * wa.z; acc[3] += fk * wa.w;
            acc[4] += fk * wb.x; acc[5] += fk * wb.y;
            acc[6] += fk * wb.z; acc[7] += fk * wb.w;
        }
        short8 h8;
#pragma unroll
        for (int cc = 0; cc < 8; ++cc) h8[cc] = (short)f2bf(acc[cc]);
        *(short8*)(xh + (size_t)n * 128 + 8 * j) = h8;
        r = rn;
    }
}

// ---------------------------------------------------------------------------
// CSR build: tiny scan -> bucket scatter -> local CSR
// ---------------------------------------------------------------------------
__global__ __launch_bounds__(256) void scanb_kernel(
    const int* __restrict__ bucket_counts, int* __restrict__ bucket_base,
    int* __restrict__ bucket_cursor, int* __restrict__ offsets)
{
    __shared__ int ws[4];
    int t = threadIdx.x;
    int c = (t < NBUCKETS) ? bucket_counts[t] : 0;
    int lane = t & 63, wid = t >> 6;
    int v = c;
#pragma unroll
    for (int off = 1; off < 64; off <<= 1) {
        int s = __shfl_up(v, off, 64);
        if (lane >= off) v += s;
    }
    if (lane == 63) ws[wid] = v;
    __syncthreads();
    if (t == 0) {
        int run = 0;
#pragma unroll
        for (int j = 0; j < 4; ++j) { int s = ws[j]; ws[j] = run; run += s; }
    }
    __syncthreads();
    int excl = ws[wid] + (v - c);
    if (t < NBUCKETS) {
        bucket_base[t] = excl;
        bucket_cursor[t] = excl;
    }
    if (t == 0) {
        bucket_base[NBUCKETS] = N_EDGES;
        offsets[N_NODES] = N_EDGES;
    }
}

__global__ __launch_bounds__(256) void bucket1_kernel(
    const int* __restrict__ src, const int* __restrict__ dst,
    int* __restrict__ bucket_cursor, uint2* __restrict__ pairs)
{
    __shared__ int hist[NBUCKETS];
    __shared__ int base[NBUCKETS];
    __shared__ int cur[NBUCKETS];
    int tid = threadIdx.x;
    for (int i = tid; i < NBUCKETS; i += 256) { hist[i] = 0; cur[i] = 0; }
    __syncthreads();
    int ebeg = blockIdx.x * CHUNK1;
    int eend = ebeg + CHUNK1;
    if (eend > N_EDGES) eend = N_EDGES;
    for (int e = ebeg + tid; e < eend; e += 256)
        atomicAdd(&hist[dst[e] >> 8], 1);
    __syncthreads();
    for (int i = tid; i < NBUCKETS; i += 256)
        if (hist[i] > 0) base[i] = atomicAdd(&bucket_cursor[i], hist[i]);
    __syncthreads();
    for (int e = ebeg + tid; e < eend; e += 256) {
        int d = dst[e];
        int b = d >> 8;
        int pos = base[b] + atomicAdd(&cur[b], 1);
        pairs[pos] = make_uint2((unsigned)src[e], (unsigned)d);
    }
}

__global__ __launch_bounds__(256) void bucket2_kernel(
    const uint2* __restrict__ pairs, const int* __restrict__ bucket_base,
    int* __restrict__ offsets, float* __restrict__ deg,
    int* __restrict__ src_sorted)
{
    __shared__ int cnt[256];
    __shared__ int noff[256];
    __shared__ int cur[256];
    __shared__ int ws[4];
    int b = blockIdx.x;
    int n0 = b << 8;
    int tid = threadIdx.x;
    int bb = bucket_base[b];
    int be = bucket_base[b + 1];
    cnt[tid] = 0;
    cur[tid] = 0;
    __syncthreads();
    for (int e = bb + tid; e < be; e += 256)
        atomicAdd(&cnt[pairs[e].y & 255], 1);
    __syncthreads();
    int c = cnt[tid];
    int lane = tid & 63, wid = tid >> 6;
    int v = c;
#pragma unroll
    for (int off = 1; off < 64; off <<= 1) {
        int s = __shfl_up(v, off, 64);
        if (lane >= off) v += s;
    }
    if (lane == 63) ws[wid] = v;
    __syncthreads();
    if (tid == 0) {
        int run = 0;
#pragma unroll
        for (int j = 0; j < 4; ++j) { int s = ws[j]; ws[j] = run; run += s; }
    }
    __syncthreads();
    int o = bb + ws[wid] + (v - c);
    noff[tid] = o;
    int n = n0 + tid;
    if (n < N_NODES) {
        offsets[n] = o;
        deg[n] = (float)(c > 0 ? c : 1);
    }
    __syncthreads();
    for (int e = bb + tid; e < be; e += 256) {
        uint2 p = pairs[e];
        int local = p.y & 255;
        int pos = noff[local] + atomicAdd(&cur[local], 1);
        src_sorted[pos] = (int)p.x;
    }
}

// ---------------------------------------------------------------------------
// Aggregate: one wave per dst node. lane = h*16 + u; one wave-load covers
// FOUR edges; 32 edges / 8 independent gathers per iteration (MLP=8).
// ---------------------------------------------------------------------------
__global__ __launch_bounds__(256) void aggregate_kernel(
    const unsigned short* __restrict__ xh, const int* __restrict__ offsets,
    const int* __restrict__ src_sorted, const float* __restrict__ deg,
    unsigned short* __restrict__ ah)
{
    int wave = (blockIdx.x * blockDim.x + threadIdx.x) >> 6;
    int lane = threadIdx.x & 63;
    if (wave >= N_NODES) return;
    int h = lane >> 4;
    int u = lane & 15;
    int beg = offsets[wave];
    int end = offsets[wave + 1];
    float acc[8];
#pragma unroll
    for (int j = 0; j < 8; ++j) acc[j] = 0.f;

    for (int e = beg; e < end; e += 32) {
        int idx[8], s[8];
#pragma unroll
        for (int t = 0; t < 8; ++t) {
            idx[t] = e + 4 * t + h;
            int cc = idx[t] < end ? idx[t] : beg;
            s[t] = src_sorted[cc];
        }
        uint4 v[8];
#pragma unroll
        for (int t = 0; t < 8; ++t)
            v[t] = *(const uint4*)(xh + (size_t)s[t] * 128 + u * 8);
#pragma unroll
        for (int t = 0; t < 8; ++t)
            if (idx[t] < end) add8(acc, v[t]);
    }

#pragma unroll
    for (int j = 0; j < 8; ++j) {
        acc[j] += __shfl_xor(acc[j], 16);
        acc[j] += __shfl_xor(acc[j], 32);
    }
    if (lane < 16) {
        float inv = 1.0f / deg[wave];
        short8 hv;
#pragma unroll
        for (int j = 0; j < 8; ++j)
            hv[j] = (short)f2bf(acc[j] * inv);
        *(short8*)(ah + (size_t)wave * 128 + u * 8) = hv;
    }
}

// ---------------------------------------------------------------------------
// Layer GEMM: 512 thr / 8 waves, tile 128x128, K=256 in 2 chunks of 128:
// {xh*Ws_hi, ah*Wn_hi}. BT row = 256 slots (512 B).
// mode=1: relu, write xh plane. mode=2: fused head -> out[N][16].
// ---------------------------------------------------------------------------
#define BM 128
__global__ __launch_bounds__(512) void gemm_mfma(
    unsigned short* __restrict__ xh, const unsigned short* __restrict__ ah,
    const unsigned short* __restrict__ BT, const float* __restrict__ bias,
    int mode,
    const unsigned short* __restrict__ hwbh,
    const unsigned short* __restrict__ hwbl,
    const float* __restrict__ hb, float* __restrict__ out)
{
    __shared__ uint4 smem4[4096];           // 64 KB: As 32K | Bs 32K / th
    char* As = (char*)smem4;
    char* Bs = (char*)smem4 + 32768;
    __shared__ float bias_s[C];
    __shared__ unsigned short hwh_s[16 * 136];
    __shared__ unsigned short hwl_s[16 * 136];
    __shared__ float hb_s[OUT_DIM];

    int tid = threadIdx.x;
    int w = tid >> 6, l = tid & 63;
    int row0 = blockIdx.x * BM;
    if (tid < C) bias_s[tid] = bias[tid];
    if (mode == 2) {
        for (int i = tid; i < 16 * 136; i += 512) {
            hwh_s[i] = hwbh[i];
            hwl_s[i] = hwbl[i];
        }
        if (tid < OUT_DIM) hb_s[tid] = hb[tid];
    }

    f32x4 acc[2][4];
#pragma unroll
    for (int mt = 0; mt < 2; ++mt)
#pragma unroll
        for (int nt = 0; nt < 4; ++nt)
            acc[mt][nt] = (f32x4)(0.f);

    int wm = w & 3;
    int wn = w >> 2;
    int quad = l >> 4;
    int mrow = l & 15;

    for (int c = 0; c < 2; ++c) {
        const char* abase = (const char*)(c == 0 ? xh : ah);
#pragma unroll
        for (int i = 0; i < 4; ++i) {
            int off = i * 8192 + tid * 16;
            int rl = off >> 8;
            int row = row0 + rl;
            if (row > N_NODES - 1) row = N_NODES - 1;
            int u = ((off >> 4) & 15) ^ (rl & 15);
            async16(As + off, abase + (size_t)row * 256 + u * 16);
        }
#pragma unroll
        for (int i = 0; i < 4; ++i) {
            int off = i * 8192 + tid * 16;
            int n = off >> 8;
            int u = ((off >> 4) & 15) ^ (n & 15);
            async16(Bs + off, (const char*)BT + (size_t)n * 512 + c * 256 + u * 16);
        }
        __syncthreads();
#pragma unroll
        for (int ks = 0; ks < 4; ++ks) {
            int cu = ks * 4 + quad;
            int swz = (cu ^ mrow) * 16;
            short8 a0 = *(const short8*)(As + (wm * 32 + mrow) * 256 + swz);
            short8 a1 = *(const short8*)(As + (wm * 32 + 16 + mrow) * 256 + swz);
            short8 b[4];
#pragma unroll
            for (int nt = 0; nt < 4; ++nt)
                b[nt] = *(const short8*)(Bs + (wn * 64 + nt * 16 + mrow) * 256 + swz);
#pragma unroll
            for (int nt = 0; nt < 4; ++nt) {
                acc[0][nt] = __builtin_amdgcn_mfma_f32_16x16x32_bf16(a0, b[nt], acc[0][nt], 0, 0, 0);
                acc[1][nt] = __builtin_amdgcn_mfma_f32_16x16x32_bf16(a1, b[nt], acc[1][nt], 0, 0, 0);
            }
        }
        __syncthreads();
    }

    // epilogue: bf16 tile in LDS, XOR-swizzled (unit' = unit ^ (rl&15))
    char* th = (char*)smem4;            // 32 KB: 128 rows x 256 B
    int relu = (mode == 1);
#pragma unroll
    for (int mt = 0; mt < 2; ++mt)
#pragma unroll
        for (int nt = 0; nt < 4; ++nt) {
            int col = wn * 64 + nt * 16 + mrow;
#pragma unroll
            for (int r = 0; r < 4; ++r) {
                int rl = wm * 32 + mt * 16 + quad * 4 + r;
                float v = acc[mt][nt][r] + bias_s[col];
                if (relu) v = fmaxf(v, 0.f);
                int su = (col >> 3) ^ (rl & 15);
                *(unsigned short*)(th + rl * 256 + su * 16 + (col & 7) * 2) =
                    f2bf(v);
            }
        }
    __syncthreads();

    if (mode == 1) {
        // unswizzling copy-out to xh
#pragma unroll
        for (int i = 0; i < 4; ++i) {
            int off = i * 8192 + tid * 16;
            int rl = off >> 8;
            int su = (((off >> 4) & 15) ^ (rl & 15)) * 16;
            int row = row0 + rl;
            if (row < N_NODES)
                *(uint4*)((char*)xh + (size_t)row * 256 + (off & 255)) =
                    *(const uint4*)(th + rl * 256 + su);
        }
    } else {
        // fused head: out_tile = th @ (hwh + hwl) + hb
        f32x4 hacc = (f32x4)(0.f);
        const unsigned short* Bp[2] = {hwh_s, hwl_s};
#pragma unroll
        for (int ps = 0; ps < 2; ++ps) {
#pragma unroll
            for (int ks = 0; ks < 4; ++ks) {
                int su = ((ks * 4 + quad) ^ mrow) * 16;
                short8 a = *(const short8*)(th + (w * 16 + mrow) * 256 + su);
                short8 b = *(const short8*)((const char*)Bp[ps] +
                                            mrow * 272 + ks * 64 + quad * 16);
                hacc = __builtin_amdgcn_mfma_f32_16x16x32_bf16(a, b, hacc, 0, 0, 0);
            }
        }
        float bb = hb_s[mrow];
#pragma unroll
        for (int r = 0; r < 4; ++r) {
            int grow = row0 + w * 16 + quad * 4 + r;
            if (grow < N_NODES)
                out[(size_t)grow * OUT_DIM + mrow] = hacc[r] + bb;
        }
    }
}

// ---------------------------------------------------------------------------
extern "C" void kernel_launch(void* const* d_in, const int* in_sizes, int n_in,
                              void* d_out, int out_size, void* d_ws, size_t ws_size,
                              hipStream_t stream)
{
    const float* feats0 = (const float*)d_in[0];
    const float* feats1 = (const float*)d_in[1];
    const float* enc_w0 = (const float*)d_in[2];
    const float* enc_b0 = (const float*)d_in[3];
    const float* enc_w1 = (const float*)d_in[4];
    const float* enc_b1 = (const float*)d_in[5];
    const float* w_self0 = (const float*)d_in[6];
    const float* w_neigh0 = (const float*)d_in[7];
    const float* b0 = (const float*)d_in[8];
    const float* w_self1 = (const float*)d_in[9];
    const float* w_neigh1 = (const float*)d_in[10];
    const float* b1 = (const float*)d_in[11];
    const float* head_w = (const float*)d_in[12];
    const float* head_b = (const float*)d_in[13];
    const int* node_row_idx = (const int*)d_in[14];
    const int* edge_index = (const int*)d_in[15];
    const int* e_src = edge_index;
    const int* e_dst = edge_index + N_EDGES;

    char* p = (char*)d_ws;
    unsigned short* xh = (unsigned short*)p;  p += (size_t)N_NODES * C * 2;
    unsigned short* ah = (unsigned short*)p;  p += (size_t)N_NODES * C * 2;
    unsigned short* BT0 = (unsigned short*)p; p += (size_t)128 * 256 * 2;
    unsigned short* BT1 = (unsigned short*)p; p += (size_t)128 * 256 * 2;
    unsigned short* hwbh = (unsigned short*)p; p += (size_t)16 * 136 * 2;
    unsigned short* hwbl = (unsigned short*)p; p += (size_t)16 * 136 * 2;
    float* deg = (float*)p;        p += (size_t)N_NODES * 4;
    int* offsets = (int*)p;        p += (size_t)(N_NODES + 8) * 4;
    int* bucket_counts = (int*)p;  p += (size_t)(NBUCKETS + 8) * 4;
    int* bucket_base = (int*)p;    p += (size_t)(NBUCKETS + 8) * 4;
    int* bucket_cursor = (int*)p;  p += (size_t)(NBUCKETS + 8) * 4;
    int* src_sorted = (int*)p;     p += (size_t)N_EDGES * 4;
    // pairs aliases ah (ah unwritten until aggregate, which runs after
    // bucket2 on the same stream): 800K * 8 B = 6.4 MB <= 12.8 MB
    uint2* pairs = (uint2*)ah;

    hipMemsetAsync(bucket_counts, 0, (size_t)(NBUCKETS + 8) * 4, stream);

    encode_hist_prep_kernel<<<ENC_BLOCKS + HIST_BLOCKS + PREP_BLOCKS, 256, 0,
                              stream>>>(
        feats0, feats1, enc_w0, enc_b0, enc_w1, enc_b1, node_row_idx, xh,
        e_dst, bucket_counts,
        w_self0, w_neigh0, w_self1, w_neigh1, head_w, BT0, BT1, hwbh, hwbl);

    scanb_kernel<<<1, 256, 0, stream>>>(bucket_counts, bucket_base,
                                        bucket_cursor, offsets);
    bucket1_kernel<<<NB1, 256, 0, stream>>>(e_src, e_dst, bucket_cursor, pairs);
    bucket2_kernel<<<NBUCKETS, 256, 0, stream>>>(pairs, bucket_base, offsets,
                                                 deg, src_sorted);

    // Layer 0
    aggregate_kernel<<<(N_NODES * 64 + 255) / 256, 256, 0, stream>>>(
        xh, offsets, src_sorted, deg, ah);
    gemm_mfma<<<(N_NODES + BM - 1) / BM, 512, 0, stream>>>(
        xh, ah, BT0, b0, 1, hwbh, hwbl, head_b, (float*)d_out);

    // Layer 1 (fused head)
    aggregate_kernel<<<(N_NODES * 64 + 255) / 256, 256, 0, stream>>>(
        xh, offsets, src_sorted, deg, ah);
    gemm_mfma<<<(N_NODES + BM - 1) / BM, 512, 0, stream>>>(
        xh, ah, BT1, b1, 2, hwbh, hwbl, head_b, (float*)d_out);
}